// Round 7
// baseline (827.538 us; speedup 1.0000x reference)
//
#include <hip/hip_runtime.h>
#include <hip/hip_fp16.h>

#define NLAYERS 4
#define BSHIFT 10   // 1024 rows per bucket
#define CHUNK 4096  // edges per bucket_scatter block
#define SGPB 2      // score: groups per wave (compile-time, unrolled)

typedef _Float16 f16x8 __attribute__((ext_vector_type(8)));
typedef float f32x4 __attribute__((ext_vector_type(4)));

// ---------------- zero fill ----------------
__global__ void zero_int_kernel(int* __restrict__ p, long n) {
    long i = (long)blockIdx.x * 256 + threadIdx.x;
    long stride = (long)gridDim.x * 256;
    for (; i < n; i += stride) p[i] = 0;
}

__device__ __forceinline__ float fast_tanh(float y) {
    y = fminf(fmaxf(y, -15.f), 15.f);
    float t = __expf(2.f * y);
    return (t - 1.f) / (t + 1.f);
}

__device__ __forceinline__ __half2 h2relu(__half2 v) {
    float2 f = __half22float2(v);
    return __floats2half2_rn(fmaxf(f.x, 0.f), fmaxf(f.y, 0.f));
}

// ================= CSR build over concatenated dst space =================
// [0,NT) rel0 dsts | [NT,NT+NA) rel1 dsts | [NT+NA,NCAT) rel2 dsts
__device__ __forceinline__ int edge_row(const int* ei_in, const int* ei_out, const int* ei_sp,
                                        int E_IN, int E_OUT, int E_SP, int NT, int NA,
                                        int e, int* src) {
    if (e < E_IN) { *src = ei_in[e]; return ei_in[E_IN + e]; }
    if (e < E_IN + E_OUT) { int i = e - E_IN; *src = ei_out[i]; return NT + ei_out[E_OUT + i]; }
    int i = e - E_IN - E_OUT; *src = ei_sp[i]; return NT + NA + ei_sp[E_SP + i];
}

// legacy direct hist/scatter (fallback when no workspace room for bucket buffer)
__global__ void hist_kernel(const int* __restrict__ ei_in, const int* __restrict__ ei_out,
                            const int* __restrict__ ei_sp, int E_IN, int E_OUT, int E_SP,
                            int NT, int NA, int* __restrict__ deg, int E_TOT) {
    int e = blockIdx.x * 256 + threadIdx.x;
    if (e >= E_TOT) return;
    int s;
    int row = edge_row(ei_in, ei_out, ei_sp, E_IN, E_OUT, E_SP, NT, NA, e, &s);
    atomicAdd(&deg[row], 1);
}

__global__ void scatter_kernel(const int* __restrict__ ei_in, const int* __restrict__ ei_out,
                               const int* __restrict__ ei_sp, int E_IN, int E_OUT, int E_SP,
                               int NT, int NA, int* __restrict__ cursor, int* __restrict__ col,
                               int E_TOT) {
    int e = blockIdx.x * 256 + threadIdx.x;
    if (e >= E_TOT) return;
    int s;
    int row = edge_row(ei_in, ei_out, ei_sp, E_IN, E_OUT, E_SP, NT, NA, e, &s);
    int pos = atomicAdd(&cursor[row], 1);
    col[pos] = s;
}

__global__ void scan1_kernel(const int* __restrict__ deg, int* __restrict__ rowptr,
                             int* __restrict__ bsum, int n) {
    __shared__ int lds[256];
    int tid = threadIdx.x;
    int base = blockIdx.x * 1024;
    int v[4];
    int mysum = 0;
    #pragma unroll
    for (int j = 0; j < 4; j++) {
        int idx = base + tid * 4 + j;
        v[j] = (idx < n) ? deg[idx] : 0;
        mysum += v[j];
    }
    lds[tid] = mysum;
    __syncthreads();
    for (int off = 1; off < 256; off <<= 1) {
        int t = (tid >= off) ? lds[tid - off] : 0;
        __syncthreads();
        lds[tid] += t;
        __syncthreads();
    }
    int excl = lds[tid] - mysum;
    if (tid == 255) bsum[blockIdx.x] = lds[tid];
    int run = excl;
    #pragma unroll
    for (int j = 0; j < 4; j++) {
        int idx = base + tid * 4 + j;
        if (idx < n) rowptr[idx] = run;
        run += v[j];
    }
}

__global__ void scan2_kernel(int* __restrict__ bsum, int nb) {
    __shared__ int lds[1024];
    int tid = threadIdx.x;
    int v = (tid < nb) ? bsum[tid] : 0;
    lds[tid] = v;
    __syncthreads();
    for (int off = 1; off < 1024; off <<= 1) {
        int t = (tid >= off) ? lds[tid - off] : 0;
        __syncthreads();
        lds[tid] += t;
        __syncthreads();
    }
    if (tid < nb) bsum[tid] = lds[tid] - v;
}

__global__ void scan3_kernel(int* __restrict__ rowptr, const int* __restrict__ bsum,
                             int* __restrict__ cursor, int n, int E) {
    int i = blockIdx.x * 256 + threadIdx.x;
    if (i < n) {
        int r = rowptr[i] + bsum[i >> 10];
        rowptr[i] = r;
        cursor[i] = r;
    }
    if (i == 0) rowptr[n] = E;
}

// ---- bucketed CSR build, pass 1: single-pass bin into fixed-capacity per-bucket regions ----
__global__ void bucket_scatter_kernel(const int* __restrict__ ei_in, const int* __restrict__ ei_out,
                                      const int* __restrict__ ei_sp, int E_IN, int E_OUT, int E_SP,
                                      int NT, int NA, int* __restrict__ bcur,
                                      uint2* __restrict__ ebuf, int E_TOT, int nbuck, int cap) {
    __shared__ int lc[1024], lbase[1024], lcur[1024];
    int tid = threadIdx.x;
    int chunk0 = blockIdx.x * CHUNK;
    int chunkN = E_TOT - chunk0;
    if (chunkN > CHUNK) chunkN = CHUNK;
    if (chunkN <= 0) return;
    for (int i = tid; i < nbuck; i += 256) { lc[i] = 0; lcur[i] = 0; }
    __syncthreads();
    for (int i = tid; i < chunkN; i += 256) {
        int s;
        int row = edge_row(ei_in, ei_out, ei_sp, E_IN, E_OUT, E_SP, NT, NA, chunk0 + i, &s);
        atomicAdd(&lc[row >> BSHIFT], 1);
    }
    __syncthreads();
    for (int i = tid; i < nbuck; i += 256) if (lc[i]) lbase[i] = atomicAdd(&bcur[i], lc[i]);
    __syncthreads();
    for (int i = tid; i < chunkN; i += 256) {
        int s;
        int row = edge_row(ei_in, ei_out, ei_sp, E_IN, E_OUT, E_SP, NT, NA, chunk0 + i, &s);
        int b = row >> BSHIFT;
        int pos = lbase[b] + atomicAdd(&lcur[b], 1);
        if (pos < cap) ebuf[(size_t)b * cap + pos] = make_uint2((unsigned)row, (unsigned)s);
    }
}

// ---- pass 2: exclusive scan of bucket counts -> global col offsets ----
__global__ void scanb_kernel(const int* __restrict__ bcur, int* __restrict__ boff,
                             int* __restrict__ rowptr, int nbuck, int cap, int NCAT) {
    __shared__ int lds[1024];
    int tid = threadIdx.x;
    int v = 0;
    if (tid < nbuck) { v = bcur[tid]; if (v > cap) v = cap; }
    lds[tid] = v;
    __syncthreads();
    for (int off = 1; off < 1024; off <<= 1) {
        int t = (tid >= off) ? lds[tid - off] : 0;
        __syncthreads();
        lds[tid] += t;
        __syncthreads();
    }
    if (tid < nbuck) boff[tid] = lds[tid] - v;
    if (tid == 1023) {
        boff[nbuck] = lds[1023];
        rowptr[NCAT] = lds[1023];
    }
}

// ---- pass 3: one block per bucket; LDS hist + LDS scan + LDS-cursor scatter ----
__global__ void __launch_bounds__(256) bucket_csr_kernel(
    const uint2* __restrict__ ebuf, const int* __restrict__ boff,
    int* __restrict__ rowptr, int* __restrict__ col, int NCAT, int cap) {
    __shared__ int ldeg[1024];
    __shared__ int lsum[256];
    int tid = threadIdx.x;
    int b = blockIdx.x;
    int row0 = b << BSHIFT;
    int e0 = boff[b], e1 = boff[b + 1];
    int cnt = e1 - e0;
    const uint2* src = ebuf + (size_t)b * cap;
    for (int i = tid; i < 1024; i += 256) ldeg[i] = 0;
    __syncthreads();
    for (int i = tid; i < cnt; i += 256)
        atomicAdd(&ldeg[src[i].x - (unsigned)row0], 1);
    __syncthreads();
    int bidx = tid * 4;
    int v0 = ldeg[bidx], v1 = ldeg[bidx + 1], v2 = ldeg[bidx + 2], v3 = ldeg[bidx + 3];
    int mysum = v0 + v1 + v2 + v3;
    lsum[tid] = mysum;
    __syncthreads();
    for (int off = 1; off < 256; off <<= 1) {
        int t = (tid >= off) ? lsum[tid - off] : 0;
        __syncthreads();
        lsum[tid] += t;
        __syncthreads();
    }
    int run = e0 + lsum[tid] - mysum;
    int vv[4] = {v0, v1, v2, v3};
    #pragma unroll
    for (int j = 0; j < 4; j++) {
        int r = bidx + j;
        if (row0 + r < NCAT) rowptr[row0 + r] = run;
        ldeg[r] = run;          // becomes the cursor
        run += vv[j];
    }
    __syncthreads();
    for (int i = tid; i < cnt; i += 256) {
        uint2 p = src[i];
        int pos = atomicAdd(&ldeg[p.x - (unsigned)row0], 1);
        col[pos] = (int)p.y;
    }
}

// ================= fused encoder + layer-0 projection (MFMA, 1 wave = 16 nodes) =================
__global__ void __launch_bounds__(256) encproj_addr_kernel(
    const float* __restrict__ x,
    const float* __restrict__ We, const float* __restrict__ be,
    const float* __restrict__ Wp, const float* __restrict__ bp,
    const float* __restrict__ a0, const float* __restrict__ a1,
    float* __restrict__ xa, __half* __restrict__ h,
    __half* __restrict__ o0, float* __restrict__ o1,
    int n, int gpb) {
    __shared__ __align__(16) float lds_t[4][16][36];
    __shared__ float sx[4][16 * 57];
    int tid = threadIdx.x;
    int wave = tid >> 6, lane = tid & 63;
    int colid = lane & 15, kgrp = lane >> 4;
    int fbase = kgrp * 8;

    f16x8 bE00, bE01, bE10, bE11;
    #pragma unroll
    for (int j = 0; j < 8; j++) {
        int k0 = fbase + j;
        int k1 = 32 + fbase + j;
        bE00[j] = (_Float16)We[k0 * 32 + colid];
        bE01[j] = (_Float16)We[k0 * 32 + 16 + colid];
        float w10 = (k1 < 53) ? We[k1 * 32 + colid] : 0.f;
        float w11 = (k1 < 53) ? We[k1 * 32 + 16 + colid] : 0.f;
        bE10[j] = (_Float16)w10;
        bE11[j] = (_Float16)w11;
    }
    float beC0 = be[colid], beC1 = be[16 + colid];

    f16x8 bP0, bP1;
    #pragma unroll
    for (int j = 0; j < 8; j++) {
        bP0[j] = (_Float16)Wp[(fbase + j) * 32 + colid];
        bP1[j] = (_Float16)Wp[(fbase + j) * 32 + 16 + colid];
    }
    float bpC0 = bp[colid], bpC1 = bp[16 + colid];

    float va0[8], va1[8];
    #pragma unroll
    for (int j = 0; j < 8; j++) { va0[j] = a0[fbase + j]; va1[j] = a1[fbase + j]; }

    float (*tp)[36] = lds_t[wave];
    float* sxw = sx[wave];
    int blockBase = blockIdx.x * gpb * 64;
    for (int gi = 0; gi < gpb; gi++) {
        int node0 = blockBase + gi * 64 + wave * 16;
        int node = node0 + colid;
        bool valid = node < n;
        int nn = n - node0;
        if (nn > 16) nn = 16;
        if (nn < 0) nn = 0;
        int elems = nn * 53;
        for (int i = lane; i < elems; i += 64) {
            int r = i / 53, c = i - r * 53;
            sxw[r * 57 + c] = x[(size_t)node0 * 53 + i];
        }
        f16x8 af0, af1;
        #pragma unroll
        for (int j = 0; j < 8; j++) {
            af0[j] = (_Float16)sxw[colid * 57 + fbase + j];
            int kk = 32 + fbase + j;
            float v1 = (kk < 53) ? sxw[colid * 57 + kk] : 0.f;
            af1[j] = (_Float16)v1;
        }
        f32x4 c0 = {0.f, 0.f, 0.f, 0.f};
        f32x4 c1 = {0.f, 0.f, 0.f, 0.f};
        c0 = __builtin_amdgcn_mfma_f32_16x16x32_f16(af0, bE00, c0, 0, 0, 0);
        c0 = __builtin_amdgcn_mfma_f32_16x16x32_f16(af1, bE10, c0, 0, 0, 0);
        c1 = __builtin_amdgcn_mfma_f32_16x16x32_f16(af0, bE01, c1, 0, 0, 0);
        c1 = __builtin_amdgcn_mfma_f32_16x16x32_f16(af1, bE11, c1, 0, 0, 0);
        #pragma unroll
        for (int r = 0; r < 4; r++) {
            c0[r] = fmaxf(c0[r] + beC0, 0.f);
            c1[r] = fmaxf(c1[r] + beC1, 0.f);
        }
        #pragma unroll
        for (int r = 0; r < 4; r++) {
            int row = kgrp * 4 + r;
            tp[row][colid] = c0[r];
            tp[row][16 + colid] = c1[r];
        }
        float4 xlo = *(const float4*)&tp[colid][fbase];
        float4 xhi = *(const float4*)&tp[colid][fbase + 4];
        float xe[8] = {xlo.x, xlo.y, xlo.z, xlo.w, xhi.x, xhi.y, xhi.z, xhi.w};
        if (valid) {
            size_t basep = (size_t)node * 32 + fbase;
            *(float4*)(xa + basep) = xlo;
            *(float4*)(xa + basep + 4) = xhi;
        }
        f16x8 af;
        #pragma unroll
        for (int j = 0; j < 8; j++) af[j] = (_Float16)xe[j];
        f32x4 p0 = {0.f, 0.f, 0.f, 0.f};
        f32x4 p1 = {0.f, 0.f, 0.f, 0.f};
        p0 = __builtin_amdgcn_mfma_f32_16x16x32_f16(af, bP0, p0, 0, 0, 0);
        p1 = __builtin_amdgcn_mfma_f32_16x16x32_f16(af, bP1, p1, 0, 0, 0);
        #pragma unroll
        for (int r = 0; r < 4; r++) { p0[r] += bpC0; p1[r] += bpC1; }
        #pragma unroll
        for (int r = 0; r < 4; r++) {
            int row = kgrp * 4 + r;
            tp[row][colid] = p0[r];
            tp[row][16 + colid] = p1[r];
        }
        float4 hlo = *(const float4*)&tp[colid][fbase];
        float4 hhi = *(const float4*)&tp[colid][fbase + 4];
        float hv[8] = {hlo.x, hlo.y, hlo.z, hlo.w, hhi.x, hhi.y, hhi.z, hhi.w};
        if (valid) {
            float4 hout;
            __half2* hp2 = (__half2*)&hout;
            hp2[0] = __floats2half2_rn(hv[0], hv[1]);
            hp2[1] = __floats2half2_rn(hv[2], hv[3]);
            hp2[2] = __floats2half2_rn(hv[4], hv[5]);
            hp2[3] = __floats2half2_rn(hv[6], hv[7]);
            *(float4*)(h + (size_t)node * 32 + fbase) = hout;
            float d0 = 0.f, d1 = 0.f;
            #pragma unroll
            for (int j = 0; j < 8; j++) {
                d0 += hv[j] * va0[j];
                d1 += hv[j] * va1[j];
            }
            size_t oidx = (size_t)node * 4 + kgrp;
            o0[oidx] = __float2half(d0);
            o1[oidx] = d1;
        }
    }
}

__global__ void __launch_bounds__(256) encproj_tx_kernel(
    const float* __restrict__ x,
    const float* __restrict__ We, const float* __restrict__ be,
    const float* __restrict__ Wp, const float* __restrict__ bp,
    const float* __restrict__ a0, const float* __restrict__ a1,
    const float* __restrict__ a2, const float* __restrict__ a3,
    float* __restrict__ xt, __half* __restrict__ h,
    __half* __restrict__ o0, float* __restrict__ o1,
    __half* __restrict__ o2, float* __restrict__ o3,
    int n, int gpb) {
    __shared__ __align__(16) float lds_t[4][16][36];
    int tid = threadIdx.x;
    int wave = tid >> 6, lane = tid & 63;
    int colid = lane & 15, kgrp = lane >> 4;
    int fbase = kgrp * 8;

    f16x8 bE0, bE1;
    #pragma unroll
    for (int j = 0; j < 8; j++) {
        int k = fbase + j;
        float w0 = (k < 6) ? We[k * 32 + colid] : 0.f;
        float w1 = (k < 6) ? We[k * 32 + 16 + colid] : 0.f;
        bE0[j] = (_Float16)w0;
        bE1[j] = (_Float16)w1;
    }
    float beC0 = be[colid], beC1 = be[16 + colid];

    f16x8 bP0, bP1;
    #pragma unroll
    for (int j = 0; j < 8; j++) {
        bP0[j] = (_Float16)Wp[(fbase + j) * 32 + colid];
        bP1[j] = (_Float16)Wp[(fbase + j) * 32 + 16 + colid];
    }
    float bpC0 = bp[colid], bpC1 = bp[16 + colid];

    float va0[8], va1[8], va2[8], va3[8];
    #pragma unroll
    for (int j = 0; j < 8; j++) {
        va0[j] = a0[fbase + j]; va1[j] = a1[fbase + j];
        va2[j] = a2[fbase + j]; va3[j] = a3[fbase + j];
    }

    float (*tp)[36] = lds_t[wave];
    int blockBase = blockIdx.x * gpb * 64;
    for (int gi = 0; gi < gpb; gi++) {
        int node = blockBase + gi * 64 + wave * 16 + colid;
        bool valid = node < n;
        f16x8 af0;
        #pragma unroll
        for (int j = 0; j < 8; j++) {
            int k = fbase + j;
            float xv = 0.f;
            if (k < 6 && valid) xv = x[(size_t)node * 6 + k];
            af0[j] = (_Float16)xv;
        }
        f32x4 c0 = {0.f, 0.f, 0.f, 0.f};
        f32x4 c1 = {0.f, 0.f, 0.f, 0.f};
        c0 = __builtin_amdgcn_mfma_f32_16x16x32_f16(af0, bE0, c0, 0, 0, 0);
        c1 = __builtin_amdgcn_mfma_f32_16x16x32_f16(af0, bE1, c1, 0, 0, 0);
        #pragma unroll
        for (int r = 0; r < 4; r++) {
            c0[r] = fmaxf(c0[r] + beC0, 0.f);
            c1[r] = fmaxf(c1[r] + beC1, 0.f);
        }
        #pragma unroll
        for (int r = 0; r < 4; r++) {
            int row = kgrp * 4 + r;
            tp[row][colid] = c0[r];
            tp[row][16 + colid] = c1[r];
        }
        float4 xlo = *(const float4*)&tp[colid][fbase];
        float4 xhi = *(const float4*)&tp[colid][fbase + 4];
        float xe[8] = {xlo.x, xlo.y, xlo.z, xlo.w, xhi.x, xhi.y, xhi.z, xhi.w};
        if (valid) {
            size_t basep = (size_t)node * 32 + fbase;
            *(float4*)(xt + basep) = xlo;
            *(float4*)(xt + basep + 4) = xhi;
        }
        f16x8 af;
        #pragma unroll
        for (int j = 0; j < 8; j++) af[j] = (_Float16)xe[j];
        f32x4 p0 = {0.f, 0.f, 0.f, 0.f};
        f32x4 p1 = {0.f, 0.f, 0.f, 0.f};
        p0 = __builtin_amdgcn_mfma_f32_16x16x32_f16(af, bP0, p0, 0, 0, 0);
        p1 = __builtin_amdgcn_mfma_f32_16x16x32_f16(af, bP1, p1, 0, 0, 0);
        #pragma unroll
        for (int r = 0; r < 4; r++) { p0[r] += bpC0; p1[r] += bpC1; }
        #pragma unroll
        for (int r = 0; r < 4; r++) {
            int row = kgrp * 4 + r;
            tp[row][colid] = p0[r];
            tp[row][16 + colid] = p1[r];
        }
        float4 hlo = *(const float4*)&tp[colid][fbase];
        float4 hhi = *(const float4*)&tp[colid][fbase + 4];
        float hv[8] = {hlo.x, hlo.y, hlo.z, hlo.w, hhi.x, hhi.y, hhi.z, hhi.w};
        if (valid) {
            float4 hout;
            __half2* hp2 = (__half2*)&hout;
            hp2[0] = __floats2half2_rn(hv[0], hv[1]);
            hp2[1] = __floats2half2_rn(hv[2], hv[3]);
            hp2[2] = __floats2half2_rn(hv[4], hv[5]);
            hp2[3] = __floats2half2_rn(hv[6], hv[7]);
            *(float4*)(h + (size_t)node * 32 + fbase) = hout;
            float d0 = 0.f, d1 = 0.f, d2 = 0.f, d3 = 0.f;
            #pragma unroll
            for (int j = 0; j < 8; j++) {
                d0 += hv[j] * va0[j];
                d1 += hv[j] * va1[j];
                d2 += hv[j] * va2[j];
                d3 += hv[j] * va3[j];
            }
            size_t oidx = (size_t)node * 4 + kgrp;
            o0[oidx] = __float2half(d0);
            o1[oidx] = d1;
            o2[oidx] = __float2half(d2);
            o3[oidx] = d3;
        }
    }
}

// ================= merged CSR aggregation (all rels), score-free =================
__global__ void __launch_bounds__(256) agg_all_kernel(
    const int* __restrict__ rowptr, const int* __restrict__ col,
    const __half* __restrict__ h_a, const __half* __restrict__ h_t,
    const __half* __restrict__ asrc0, const float* __restrict__ adst0,
    const __half* __restrict__ asrc1, const float* __restrict__ adst1,
    const __half* __restrict__ asrc2, const float* __restrict__ adst2,
    __half* __restrict__ agg_t0, __half* __restrict__ agg_a, __half* __restrict__ agg_t2,
    int NT, int NA, int mode, int nRows) {
    int tid = threadIdx.x;
    int lane = tid & 7;
    int head = lane >> 1;
    int f0 = lane * 4;
    long stride = (long)gridDim.x * 32;
    for (long gi = (long)blockIdx.x * 32 + (tid >> 3); gi < (long)nRows; gi += stride) {
        int row;
        if (mode == 0) row = (int)gi;
        else if (mode == 1) row = (gi < NT) ? (int)gi : (int)(gi + NA);
        else row = NT + (int)gi;
        int dst;
        const __half* h; const __half* asrc; const float* adp; __half* agg;
        if (row < NT)           { dst = row;           h = h_a; asrc = asrc0; adp = adst0; agg = agg_t0; }
        else if (row < NT + NA) { dst = row - NT;      h = h_t; asrc = asrc1; adp = adst1; agg = agg_a; }
        else                    { dst = row - NT - NA; h = h_t; asrc = asrc2; adp = adst2; agg = agg_t2; }
        float ad = adp[dst * 4 + head];
        int e0 = rowptr[row], e1 = rowptr[row + 1];
        __half2 acc0 = __floats2half2_rn(0.f, 0.f);
        __half2 acc1 = acc0;
        float den = 0.f;
        for (int e = e0; e < e1; e += 4) {
            int s0 = col[e];
            int s1 = (e + 1 < e1) ? col[e + 1] : s0;
            int s2 = (e + 2 < e1) ? col[e + 2] : s0;
            int s3 = (e + 3 < e1) ? col[e + 3] : s0;
            float as0 = __half2float(asrc[s0 * 4 + head]);
            float as1 = __half2float(asrc[s1 * 4 + head]);
            float as2 = __half2float(asrc[s2 * 4 + head]);
            float as3 = __half2float(asrc[s3 * 4 + head]);
            float2 r0 = *(const float2*)(h + s0 * 32 + f0);
            float2 r1 = *(const float2*)(h + s1 * 32 + f0);
            float2 r2 = *(const float2*)(h + s2 * 32 + f0);
            float2 r3 = *(const float2*)(h + s3 * 32 + f0);
            float t0 = as0 + ad; t0 = t0 > 0.f ? t0 : 0.2f * t0;
            float t1 = as1 + ad; t1 = t1 > 0.f ? t1 : 0.2f * t1;
            float t2 = as2 + ad; t2 = t2 > 0.f ? t2 : 0.2f * t2;
            float t3 = as3 + ad; t3 = t3 > 0.f ? t3 : 0.2f * t3;
            float ex0 = __expf(t0);
            float ex1 = (e + 1 < e1) ? __expf(t1) : 0.f;
            float ex2 = (e + 2 < e1) ? __expf(t2) : 0.f;
            float ex3 = (e + 3 < e1) ? __expf(t3) : 0.f;
            den += (ex0 + ex1) + (ex2 + ex3);
            __half2 eh0 = __float2half2_rn(ex0), eh1 = __float2half2_rn(ex1);
            __half2 eh2 = __float2half2_rn(ex2), eh3 = __float2half2_rn(ex3);
            acc0 = __hfma2(eh0, *(__half2*)&r0.x, acc0);
            acc1 = __hfma2(eh0, *(__half2*)&r0.y, acc1);
            acc0 = __hfma2(eh1, *(__half2*)&r1.x, acc0);
            acc1 = __hfma2(eh1, *(__half2*)&r1.y, acc1);
            acc0 = __hfma2(eh2, *(__half2*)&r2.x, acc0);
            acc1 = __hfma2(eh2, *(__half2*)&r2.y, acc1);
            acc0 = __hfma2(eh3, *(__half2*)&r3.x, acc0);
            acc1 = __hfma2(eh3, *(__half2*)&r3.y, acc1);
        }
        float r = 1.f / (den + 1e-16f);
        float2 a0 = __half22float2(acc0), a1 = __half22float2(acc1);
        float v0 = a0.x * r, v1 = a0.y * r, v2 = a1.x * r, v3 = a1.y * r;
        float2 opack;
        __half2 o0 = __floats2half2_rn(v0, v1), o1 = __floats2half2_rn(v2, v3);
        opack.x = *(float*)&o0; opack.y = *(float*)&o1;
        *(float2*)(agg + dst * 32 + f0) = opack;
    }
}

// ================= semantic score over agg_t0/agg_t2 (MFMA, 1 wave = 16 nodes x SGPB) =================
__global__ void __launch_bounds__(256) score_tx_kernel(
    const __half* __restrict__ agg_t0, const __half* __restrict__ agg_t2,
    const float* __restrict__ kw, const float* __restrict__ kb,
    const float* __restrict__ q, float* __restrict__ scoreOut, int n) {
    __shared__ float sS[2];
    int tid = threadIdx.x;
    int wave = tid >> 6, lane = tid & 63;
    int colid = lane & 15, kgrp = lane >> 4;
    int fbase = kgrp * 8;
    if (tid < 2) sS[tid] = 0.f;
    __syncthreads();

    f16x8 bK0, bK1;
    #pragma unroll
    for (int j = 0; j < 8; j++) {
        bK0[j] = (_Float16)kw[(fbase + j) * 32 + colid];
        bK1[j] = (_Float16)kw[(fbase + j) * 32 + 16 + colid];
    }
    float kb0 = kb[colid], kb1 = kb[16 + colid];
    float q0 = q[colid], q1 = q[16 + colid];

    float s0acc = 0.f, s2acc = 0.f;
    int blockBase = blockIdx.x * SGPB * 64;
    #pragma unroll
    for (int gi = 0; gi < SGPB; gi++) {
        int grp0 = blockBase + gi * 64 + wave * 16;   // 16-node group base
        int nodeA = grp0 + colid;                     // A-row this lane loads
        bool validA = nodeA < n;
        f16x8 af0 = {}, af2 = {};
        if (validA) {
            float4 r0 = *(const float4*)(agg_t0 + (size_t)nodeA * 32 + fbase);
            float4 r2 = *(const float4*)(agg_t2 + (size_t)nodeA * 32 + fbase);
            __half2* h0 = (__half2*)&r0;
            __half2* h2 = (__half2*)&r2;
            #pragma unroll
            for (int j = 0; j < 4; j++) {
                h0[j] = h2relu(h0[j]);
                h2[j] = h2relu(h2[j]);
            }
            af0 = *(f16x8*)&r0;
            af2 = *(f16x8*)&r2;
        }
        f32x4 c00 = {0.f, 0.f, 0.f, 0.f}, c01 = {0.f, 0.f, 0.f, 0.f};
        f32x4 c20 = {0.f, 0.f, 0.f, 0.f}, c21 = {0.f, 0.f, 0.f, 0.f};
        c00 = __builtin_amdgcn_mfma_f32_16x16x32_f16(af0, bK0, c00, 0, 0, 0);
        c01 = __builtin_amdgcn_mfma_f32_16x16x32_f16(af0, bK1, c01, 0, 0, 0);
        c20 = __builtin_amdgcn_mfma_f32_16x16x32_f16(af2, bK0, c20, 0, 0, 0);
        c21 = __builtin_amdgcn_mfma_f32_16x16x32_f16(af2, bK1, c21, 0, 0, 0);
        #pragma unroll
        for (int r = 0; r < 4; r++) {
            if (grp0 + kgrp * 4 + r < n) {   // C-row node validity
                s0acc += q0 * fast_tanh(c00[r] + kb0) + q1 * fast_tanh(c01[r] + kb1);
                s2acc += q0 * fast_tanh(c20[r] + kb0) + q1 * fast_tanh(c21[r] + kb1);
            }
        }
    }
    #pragma unroll
    for (int m = 1; m < 64; m <<= 1) {
        s0acc += __shfl_xor(s0acc, m, 64);
        s2acc += __shfl_xor(s2acc, m, 64);
    }
    if (lane == 0) {
        atomicAdd(&sS[0], s0acc);
        atomicAdd(&sS[1], s2acc);
    }
    __syncthreads();
    if (tid < 2) unsafeAtomicAdd(scoreOut + tid, sS[tid]);
}

// ================= fused combine + next-layer projection (MFMA, 1 wave = 16 nodes) =================
__global__ void __launch_bounds__(256) combineproj_kernel(
    const __half* __restrict__ agg_a, const __half* __restrict__ agg_t0, const __half* __restrict__ agg_t2,
    float* __restrict__ xa, float* __restrict__ xt,
    const float* __restrict__ ln_ag, const float* __restrict__ ln_ab,
    const float* __restrict__ ln_tg, const float* __restrict__ ln_tb,
    const float* __restrict__ scores, float invNT,
    const float* __restrict__ Wa, const float* __restrict__ Ba,
    const float* __restrict__ Wt, const float* __restrict__ Bt,
    const float* __restrict__ as0, const float* __restrict__ ad1,
    const float* __restrict__ as1, const float* __restrict__ ad0,
    const float* __restrict__ as2, const float* __restrict__ ad2,
    __half* __restrict__ h_a, __half* __restrict__ h_t,
    __half* __restrict__ o_as0, float* __restrict__ o_ad1,
    __half* __restrict__ o_as1, float* __restrict__ o_ad0,
    __half* __restrict__ o_as2, float* __restrict__ o_ad2,
    int NA_, int NT_, int nbAcp, int gpb, int lastProj) {
    __shared__ __align__(16) float lds_t[4][16][36];
    int tid = threadIdx.x;
    int wave = tid >> 6;
    int lane = tid & 63;
    int colid = lane & 15;
    int kgrp = lane >> 4;
    int fbase = kgrp * 8;

    bool isA = blockIdx.x < (unsigned)nbAcp;
    const float* W = isA ? Wa : Wt;
    const float* Bp = isA ? Ba : Bt;
    int n = isA ? NA_ : NT_;

    f16x8 bf0, bf1;
    #pragma unroll
    for (int j = 0; j < 8; j++) {
        bf0[j] = (_Float16)W[(fbase + j) * 32 + colid];
        bf1[j] = (_Float16)W[(fbase + j) * 32 + 16 + colid];
    }
    float bp0 = Bp[colid], bp1 = Bp[16 + colid];

    const float* lng = isA ? ln_ag : ln_tg;
    const float* lnb = isA ? ln_ab : ln_tb;
    float g[8], bb[8];
    #pragma unroll
    for (int j = 0; j < 8; j++) { g[j] = lng[fbase + j]; bb[j] = lnb[fbase + j]; }

    float va0[8], va1[8], va2[8], va3[8];
    if (isA) {
        #pragma unroll
        for (int j = 0; j < 8; j++) { va0[j] = as0[fbase + j]; va1[j] = ad1[fbase + j]; }
    } else {
        #pragma unroll
        for (int j = 0; j < 8; j++) {
            va0[j] = as1[fbase + j]; va1[j] = ad0[fbase + j];
            va2[j] = as2[fbase + j]; va3[j] = ad2[fbase + j];
        }
    }

    float wsem0 = 0.f, wsem2 = 0.f;
    if (!isA) {
        float s0 = scores[0] * invNT, s2 = scores[1] * invNT;
        float mx = fmaxf(s0, s2);
        float e0 = __expf(s0 - mx), e2 = __expf(s2 - mx);
        float inv_s = 1.f / (e0 + e2);
        wsem0 = e0 * inv_s; wsem2 = e2 * inv_s;
    }

    float (*tp)[36] = lds_t[wave];
    int blockBase = (isA ? (int)blockIdx.x : (int)blockIdx.x - nbAcp) * gpb * 64;
    for (int gi = 0; gi < gpb; gi++) {
        int node = blockBase + gi * 64 + wave * 16 + colid;
        bool valid = node < n;
        float v[8];
        if (valid) {
            size_t base = (size_t)node * 32 + fbase;
            float4 xlo, xhi;
            if (isA) {
                xlo = *(const float4*)(xa + base);
                xhi = *(const float4*)(xa + base + 4);
                float4 ar = *(const float4*)(agg_a + base);
                const __half2* ah2 = (const __half2*)&ar;
                float2 f0 = __half22float2(ah2[0]);
                float2 f1 = __half22float2(ah2[1]);
                float2 f2 = __half22float2(ah2[2]);
                float2 f3 = __half22float2(ah2[3]);
                float av[8] = {f0.x, f0.y, f1.x, f1.y, f2.x, f2.y, f3.x, f3.y};
                float xv[8] = {xlo.x, xlo.y, xlo.z, xlo.w, xhi.x, xhi.y, xhi.z, xhi.w};
                #pragma unroll
                for (int j = 0; j < 8; j++) v[j] = fmaxf(av[j], 0.f) + xv[j];
            } else {
                xlo = *(const float4*)(xt + base);
                xhi = *(const float4*)(xt + base + 4);
                float4 a0r = *(const float4*)(agg_t0 + base);
                float4 a2r = *(const float4*)(agg_t2 + base);
                const __half2* a0h = (const __half2*)&a0r;
                const __half2* a2h = (const __half2*)&a2r;
                float xv[8] = {xlo.x, xlo.y, xlo.z, xlo.w, xhi.x, xhi.y, xhi.z, xhi.w};
                #pragma unroll
                for (int j = 0; j < 4; j++) {
                    float2 p0 = __half22float2(a0h[j]);
                    float2 p2 = __half22float2(a2h[j]);
                    float c0 = wsem0 * fmaxf(p0.x, 0.f) + wsem2 * fmaxf(p2.x, 0.f);
                    float c1 = wsem0 * fmaxf(p0.y, 0.f) + wsem2 * fmaxf(p2.y, 0.f);
                    v[2 * j]     = fmaxf(c0, 0.f) + xv[2 * j];
                    v[2 * j + 1] = fmaxf(c1, 0.f) + xv[2 * j + 1];
                }
            }
        } else {
            #pragma unroll
            for (int j = 0; j < 8; j++) v[j] = 0.f;
        }
        float s = 0.f;
        #pragma unroll
        for (int j = 0; j < 8; j++) s += v[j];
        s += __shfl_xor(s, 16, 64);
        s += __shfl_xor(s, 32, 64);
        float m = s * 0.03125f;
        float d[8], vv = 0.f;
        #pragma unroll
        for (int j = 0; j < 8; j++) { d[j] = v[j] - m; vv += d[j] * d[j]; }
        vv += __shfl_xor(vv, 16, 64);
        vv += __shfl_xor(vv, 32, 64);
        float inv = 1.f / sqrtf(vv * 0.03125f + 1e-5f);
        float ln[8];
        #pragma unroll
        for (int j = 0; j < 8; j++) ln[j] = d[j] * inv * g[j] + bb[j];

        if (valid && (isA || !lastProj)) {
            float* xp = isA ? xa : xt;
            size_t base = (size_t)node * 32 + fbase;
            *(float4*)(xp + base)     = make_float4(ln[0], ln[1], ln[2], ln[3]);
            *(float4*)(xp + base + 4) = make_float4(ln[4], ln[5], ln[6], ln[7]);
        }

        f16x8 af;
        #pragma unroll
        for (int j = 0; j < 8; j++) af[j] = (_Float16)ln[j];
        f32x4 c0 = {0.f, 0.f, 0.f, 0.f};
        f32x4 c1 = {0.f, 0.f, 0.f, 0.f};
        c0 = __builtin_amdgcn_mfma_f32_16x16x32_f16(af, bf0, c0, 0, 0, 0);
        c1 = __builtin_amdgcn_mfma_f32_16x16x32_f16(af, bf1, c1, 0, 0, 0);
        #pragma unroll
        for (int r = 0; r < 4; r++) { c0[r] += bp0; c1[r] += bp1; }

        #pragma unroll
        for (int r = 0; r < 4; r++) {
            int row = kgrp * 4 + r;
            tp[row][colid] = c0[r];
            tp[row][16 + colid] = c1[r];
        }
        float4 hlo = *(const float4*)&tp[colid][fbase];
        float4 hhi = *(const float4*)&tp[colid][fbase + 4];
        float hv[8] = {hlo.x, hlo.y, hlo.z, hlo.w, hhi.x, hhi.y, hhi.z, hhi.w};

        bool writeH = (!isA || !lastProj);
        if (valid && writeH) {
            float4 hout;
            __half2* hp2 = (__half2*)&hout;
            hp2[0] = __floats2half2_rn(hv[0], hv[1]);
            hp2[1] = __floats2half2_rn(hv[2], hv[3]);
            hp2[2] = __floats2half2_rn(hv[4], hv[5]);
            hp2[3] = __floats2half2_rn(hv[6], hv[7]);
            __half* hp = isA ? h_a : h_t;
            *(float4*)(hp + (size_t)node * 32 + fbase) = hout;
        }

        if (valid) {
            size_t oidx = (size_t)node * 4 + kgrp;
            if (isA) {
                if (!lastProj) {
                    float ds = 0.f;
                    #pragma unroll
                    for (int j = 0; j < 8; j++) ds += hv[j] * va0[j];
                    o_as0[oidx] = __float2half(ds);
                }
                float dd = 0.f;
                #pragma unroll
                for (int j = 0; j < 8; j++) dd += hv[j] * va1[j];
                o_ad1[oidx] = dd;
            } else {
                float d0 = 0.f;
                #pragma unroll
                for (int j = 0; j < 8; j++) d0 += hv[j] * va0[j];
                o_as1[oidx] = __float2half(d0);
                if (!lastProj) {
                    float d1 = 0.f, d2 = 0.f, d3 = 0.f;
                    #pragma unroll
                    for (int j = 0; j < 8; j++) {
                        d1 += hv[j] * va1[j];
                        d2 += hv[j] * va2[j];
                        d3 += hv[j] * va3[j];
                    }
                    o_ad0[oidx] = d1;
                    o_as2[oidx] = __float2half(d2);
                    o_ad2[oidx] = d3;
                }
            }
        }
    }
}

// ================= layer-3 combine_addr + output head =================
__global__ void combine_final_kernel(const __half* __restrict__ agg_a, const float* __restrict__ xa,
                                     const float* __restrict__ g, const float* __restrict__ bt,
                                     const float* __restrict__ lw, const float* __restrict__ lb,
                                     float* __restrict__ out, int n) {
    int tid = threadIdx.x;
    int local = tid >> 5, f = tid & 31;
    int node = blockIdx.x * 8 + local;
    if (node >= n) return;
    float a = __half2float(agg_a[(size_t)node * 32 + f]);
    float v = fmaxf(a, 0.f) + xa[(size_t)node * 32 + f];
    float m = v;
    #pragma unroll
    for (int mask = 1; mask < 32; mask <<= 1) m += __shfl_xor(m, mask, 64);
    m *= (1.f / 32.f);
    float d = v - m;
    float var = d * d;
    #pragma unroll
    for (int mask = 1; mask < 32; mask <<= 1) var += __shfl_xor(var, mask, 64);
    var *= (1.f / 32.f);
    float inv = 1.f / sqrtf(var + 1e-5f);
    float ln = d * inv * g[f] + bt[f];
    float p0 = ln * lw[f * 2 + 0];
    float p1 = ln * lw[f * 2 + 1];
    #pragma unroll
    for (int mask = 1; mask < 32; mask <<= 1) {
        p0 += __shfl_xor(p0, mask, 64);
        p1 += __shfl_xor(p1, mask, 64);
    }
    if (f == 0) {
        out[(size_t)node * 2 + 0] = p0 + lb[0];
        out[(size_t)node * 2 + 1] = p1 + lb[1];
    }
}

extern "C" void kernel_launch(void* const* d_in, const int* in_sizes, int n_in,
                              void* d_out, int out_size, void* d_ws, size_t ws_size,
                              hipStream_t stream) {
    const float* x_addr = (const float*)d_in[0];
    const float* x_tx   = (const float*)d_in[1];
    const int* ei_in    = (const int*)d_in[2];
    const int* ei_out   = (const int*)d_in[3];
    const int* ei_sp    = (const int*)d_in[4];
    const float* enc_w_addr = (const float*)d_in[5];
    const float* enc_b_addr = (const float*)d_in[6];
    const float* enc_w_tx   = (const float*)d_in[7];
    const float* enc_b_tx   = (const float*)d_in[8];
    const float* ln_ag = (const float*)d_in[9];
    const float* ln_ab = (const float*)d_in[10];
    const float* ln_tg = (const float*)d_in[11];
    const float* ln_tb = (const float*)d_in[12];
    const float* pw_a = (const float*)d_in[13];
    const float* pb_a = (const float*)d_in[14];
    const float* pw_t = (const float*)d_in[15];
    const float* pb_t = (const float*)d_in[16];
    const float* att_src = (const float*)d_in[17];
    const float* att_dst = (const float*)d_in[18];
    const float* klw = (const float*)d_in[19];
    const float* klb = (const float*)d_in[20];
    const float* qv  = (const float*)d_in[21];
    const float* lin_w = (const float*)d_in[22];
    const float* lin_b = (const float*)d_in[23];
    float* out = (float*)d_out;

    const int NA = in_sizes[0] / 53;
    const int NT = in_sizes[1] / 6;
    const int E_IN = in_sizes[2] / 2;
    const int E_OUT = in_sizes[3] / 2;
    const int E_SP = in_sizes[4] / 2;
    const int E_TOT = E_IN + E_OUT + E_SP;
    const int NCAT = NT + NA + NT;
    const int NBUCK = (NCAT + (1 << BSHIFT) - 1) >> BSHIFT;

    size_t off = 0;
    float* base = (float*)d_ws;
    auto alloc = [&](size_t nfloats) {
        float* p = base + off;
        off += (nfloats + 63) & ~(size_t)63;
        return p;
    };
    float* xa      = alloc((size_t)NA * 32);
    float* xt      = alloc((size_t)NT * 32);
    float* agg_a_f = alloc((size_t)NA * 16);
    float* agg_t0f = alloc((size_t)NT * 16);
    float* agg_t2f = alloc((size_t)NT * 16);
    float* h_t_f   = alloc((size_t)NT * 16);
    float* asrc0a  = alloc((size_t)NA * 2);   // fp16 x4 per node
    float* adst1a  = alloc((size_t)NA * 4);
    float* asrc1t  = alloc((size_t)NT * 2);   // fp16
    float* adst0t  = alloc((size_t)NT * 4);
    float* asrc2t  = alloc((size_t)NT * 2);   // fp16
    float* adst2t  = alloc((size_t)NT * 4);
    int* rowptrAll = (int*)alloc((size_t)NCAT + 64);
    int* colAll    = (int*)alloc((size_t)E_TOT);
    // legacy: tmp+bsum+scores+bcur zeroed together; bucket: scores+bcur only
    size_t tmp_span = (((size_t)NCAT + 63) & ~(size_t)63) + 1088 + 64 + 1024;
    int* tmp       = (int*)alloc((size_t)NCAT);
    int* bsum      = (int*)alloc(1088);
    float* scores  = alloc(64);
    int* bcur      = (int*)alloc(1024);
    int* boff      = (int*)alloc(1088);

    size_t ha_floats = (((size_t)NA * 16) + 63) & ~(size_t)63;
    bool roomy = ((off + ha_floats) * sizeof(float)) <= ws_size;
    float* h_a_f = roomy ? alloc((size_t)NA * 16) : agg_a_f;

    // bucketed edge pair buffer: fixed-capacity regions, cap = 1.25*avg + 256 (rounded to 256)
    int avgb = (int)(((long)E_TOT << BSHIFT) / (long)NCAT);
    int cap = ((avgb + avgb / 4 + 256) + 255) & ~255;
    size_t ebuf_floats = (size_t)NBUCK * (size_t)cap * 2;
    bool canBucket = (NBUCK <= 1024) &&
                     (((off + ebuf_floats + 64) * sizeof(float)) <= ws_size);
    uint2* ebuf = canBucket ? (uint2*)alloc(ebuf_floats) : nullptr;

    __half* agg_a  = (__half*)agg_a_f;
    __half* agg_t0 = (__half*)agg_t0f;
    __half* agg_t2 = (__half*)agg_t2f;
    __half* h_t    = (__half*)h_t_f;
    __half* h_a    = (__half*)h_a_f;
    __half* has0   = (__half*)asrc0a;
    __half* has1   = (__half*)asrc1t;
    __half* has2   = (__half*)asrc2t;

    dim3 blk(256);
    const int GPB_E = 4;    // encproj: 64 nodes per g-iter, 256 nodes/block
    const int GPB_C = 4;    // combineproj: 64 nodes per g-iter, 256 nodes/block
    int nbA8 = (NA + 7) / 8;
    int nbAe = (NA + 64 * GPB_E - 1) / (64 * GPB_E);
    int nbTe = (NT + 64 * GPB_E - 1) / (64 * GPB_E);
    int nbAcp = (NA + 64 * GPB_C - 1) / (64 * GPB_C);
    int nbTcp = (NT + 64 * GPB_C - 1) / (64 * GPB_C);
    int nbTs  = (NT + 64 * SGPB - 1) / (64 * SGPB);
    int nbE = (E_TOT + 255) / 256;
    int nbScan = (NCAT + 1023) / 1024;

    // ---- CSR build (once, reused by all layers) ----
    if (canBucket) {
        int nbChunk = (E_TOT + CHUNK - 1) / CHUNK;
        zero_int_kernel<<<8, blk, 0, stream>>>((int*)scores, 64 + 1024);
        bucket_scatter_kernel<<<nbChunk, blk, 0, stream>>>(
            ei_in, ei_out, ei_sp, E_IN, E_OUT, E_SP, NT, NA, bcur, ebuf, E_TOT, NBUCK, cap);
        scanb_kernel<<<1, 1024, 0, stream>>>(bcur, boff, rowptrAll, NBUCK, cap, NCAT);
        bucket_csr_kernel<<<NBUCK, blk, 0, stream>>>(ebuf, boff, rowptrAll, colAll, NCAT, cap);
    } else {
        zero_int_kernel<<<2048, blk, 0, stream>>>(tmp, (long)tmp_span);
        hist_kernel<<<nbE, blk, 0, stream>>>(ei_in, ei_out, ei_sp, E_IN, E_OUT, E_SP, NT, NA, tmp, E_TOT);
        scan1_kernel<<<nbScan, blk, 0, stream>>>(tmp, rowptrAll, bsum, NCAT);
        scan2_kernel<<<1, 1024, 0, stream>>>(bsum, nbScan);
        scan3_kernel<<<(NCAT + 255) / 256, blk, 0, stream>>>(rowptrAll, bsum, tmp, NCAT, E_TOT);
        scatter_kernel<<<nbE, blk, 0, stream>>>(ei_in, ei_out, ei_sp, E_IN, E_OUT, E_SP, NT, NA, tmp, colAll, E_TOT);
    }

    // ---- fused encoder + layer-0 projection ----
    encproj_addr_kernel<<<nbAe, blk, 0, stream>>>(
        x_addr, enc_w_addr, enc_b_addr, pw_a, pb_a,
        att_src + 0 * 32, att_dst + 1 * 32,
        xa, h_a, has0, adst1a, NA, GPB_E);
    encproj_tx_kernel<<<nbTe, blk, 0, stream>>>(
        x_tx, enc_w_tx, enc_b_tx, pw_t, pb_t,
        att_src + 1 * 32, att_dst + 0 * 32, att_src + 2 * 32, att_dst + 2 * 32,
        xt, h_t, has1, adst0t, has2, adst2t, NT, GPB_E);

    auto agg_launch = [&](int mode, int nRows) {
        int blocks = (nRows + 31) / 32;
        if (blocks > 2048) blocks = 2048;
        agg_all_kernel<<<blocks, blk, 0, stream>>>(
            rowptrAll, colAll, h_a, h_t,
            has0, adst0t, has1, adst1a, has2, adst2t,
            agg_t0, agg_a, agg_t2, NT, NA, mode, nRows);
    };

    for (int l = 0; l < NLAYERS; l++) {
        bool last = (l == NLAYERS - 1);
        const float* kw = klw + l * 1024;
        const float* kb = klb + l * 32;
        const float* q  = qv + l * 32;
        float* sc = scores + 2 * l;
        if (!last) {
            if (roomy) {
                agg_launch(0, NCAT);
            } else {
                agg_launch(1, 2 * NT);
                agg_launch(2, NA);
            }
            score_tx_kernel<<<nbTs, blk, 0, stream>>>(agg_t0, agg_t2, kw, kb, q, sc, NT);
            int lp = l + 1;
            combineproj_kernel<<<nbAcp + nbTcp, blk, 0, stream>>>(
                agg_a, agg_t0, agg_t2, xa, xt,
                ln_ag, ln_ab, ln_tg, ln_tb,
                sc, 1.0f / (float)NT,
                pw_a + lp * 1024, pb_a + lp * 32, pw_t + lp * 1024, pb_t + lp * 32,
                att_src + (lp * 3 + 0) * 32, att_dst + (lp * 3 + 1) * 32,
                att_src + (lp * 3 + 1) * 32, att_dst + (lp * 3 + 0) * 32,
                att_src + (lp * 3 + 2) * 32, att_dst + (lp * 3 + 2) * 32,
                h_a, h_t,
                has0, adst1a, has1, adst0t, has2, adst2t,
                NA, NT, nbAcp, GPB_C, lp == 3 ? 1 : 0);
        } else {
            agg_launch(2, NA);
            combine_final_kernel<<<nbA8, blk, 0, stream>>>(agg_a, xa, ln_ag, ln_ab,
                                                           lin_w, lin_b, out, NA);
        }
    }
}

// Round 9
// 750.993 us; speedup vs baseline: 1.1019x; 1.1019x over previous
//
#include <hip/hip_runtime.h>
#include <hip/hip_fp16.h>

#define NLAYERS 4
#define BSHIFT 10   // 1024 rows per bucket
#define CHUNK 4096  // edges per bucket_scatter block (16/thread, register-staged)

typedef _Float16 f16x8 __attribute__((ext_vector_type(8)));
typedef float f32x4 __attribute__((ext_vector_type(4)));

// ---------------- zero fill ----------------
__global__ void zero_int_kernel(int* __restrict__ p, long n) {
    long i = (long)blockIdx.x * 256 + threadIdx.x;
    long stride = (long)gridDim.x * 256;
    for (; i < n; i += stride) p[i] = 0;
}

__device__ __forceinline__ float fast_tanh(float y) {
    y = fminf(fmaxf(y, -15.f), 15.f);
    float t = __expf(2.f * y);
    return (t - 1.f) / (t + 1.f);
}

// ================= CSR build over concatenated dst space =================
// [0,NT) rel0 dsts | [NT,NT+NA) rel1 dsts | [NT+NA,NCAT) rel2 dsts
__device__ __forceinline__ int edge_row(const int* ei_in, const int* ei_out, const int* ei_sp,
                                        int E_IN, int E_OUT, int E_SP, int NT, int NA,
                                        int e, int* src) {
    if (e < E_IN) { *src = ei_in[e]; return ei_in[E_IN + e]; }
    if (e < E_IN + E_OUT) { int i = e - E_IN; *src = ei_out[i]; return NT + ei_out[E_OUT + i]; }
    int i = e - E_IN - E_OUT; *src = ei_sp[i]; return NT + NA + ei_sp[E_SP + i];
}

// legacy direct hist/scatter (fallback when no workspace room for bucket buffer)
__global__ void hist_kernel(const int* __restrict__ ei_in, const int* __restrict__ ei_out,
                            const int* __restrict__ ei_sp, int E_IN, int E_OUT, int E_SP,
                            int NT, int NA, int* __restrict__ deg, int E_TOT) {
    int e = blockIdx.x * 256 + threadIdx.x;
    if (e >= E_TOT) return;
    int s;
    int row = edge_row(ei_in, ei_out, ei_sp, E_IN, E_OUT, E_SP, NT, NA, e, &s);
    atomicAdd(&deg[row], 1);
}

__global__ void scatter_kernel(const int* __restrict__ ei_in, const int* __restrict__ ei_out,
                               const int* __restrict__ ei_sp, int E_IN, int E_OUT, int E_SP,
                               int NT, int NA, int* __restrict__ cursor, int* __restrict__ col,
                               int E_TOT) {
    int e = blockIdx.x * 256 + threadIdx.x;
    if (e >= E_TOT) return;
    int s;
    int row = edge_row(ei_in, ei_out, ei_sp, E_IN, E_OUT, E_SP, NT, NA, e, &s);
    int pos = atomicAdd(&cursor[row], 1);
    col[pos] = s;
}

__global__ void scan1_kernel(const int* __restrict__ deg, int* __restrict__ rowptr,
                             int* __restrict__ bsum, int n) {
    __shared__ int lds[256];
    int tid = threadIdx.x;
    int base = blockIdx.x * 1024;
    int v[4];
    int mysum = 0;
    #pragma unroll
    for (int j = 0; j < 4; j++) {
        int idx = base + tid * 4 + j;
        v[j] = (idx < n) ? deg[idx] : 0;
        mysum += v[j];
    }
    lds[tid] = mysum;
    __syncthreads();
    for (int off = 1; off < 256; off <<= 1) {
        int t = (tid >= off) ? lds[tid - off] : 0;
        __syncthreads();
        lds[tid] += t;
        __syncthreads();
    }
    int excl = lds[tid] - mysum;
    if (tid == 255) bsum[blockIdx.x] = lds[tid];
    int run = excl;
    #pragma unroll
    for (int j = 0; j < 4; j++) {
        int idx = base + tid * 4 + j;
        if (idx < n) rowptr[idx] = run;
        run += v[j];
    }
}

__global__ void scan2_kernel(int* __restrict__ bsum, int nb) {
    __shared__ int lds[1024];
    int tid = threadIdx.x;
    int v = (tid < nb) ? bsum[tid] : 0;
    lds[tid] = v;
    __syncthreads();
    for (int off = 1; off < 1024; off <<= 1) {
        int t = (tid >= off) ? lds[tid - off] : 0;
        __syncthreads();
        lds[tid] += t;
        __syncthreads();
    }
    if (tid < nb) bsum[tid] = lds[tid] - v;
}

__global__ void scan3_kernel(int* __restrict__ rowptr, const int* __restrict__ bsum,
                             int* __restrict__ cursor, int n, int E) {
    int i = blockIdx.x * 256 + threadIdx.x;
    if (i < n) {
        int r = rowptr[i] + bsum[i >> 10];
        rowptr[i] = r;
        cursor[i] = r;
    }
    if (i == 0) rowptr[n] = E;
}

// ---- bucketed CSR build, pass 1: single global read; edges register-staged ----
__global__ void __launch_bounds__(256) bucket_scatter_kernel(
    const int* __restrict__ ei_in, const int* __restrict__ ei_out,
    const int* __restrict__ ei_sp, int E_IN, int E_OUT, int E_SP,
    int NT, int NA, int* __restrict__ bcur,
    uint2* __restrict__ ebuf, int E_TOT, int nbuck, int cap) {
    __shared__ int lc[1024], lbase[1024], lcur[1024];
    int tid = threadIdx.x;
    int chunk0 = blockIdx.x * CHUNK;
    int chunkN = E_TOT - chunk0;
    if (chunkN > CHUNK) chunkN = CHUNK;
    if (chunkN <= 0) return;
    for (int i = tid; i < nbuck; i += 256) { lc[i] = 0; lcur[i] = 0; }
    __syncthreads();
    uint2 er[CHUNK / 256];
    #pragma unroll
    for (int j = 0; j < CHUNK / 256; j++) {
        int i = tid + j * 256;   // coalesced within each sub-pass
        if (i < chunkN) {
            int s;
            int row = edge_row(ei_in, ei_out, ei_sp, E_IN, E_OUT, E_SP, NT, NA, chunk0 + i, &s);
            er[j] = make_uint2((unsigned)row, (unsigned)s);
            atomicAdd(&lc[row >> BSHIFT], 1);
        } else {
            er[j].x = 0xFFFFFFFFu;
        }
    }
    __syncthreads();
    for (int i = tid; i < nbuck; i += 256) if (lc[i]) lbase[i] = atomicAdd(&bcur[i], lc[i]);
    __syncthreads();
    #pragma unroll
    for (int j = 0; j < CHUNK / 256; j++) {
        if (er[j].x != 0xFFFFFFFFu) {
            int b = (int)(er[j].x >> BSHIFT);
            int pos = lbase[b] + atomicAdd(&lcur[b], 1);
            if (pos < cap) ebuf[(size_t)b * cap + pos] = er[j];
        }
    }
}

// ---- pass 2: exclusive scan of bucket counts -> global col offsets ----
__global__ void scanb_kernel(const int* __restrict__ bcur, int* __restrict__ boff,
                             int* __restrict__ rowptr, int nbuck, int cap, int NCAT) {
    __shared__ int lds[1024];
    int tid = threadIdx.x;
    int v = 0;
    if (tid < nbuck) { v = bcur[tid]; if (v > cap) v = cap; }
    lds[tid] = v;
    __syncthreads();
    for (int off = 1; off < 1024; off <<= 1) {
        int t = (tid >= off) ? lds[tid - off] : 0;
        __syncthreads();
        lds[tid] += t;
        __syncthreads();
    }
    if (tid < nbuck) boff[tid] = lds[tid] - v;
    if (tid == 1023) {
        boff[nbuck] = lds[1023];
        rowptr[NCAT] = lds[1023];
    }
}

// ---- pass 3: one block per bucket; LDS hist + LDS scan + LDS-cursor scatter ----
__global__ void __launch_bounds__(256) bucket_csr_kernel(
    const uint2* __restrict__ ebuf, const int* __restrict__ boff,
    int* __restrict__ rowptr, int* __restrict__ col, int NCAT, int cap) {
    __shared__ int ldeg[1024];
    __shared__ int lsum[256];
    int tid = threadIdx.x;
    int b = blockIdx.x;
    int row0 = b << BSHIFT;
    int e0 = boff[b], e1 = boff[b + 1];
    int cnt = e1 - e0;
    const uint2* src = ebuf + (size_t)b * cap;
    for (int i = tid; i < 1024; i += 256) ldeg[i] = 0;
    __syncthreads();
    for (int i = tid; i < cnt; i += 256)
        atomicAdd(&ldeg[src[i].x - (unsigned)row0], 1);
    __syncthreads();
    int bidx = tid * 4;
    int v0 = ldeg[bidx], v1 = ldeg[bidx + 1], v2 = ldeg[bidx + 2], v3 = ldeg[bidx + 3];
    int mysum = v0 + v1 + v2 + v3;
    lsum[tid] = mysum;
    __syncthreads();
    for (int off = 1; off < 256; off <<= 1) {
        int t = (tid >= off) ? lsum[tid - off] : 0;
        __syncthreads();
        lsum[tid] += t;
        __syncthreads();
    }
    int run = e0 + lsum[tid] - mysum;
    int vv[4] = {v0, v1, v2, v3};
    #pragma unroll
    for (int j = 0; j < 4; j++) {
        int r = bidx + j;
        if (row0 + r < NCAT) rowptr[row0 + r] = run;
        ldeg[r] = run;          // becomes the cursor
        run += vv[j];
    }
    __syncthreads();
    for (int i = tid; i < cnt; i += 256) {
        uint2 p = src[i];
        int pos = atomicAdd(&ldeg[p.x - (unsigned)row0], 1);
        col[pos] = (int)p.y;
    }
}

// ================= fused encoder + layer-0 projection (MFMA, 1 wave = 16 nodes) =================
__global__ void __launch_bounds__(256) encproj_addr_kernel(
    const float* __restrict__ x,
    const float* __restrict__ We, const float* __restrict__ be,
    const float* __restrict__ Wp, const float* __restrict__ bp,
    const float* __restrict__ a0, const float* __restrict__ a1,
    float* __restrict__ xa, __half* __restrict__ h,
    __half* __restrict__ o0, float* __restrict__ o1,
    int n, int gpb) {
    __shared__ __align__(16) float lds_t[4][16][36];
    __shared__ float sx[4][16 * 57];
    int tid = threadIdx.x;
    int wave = tid >> 6, lane = tid & 63;
    int colid = lane & 15, kgrp = lane >> 4;
    int fbase = kgrp * 8;

    f16x8 bE00, bE01, bE10, bE11;
    #pragma unroll
    for (int j = 0; j < 8; j++) {
        int k0 = fbase + j;
        int k1 = 32 + fbase + j;
        bE00[j] = (_Float16)We[k0 * 32 + colid];
        bE01[j] = (_Float16)We[k0 * 32 + 16 + colid];
        float w10 = (k1 < 53) ? We[k1 * 32 + colid] : 0.f;
        float w11 = (k1 < 53) ? We[k1 * 32 + 16 + colid] : 0.f;
        bE10[j] = (_Float16)w10;
        bE11[j] = (_Float16)w11;
    }
    float beC0 = be[colid], beC1 = be[16 + colid];

    f16x8 bP0, bP1;
    #pragma unroll
    for (int j = 0; j < 8; j++) {
        bP0[j] = (_Float16)Wp[(fbase + j) * 32 + colid];
        bP1[j] = (_Float16)Wp[(fbase + j) * 32 + 16 + colid];
    }
    float bpC0 = bp[colid], bpC1 = bp[16 + colid];

    float va0[8], va1[8];
    #pragma unroll
    for (int j = 0; j < 8; j++) { va0[j] = a0[fbase + j]; va1[j] = a1[fbase + j]; }

    float (*tp)[36] = lds_t[wave];
    float* sxw = sx[wave];
    int blockBase = blockIdx.x * gpb * 64;
    for (int gi = 0; gi < gpb; gi++) {
        int node0 = blockBase + gi * 64 + wave * 16;
        int node = node0 + colid;
        bool valid = node < n;
        int nn = n - node0;
        if (nn > 16) nn = 16;
        if (nn < 0) nn = 0;
        int elems = nn * 53;
        for (int i = lane; i < elems; i += 64) {
            int r = i / 53, c = i - r * 53;
            sxw[r * 57 + c] = x[(size_t)node0 * 53 + i];
        }
        f16x8 af0, af1;
        #pragma unroll
        for (int j = 0; j < 8; j++) {
            af0[j] = (_Float16)sxw[colid * 57 + fbase + j];
            int kk = 32 + fbase + j;
            float v1 = (kk < 53) ? sxw[colid * 57 + kk] : 0.f;
            af1[j] = (_Float16)v1;
        }
        f32x4 c0 = {0.f, 0.f, 0.f, 0.f};
        f32x4 c1 = {0.f, 0.f, 0.f, 0.f};
        c0 = __builtin_amdgcn_mfma_f32_16x16x32_f16(af0, bE00, c0, 0, 0, 0);
        c0 = __builtin_amdgcn_mfma_f32_16x16x32_f16(af1, bE10, c0, 0, 0, 0);
        c1 = __builtin_amdgcn_mfma_f32_16x16x32_f16(af0, bE01, c1, 0, 0, 0);
        c1 = __builtin_amdgcn_mfma_f32_16x16x32_f16(af1, bE11, c1, 0, 0, 0);
        #pragma unroll
        for (int r = 0; r < 4; r++) {
            c0[r] = fmaxf(c0[r] + beC0, 0.f);
            c1[r] = fmaxf(c1[r] + beC1, 0.f);
        }
        #pragma unroll
        for (int r = 0; r < 4; r++) {
            int row = kgrp * 4 + r;
            tp[row][colid] = c0[r];
            tp[row][16 + colid] = c1[r];
        }
        float4 xlo = *(const float4*)&tp[colid][fbase];
        float4 xhi = *(const float4*)&tp[colid][fbase + 4];
        float xe[8] = {xlo.x, xlo.y, xlo.z, xlo.w, xhi.x, xhi.y, xhi.z, xhi.w};
        if (valid) {
            size_t basep = (size_t)node * 32 + fbase;
            *(float4*)(xa + basep) = xlo;
            *(float4*)(xa + basep + 4) = xhi;
        }
        f16x8 af;
        #pragma unroll
        for (int j = 0; j < 8; j++) af[j] = (_Float16)xe[j];
        f32x4 p0 = {0.f, 0.f, 0.f, 0.f};
        f32x4 p1 = {0.f, 0.f, 0.f, 0.f};
        p0 = __builtin_amdgcn_mfma_f32_16x16x32_f16(af, bP0, p0, 0, 0, 0);
        p1 = __builtin_amdgcn_mfma_f32_16x16x32_f16(af, bP1, p1, 0, 0, 0);
        #pragma unroll
        for (int r = 0; r < 4; r++) { p0[r] += bpC0; p1[r] += bpC1; }
        #pragma unroll
        for (int r = 0; r < 4; r++) {
            int row = kgrp * 4 + r;
            tp[row][colid] = p0[r];
            tp[row][16 + colid] = p1[r];
        }
        float4 hlo = *(const float4*)&tp[colid][fbase];
        float4 hhi = *(const float4*)&tp[colid][fbase + 4];
        float hv[8] = {hlo.x, hlo.y, hlo.z, hlo.w, hhi.x, hhi.y, hhi.z, hhi.w};
        if (valid) {
            float4 hout;
            __half2* hp2 = (__half2*)&hout;
            hp2[0] = __floats2half2_rn(hv[0], hv[1]);
            hp2[1] = __floats2half2_rn(hv[2], hv[3]);
            hp2[2] = __floats2half2_rn(hv[4], hv[5]);
            hp2[3] = __floats2half2_rn(hv[6], hv[7]);
            *(float4*)(h + (size_t)node * 32 + fbase) = hout;
            float d0 = 0.f, d1 = 0.f;
            #pragma unroll
            for (int j = 0; j < 8; j++) {
                d0 += hv[j] * va0[j];
                d1 += hv[j] * va1[j];
            }
            size_t oidx = (size_t)node * 4 + kgrp;
            o0[oidx] = __float2half(d0);
            o1[oidx] = d1;
        }
    }
}

__global__ void __launch_bounds__(256) encproj_tx_kernel(
    const float* __restrict__ x,
    const float* __restrict__ We, const float* __restrict__ be,
    const float* __restrict__ Wp, const float* __restrict__ bp,
    const float* __restrict__ a0, const float* __restrict__ a1,
    const float* __restrict__ a2, const float* __restrict__ a3,
    float* __restrict__ xt, __half* __restrict__ h,
    __half* __restrict__ o0, float* __restrict__ o1,
    __half* __restrict__ o2, float* __restrict__ o3,
    int n, int gpb) {
    __shared__ __align__(16) float lds_t[4][16][36];
    int tid = threadIdx.x;
    int wave = tid >> 6, lane = tid & 63;
    int colid = lane & 15, kgrp = lane >> 4;
    int fbase = kgrp * 8;

    f16x8 bE0, bE1;
    #pragma unroll
    for (int j = 0; j < 8; j++) {
        int k = fbase + j;
        float w0 = (k < 6) ? We[k * 32 + colid] : 0.f;
        float w1 = (k < 6) ? We[k * 32 + 16 + colid] : 0.f;
        bE0[j] = (_Float16)w0;
        bE1[j] = (_Float16)w1;
    }
    float beC0 = be[colid], beC1 = be[16 + colid];

    f16x8 bP0, bP1;
    #pragma unroll
    for (int j = 0; j < 8; j++) {
        bP0[j] = (_Float16)Wp[(fbase + j) * 32 + colid];
        bP1[j] = (_Float16)Wp[(fbase + j) * 32 + 16 + colid];
    }
    float bpC0 = bp[colid], bpC1 = bp[16 + colid];

    float va0[8], va1[8], va2[8], va3[8];
    #pragma unroll
    for (int j = 0; j < 8; j++) {
        va0[j] = a0[fbase + j]; va1[j] = a1[fbase + j];
        va2[j] = a2[fbase + j]; va3[j] = a3[fbase + j];
    }

    float (*tp)[36] = lds_t[wave];
    int blockBase = blockIdx.x * gpb * 64;
    for (int gi = 0; gi < gpb; gi++) {
        int node = blockBase + gi * 64 + wave * 16 + colid;
        bool valid = node < n;
        f16x8 af0;
        #pragma unroll
        for (int j = 0; j < 8; j++) {
            int k = fbase + j;
            float xv = 0.f;
            if (k < 6 && valid) xv = x[(size_t)node * 6 + k];
            af0[j] = (_Float16)xv;
        }
        f32x4 c0 = {0.f, 0.f, 0.f, 0.f};
        f32x4 c1 = {0.f, 0.f, 0.f, 0.f};
        c0 = __builtin_amdgcn_mfma_f32_16x16x32_f16(af0, bE0, c0, 0, 0, 0);
        c1 = __builtin_amdgcn_mfma_f32_16x16x32_f16(af0, bE1, c1, 0, 0, 0);
        #pragma unroll
        for (int r = 0; r < 4; r++) {
            c0[r] = fmaxf(c0[r] + beC0, 0.f);
            c1[r] = fmaxf(c1[r] + beC1, 0.f);
        }
        #pragma unroll
        for (int r = 0; r < 4; r++) {
            int row = kgrp * 4 + r;
            tp[row][colid] = c0[r];
            tp[row][16 + colid] = c1[r];
        }
        float4 xlo = *(const float4*)&tp[colid][fbase];
        float4 xhi = *(const float4*)&tp[colid][fbase + 4];
        float xe[8] = {xlo.x, xlo.y, xlo.z, xlo.w, xhi.x, xhi.y, xhi.z, xhi.w};
        if (valid) {
            size_t basep = (size_t)node * 32 + fbase;
            *(float4*)(xt + basep) = xlo;
            *(float4*)(xt + basep + 4) = xhi;
        }
        f16x8 af;
        #pragma unroll
        for (int j = 0; j < 8; j++) af[j] = (_Float16)xe[j];
        f32x4 p0 = {0.f, 0.f, 0.f, 0.f};
        f32x4 p1 = {0.f, 0.f, 0.f, 0.f};
        p0 = __builtin_amdgcn_mfma_f32_16x16x32_f16(af, bP0, p0, 0, 0, 0);
        p1 = __builtin_amdgcn_mfma_f32_16x16x32_f16(af, bP1, p1, 0, 0, 0);
        #pragma unroll
        for (int r = 0; r < 4; r++) { p0[r] += bpC0; p1[r] += bpC1; }
        #pragma unroll
        for (int r = 0; r < 4; r++) {
            int row = kgrp * 4 + r;
            tp[row][colid] = p0[r];
            tp[row][16 + colid] = p1[r];
        }
        float4 hlo = *(const float4*)&tp[colid][fbase];
        float4 hhi = *(const float4*)&tp[colid][fbase + 4];
        float hv[8] = {hlo.x, hlo.y, hlo.z, hlo.w, hhi.x, hhi.y, hhi.z, hhi.w};
        if (valid) {
            float4 hout;
            __half2* hp2 = (__half2*)&hout;
            hp2[0] = __floats2half2_rn(hv[0], hv[1]);
            hp2[1] = __floats2half2_rn(hv[2], hv[3]);
            hp2[2] = __floats2half2_rn(hv[4], hv[5]);
            hp2[3] = __floats2half2_rn(hv[6], hv[7]);
            *(float4*)(h + (size_t)node * 32 + fbase) = hout;
            float d0 = 0.f, d1 = 0.f, d2 = 0.f, d3 = 0.f;
            #pragma unroll
            for (int j = 0; j < 8; j++) {
                d0 += hv[j] * va0[j];
                d1 += hv[j] * va1[j];
                d2 += hv[j] * va2[j];
                d3 += hv[j] * va3[j];
            }
            size_t oidx = (size_t)node * 4 + kgrp;
            o0[oidx] = __float2half(d0);
            o1[oidx] = d1;
            o2[oidx] = __float2half(d2);
            o3[oidx] = d3;
        }
    }
}

// ================= merged CSR aggregation (all rels) + fused semantic score =================
__global__ void agg_all_kernel(
    const int* __restrict__ rowptr, const int* __restrict__ col,
    const __half* __restrict__ h_a, const __half* __restrict__ h_t,
    const __half* __restrict__ asrc0, const float* __restrict__ adst0,
    const __half* __restrict__ asrc1, const float* __restrict__ adst1,
    const __half* __restrict__ asrc2, const float* __restrict__ adst2,
    __half* __restrict__ agg_t0, __half* __restrict__ agg_a, __half* __restrict__ agg_t2,
    const float* __restrict__ kw, const float* __restrict__ kb, const float* __restrict__ q,
    float* __restrict__ scoreOut, int NT, int NA, int mode, int nRows) {
    __shared__ float sW[1024];
    __shared__ float sb[32];
    __shared__ float sq[32];
    __shared__ float sScore[2];
    int tid = threadIdx.x;
    bool doScore = (mode != 2);
    if (doScore) {
        for (int i = tid; i < 1024; i += 256) sW[i] = kw[i];
        if (tid < 32) { sb[tid] = kb[tid]; sq[tid] = q[tid]; }
        if (tid < 2) sScore[tid] = 0.f;
        __syncthreads();
    }
    int lane = tid & 7;
    int head = lane >> 1;
    int f0 = lane * 4;
    long stride = (long)gridDim.x * 32;
    for (long gi = (long)blockIdx.x * 32 + (tid >> 3); gi < (long)nRows; gi += stride) {
        int row;
        if (mode == 0) row = (int)gi;
        else if (mode == 1) row = (gi < NT) ? (int)gi : (int)(gi + NA);
        else row = NT + (int)gi;
        int rel, dst;
        const __half* h; const __half* asrc; const float* adp; __half* agg;
        if (row < NT)           { rel = 0; dst = row;           h = h_a; asrc = asrc0; adp = adst0; agg = agg_t0; }
        else if (row < NT + NA) { rel = 1; dst = row - NT;      h = h_t; asrc = asrc1; adp = adst1; agg = agg_a; }
        else                    { rel = 2; dst = row - NT - NA; h = h_t; asrc = asrc2; adp = adst2; agg = agg_t2; }
        float ad = adp[dst * 4 + head];
        int e0 = rowptr[row], e1 = rowptr[row + 1];
        __half2 acc0 = __floats2half2_rn(0.f, 0.f);
        __half2 acc1 = acc0;
        float den = 0.f;
        for (int e = e0; e < e1; e += 4) {
            int s0 = col[e];
            int s1 = (e + 1 < e1) ? col[e + 1] : s0;
            int s2 = (e + 2 < e1) ? col[e + 2] : s0;
            int s3 = (e + 3 < e1) ? col[e + 3] : s0;
            float as0 = __half2float(asrc[s0 * 4 + head]);
            float as1 = __half2float(asrc[s1 * 4 + head]);
            float as2 = __half2float(asrc[s2 * 4 + head]);
            float as3 = __half2float(asrc[s3 * 4 + head]);
            float2 r0 = *(const float2*)(h + s0 * 32 + f0);
            float2 r1 = *(const float2*)(h + s1 * 32 + f0);
            float2 r2 = *(const float2*)(h + s2 * 32 + f0);
            float2 r3 = *(const float2*)(h + s3 * 32 + f0);
            float t0 = as0 + ad; t0 = t0 > 0.f ? t0 : 0.2f * t0;
            float t1 = as1 + ad; t1 = t1 > 0.f ? t1 : 0.2f * t1;
            float t2 = as2 + ad; t2 = t2 > 0.f ? t2 : 0.2f * t2;
            float t3 = as3 + ad; t3 = t3 > 0.f ? t3 : 0.2f * t3;
            float ex0 = __expf(t0);
            float ex1 = (e + 1 < e1) ? __expf(t1) : 0.f;
            float ex2 = (e + 2 < e1) ? __expf(t2) : 0.f;
            float ex3 = (e + 3 < e1) ? __expf(t3) : 0.f;
            den += (ex0 + ex1) + (ex2 + ex3);
            __half2 eh0 = __float2half2_rn(ex0), eh1 = __float2half2_rn(ex1);
            __half2 eh2 = __float2half2_rn(ex2), eh3 = __float2half2_rn(ex3);
            acc0 = __hfma2(eh0, *(__half2*)&r0.x, acc0);
            acc1 = __hfma2(eh0, *(__half2*)&r0.y, acc1);
            acc0 = __hfma2(eh1, *(__half2*)&r1.x, acc0);
            acc1 = __hfma2(eh1, *(__half2*)&r1.y, acc1);
            acc0 = __hfma2(eh2, *(__half2*)&r2.x, acc0);
            acc1 = __hfma2(eh2, *(__half2*)&r2.y, acc1);
            acc0 = __hfma2(eh3, *(__half2*)&r3.x, acc0);
            acc1 = __hfma2(eh3, *(__half2*)&r3.y, acc1);
        }
        float r = 1.f / (den + 1e-16f);
        float2 a0 = __half22float2(acc0), a1 = __half22float2(acc1);
        float v0 = a0.x * r, v1 = a0.y * r, v2 = a1.x * r, v3 = a1.y * r;
        float2 opack;
        __half2 o0 = __floats2half2_rn(v0, v1), o1 = __floats2half2_rn(v2, v3);
        opack.x = *(float*)&o0; opack.y = *(float*)&o1;
        *(float2*)(agg + dst * 32 + f0) = opack;
        if (doScore && rel != 1) {
            float rv0 = fmaxf(v0, 0.f), rv1 = fmaxf(v1, 0.f);
            float rv2 = fmaxf(v2, 0.f), rv3 = fmaxf(v3, 0.f);
            float y0 = sb[f0], y1 = sb[f0 + 1], y2 = sb[f0 + 2], y3 = sb[f0 + 3];
            #pragma unroll
            for (int g = 0; g < 8; g++) {
                float c0 = __shfl(rv0, g, 8);
                float c1 = __shfl(rv1, g, 8);
                float c2 = __shfl(rv2, g, 8);
                float c3 = __shfl(rv3, g, 8);
                int kb4 = g * 4;
                y0 += c0 * sW[(kb4 + 0) * 32 + f0] + c1 * sW[(kb4 + 1) * 32 + f0]
                    + c2 * sW[(kb4 + 2) * 32 + f0] + c3 * sW[(kb4 + 3) * 32 + f0];
                y1 += c0 * sW[(kb4 + 0) * 32 + f0 + 1] + c1 * sW[(kb4 + 1) * 32 + f0 + 1]
                    + c2 * sW[(kb4 + 2) * 32 + f0 + 1] + c3 * sW[(kb4 + 3) * 32 + f0 + 1];
                y2 += c0 * sW[(kb4 + 0) * 32 + f0 + 2] + c1 * sW[(kb4 + 1) * 32 + f0 + 2]
                    + c2 * sW[(kb4 + 2) * 32 + f0 + 2] + c3 * sW[(kb4 + 3) * 32 + f0 + 2];
                y3 += c0 * sW[(kb4 + 0) * 32 + f0 + 3] + c1 * sW[(kb4 + 1) * 32 + f0 + 3]
                    + c2 * sW[(kb4 + 2) * 32 + f0 + 3] + c3 * sW[(kb4 + 3) * 32 + f0 + 3];
            }
            float sacc = sq[f0] * fast_tanh(y0) + sq[f0 + 1] * fast_tanh(y1)
                       + sq[f0 + 2] * fast_tanh(y2) + sq[f0 + 3] * fast_tanh(y3);
            #pragma unroll
            for (int m = 1; m < 8; m <<= 1) sacc += __shfl_xor(sacc, m, 8);
            if (lane == 0) atomicAdd(&sScore[rel == 2 ? 1 : 0], sacc);
        }
    }
    if (doScore) {
        __syncthreads();
        if (tid < 2) unsafeAtomicAdd(scoreOut + tid, sScore[tid]);
    }
}

// ================= fused combine + next-layer projection (MFMA, 1 wave = 16 nodes) =================
__global__ void __launch_bounds__(256) combineproj_kernel(
    const __half* __restrict__ agg_a, const __half* __restrict__ agg_t0, const __half* __restrict__ agg_t2,
    float* __restrict__ xa, float* __restrict__ xt,
    const float* __restrict__ ln_ag, const float* __restrict__ ln_ab,
    const float* __restrict__ ln_tg, const float* __restrict__ ln_tb,
    const float* __restrict__ scores, float invNT,
    const float* __restrict__ Wa, const float* __restrict__ Ba,
    const float* __restrict__ Wt, const float* __restrict__ Bt,
    const float* __restrict__ as0, const float* __restrict__ ad1,
    const float* __restrict__ as1, const float* __restrict__ ad0,
    const float* __restrict__ as2, const float* __restrict__ ad2,
    __half* __restrict__ h_a, __half* __restrict__ h_t,
    __half* __restrict__ o_as0, float* __restrict__ o_ad1,
    __half* __restrict__ o_as1, float* __restrict__ o_ad0,
    __half* __restrict__ o_as2, float* __restrict__ o_ad2,
    int NA_, int NT_, int nbAcp, int gpb, int lastProj) {
    __shared__ __align__(16) float lds_t[4][16][36];
    int tid = threadIdx.x;
    int wave = tid >> 6;
    int lane = tid & 63;
    int colid = lane & 15;
    int kgrp = lane >> 4;
    int fbase = kgrp * 8;

    bool isA = blockIdx.x < (unsigned)nbAcp;
    const float* W = isA ? Wa : Wt;
    const float* Bp = isA ? Ba : Bt;
    int n = isA ? NA_ : NT_;

    f16x8 bf0, bf1;
    #pragma unroll
    for (int j = 0; j < 8; j++) {
        bf0[j] = (_Float16)W[(fbase + j) * 32 + colid];
        bf1[j] = (_Float16)W[(fbase + j) * 32 + 16 + colid];
    }
    float bp0 = Bp[colid], bp1 = Bp[16 + colid];

    const float* lng = isA ? ln_ag : ln_tg;
    const float* lnb = isA ? ln_ab : ln_tb;
    float g[8], bb[8];
    #pragma unroll
    for (int j = 0; j < 8; j++) { g[j] = lng[fbase + j]; bb[j] = lnb[fbase + j]; }

    float va0[8], va1[8], va2[8], va3[8];
    if (isA) {
        #pragma unroll
        for (int j = 0; j < 8; j++) { va0[j] = as0[fbase + j]; va1[j] = ad1[fbase + j]; }
    } else {
        #pragma unroll
        for (int j = 0; j < 8; j++) {
            va0[j] = as1[fbase + j]; va1[j] = ad0[fbase + j];
            va2[j] = as2[fbase + j]; va3[j] = ad2[fbase + j];
        }
    }

    float wsem0 = 0.f, wsem2 = 0.f;
    if (!isA) {
        float s0 = scores[0] * invNT, s2 = scores[1] * invNT;
        float mx = fmaxf(s0, s2);
        float e0 = __expf(s0 - mx), e2 = __expf(s2 - mx);
        float inv_s = 1.f / (e0 + e2);
        wsem0 = e0 * inv_s; wsem2 = e2 * inv_s;
    }

    float (*tp)[36] = lds_t[wave];
    int blockBase = (isA ? (int)blockIdx.x : (int)blockIdx.x - nbAcp) * gpb * 64;
    for (int gi = 0; gi < gpb; gi++) {
        int node = blockBase + gi * 64 + wave * 16 + colid;
        bool valid = node < n;
        float v[8];
        if (valid) {
            size_t base = (size_t)node * 32 + fbase;
            float4 xlo, xhi;
            if (isA) {
                xlo = *(const float4*)(xa + base);
                xhi = *(const float4*)(xa + base + 4);
                float4 ar = *(const float4*)(agg_a + base);
                const __half2* ah2 = (const __half2*)&ar;
                float2 f0 = __half22float2(ah2[0]);
                float2 f1 = __half22float2(ah2[1]);
                float2 f2 = __half22float2(ah2[2]);
                float2 f3 = __half22float2(ah2[3]);
                float av[8] = {f0.x, f0.y, f1.x, f1.y, f2.x, f2.y, f3.x, f3.y};
                float xv[8] = {xlo.x, xlo.y, xlo.z, xlo.w, xhi.x, xhi.y, xhi.z, xhi.w};
                #pragma unroll
                for (int j = 0; j < 8; j++) v[j] = fmaxf(av[j], 0.f) + xv[j];
            } else {
                xlo = *(const float4*)(xt + base);
                xhi = *(const float4*)(xt + base + 4);
                float4 a0r = *(const float4*)(agg_t0 + base);
                float4 a2r = *(const float4*)(agg_t2 + base);
                const __half2* a0h = (const __half2*)&a0r;
                const __half2* a2h = (const __half2*)&a2r;
                float xv[8] = {xlo.x, xlo.y, xlo.z, xlo.w, xhi.x, xhi.y, xhi.z, xhi.w};
                #pragma unroll
                for (int j = 0; j < 4; j++) {
                    float2 p0 = __half22float2(a0h[j]);
                    float2 p2 = __half22float2(a2h[j]);
                    float c0 = wsem0 * fmaxf(p0.x, 0.f) + wsem2 * fmaxf(p2.x, 0.f);
                    float c1 = wsem0 * fmaxf(p0.y, 0.f) + wsem2 * fmaxf(p2.y, 0.f);
                    v[2 * j]     = fmaxf(c0, 0.f) + xv[2 * j];
                    v[2 * j + 1] = fmaxf(c1, 0.f) + xv[2 * j + 1];
                }
            }
        } else {
            #pragma unroll
            for (int j = 0; j < 8; j++) v[j] = 0.f;
        }
        float s = 0.f;
        #pragma unroll
        for (int j = 0; j < 8; j++) s += v[j];
        s += __shfl_xor(s, 16, 64);
        s += __shfl_xor(s, 32, 64);
        float m = s * 0.03125f;
        float d[8], vv = 0.f;
        #pragma unroll
        for (int j = 0; j < 8; j++) { d[j] = v[j] - m; vv += d[j] * d[j]; }
        vv += __shfl_xor(vv, 16, 64);
        vv += __shfl_xor(vv, 32, 64);
        float inv = 1.f / sqrtf(vv * 0.03125f + 1e-5f);
        float ln[8];
        #pragma unroll
        for (int j = 0; j < 8; j++) ln[j] = d[j] * inv * g[j] + bb[j];

        if (valid && (isA || !lastProj)) {
            float* xp = isA ? xa : xt;
            size_t base = (size_t)node * 32 + fbase;
            *(float4*)(xp + base)     = make_float4(ln[0], ln[1], ln[2], ln[3]);
            *(float4*)(xp + base + 4) = make_float4(ln[4], ln[5], ln[6], ln[7]);
        }

        f16x8 af;
        #pragma unroll
        for (int j = 0; j < 8; j++) af[j] = (_Float16)ln[j];
        f32x4 c0 = {0.f, 0.f, 0.f, 0.f};
        f32x4 c1 = {0.f, 0.f, 0.f, 0.f};
        c0 = __builtin_amdgcn_mfma_f32_16x16x32_f16(af, bf0, c0, 0, 0, 0);
        c1 = __builtin_amdgcn_mfma_f32_16x16x32_f16(af, bf1, c1, 0, 0, 0);
        #pragma unroll
        for (int r = 0; r < 4; r++) { c0[r] += bp0; c1[r] += bp1; }

        #pragma unroll
        for (int r = 0; r < 4; r++) {
            int row = kgrp * 4 + r;
            tp[row][colid] = c0[r];
            tp[row][16 + colid] = c1[r];
        }
        float4 hlo = *(const float4*)&tp[colid][fbase];
        float4 hhi = *(const float4*)&tp[colid][fbase + 4];
        float hv[8] = {hlo.x, hlo.y, hlo.z, hlo.w, hhi.x, hhi.y, hhi.z, hhi.w};

        bool writeH = (!isA || !lastProj);
        if (valid && writeH) {
            float4 hout;
            __half2* hp2 = (__half2*)&hout;
            hp2[0] = __floats2half2_rn(hv[0], hv[1]);
            hp2[1] = __floats2half2_rn(hv[2], hv[3]);
            hp2[2] = __floats2half2_rn(hv[4], hv[5]);
            hp2[3] = __floats2half2_rn(hv[6], hv[7]);
            __half* hp = isA ? h_a : h_t;
            *(float4*)(hp + (size_t)node * 32 + fbase) = hout;
        }

        if (valid) {
            size_t oidx = (size_t)node * 4 + kgrp;
            if (isA) {
                if (!lastProj) {
                    float ds = 0.f;
                    #pragma unroll
                    for (int j = 0; j < 8; j++) ds += hv[j] * va0[j];
                    o_as0[oidx] = __float2half(ds);
                }
                float dd = 0.f;
                #pragma unroll
                for (int j = 0; j < 8; j++) dd += hv[j] * va1[j];
                o_ad1[oidx] = dd;
            } else {
                float d0 = 0.f;
                #pragma unroll
                for (int j = 0; j < 8; j++) d0 += hv[j] * va0[j];
                o_as1[oidx] = __float2half(d0);
                if (!lastProj) {
                    float d1 = 0.f, d2 = 0.f, d3 = 0.f;
                    #pragma unroll
                    for (int j = 0; j < 8; j++) {
                        d1 += hv[j] * va1[j];
                        d2 += hv[j] * va2[j];
                        d3 += hv[j] * va3[j];
                    }
                    o_ad0[oidx] = d1;
                    o_as2[oidx] = __float2half(d2);
                    o_ad2[oidx] = d3;
                }
            }
        }
    }
}

// ================= layer-3 combine_addr + output head =================
__global__ void combine_final_kernel(const __half* __restrict__ agg_a, const float* __restrict__ xa,
                                     const float* __restrict__ g, const float* __restrict__ bt,
                                     const float* __restrict__ lw, const float* __restrict__ lb,
                                     float* __restrict__ out, int n) {
    int tid = threadIdx.x;
    int local = tid >> 5, f = tid & 31;
    int node = blockIdx.x * 8 + local;
    if (node >= n) return;
    float a = __half2float(agg_a[(size_t)node * 32 + f]);
    float v = fmaxf(a, 0.f) + xa[(size_t)node * 32 + f];
    float m = v;
    #pragma unroll
    for (int mask = 1; mask < 32; mask <<= 1) m += __shfl_xor(m, mask, 64);
    m *= (1.f / 32.f);
    float d = v - m;
    float var = d * d;
    #pragma unroll
    for (int mask = 1; mask < 32; mask <<= 1) var += __shfl_xor(var, mask, 64);
    var *= (1.f / 32.f);
    float inv = 1.f / sqrtf(var + 1e-5f);
    float ln = d * inv * g[f] + bt[f];
    float p0 = ln * lw[f * 2 + 0];
    float p1 = ln * lw[f * 2 + 1];
    #pragma unroll
    for (int mask = 1; mask < 32; mask <<= 1) {
        p0 += __shfl_xor(p0, mask, 64);
        p1 += __shfl_xor(p1, mask, 64);
    }
    if (f == 0) {
        out[(size_t)node * 2 + 0] = p0 + lb[0];
        out[(size_t)node * 2 + 1] = p1 + lb[1];
    }
}

extern "C" void kernel_launch(void* const* d_in, const int* in_sizes, int n_in,
                              void* d_out, int out_size, void* d_ws, size_t ws_size,
                              hipStream_t stream) {
    const float* x_addr = (const float*)d_in[0];
    const float* x_tx   = (const float*)d_in[1];
    const int* ei_in    = (const int*)d_in[2];
    const int* ei_out   = (const int*)d_in[3];
    const int* ei_sp    = (const int*)d_in[4];
    const float* enc_w_addr = (const float*)d_in[5];
    const float* enc_b_addr = (const float*)d_in[6];
    const float* enc_w_tx   = (const float*)d_in[7];
    const float* enc_b_tx   = (const float*)d_in[8];
    const float* ln_ag = (const float*)d_in[9];
    const float* ln_ab = (const float*)d_in[10];
    const float* ln_tg = (const float*)d_in[11];
    const float* ln_tb = (const float*)d_in[12];
    const float* pw_a = (const float*)d_in[13];
    const float* pb_a = (const float*)d_in[14];
    const float* pw_t = (const float*)d_in[15];
    const float* pb_t = (const float*)d_in[16];
    const float* att_src = (const float*)d_in[17];
    const float* att_dst = (const float*)d_in[18];
    const float* klw = (const float*)d_in[19];
    const float* klb = (const float*)d_in[20];
    const float* qv  = (const float*)d_in[21];
    const float* lin_w = (const float*)d_in[22];
    const float* lin_b = (const float*)d_in[23];
    float* out = (float*)d_out;

    const int NA = in_sizes[0] / 53;
    const int NT = in_sizes[1] / 6;
    const int E_IN = in_sizes[2] / 2;
    const int E_OUT = in_sizes[3] / 2;
    const int E_SP = in_sizes[4] / 2;
    const int E_TOT = E_IN + E_OUT + E_SP;
    const int NCAT = NT + NA + NT;
    const int NBUCK = (NCAT + (1 << BSHIFT) - 1) >> BSHIFT;

    size_t off = 0;
    float* base = (float*)d_ws;
    auto alloc = [&](size_t nfloats) {
        float* p = base + off;
        off += (nfloats + 63) & ~(size_t)63;
        return p;
    };
    float* xa      = alloc((size_t)NA * 32);
    float* xt      = alloc((size_t)NT * 32);
    float* agg_a_f = alloc((size_t)NA * 16);
    float* agg_t0f = alloc((size_t)NT * 16);
    float* agg_t2f = alloc((size_t)NT * 16);
    float* h_t_f   = alloc((size_t)NT * 16);
    float* asrc0a  = alloc((size_t)NA * 2);   // fp16 x4 per node
    float* adst1a  = alloc((size_t)NA * 4);
    float* asrc1t  = alloc((size_t)NT * 2);   // fp16
    float* adst0t  = alloc((size_t)NT * 4);
    float* asrc2t  = alloc((size_t)NT * 2);   // fp16
    float* adst2t  = alloc((size_t)NT * 4);
    int* rowptrAll = (int*)alloc((size_t)NCAT + 64);
    int* colAll    = (int*)alloc((size_t)E_TOT);
    // legacy: tmp+bsum+scores+bcur zeroed together; bucket: scores+bcur only
    size_t tmp_span = (((size_t)NCAT + 63) & ~(size_t)63) + 1088 + 64 + 1024;
    int* tmp       = (int*)alloc((size_t)NCAT);
    int* bsum      = (int*)alloc(1088);
    float* scores  = alloc(64);
    int* bcur      = (int*)alloc(1024);
    int* boff      = (int*)alloc(1088);

    size_t ha_floats = (((size_t)NA * 16) + 63) & ~(size_t)63;
    bool roomy = ((off + ha_floats) * sizeof(float)) <= ws_size;
    float* h_a_f = roomy ? alloc((size_t)NA * 16) : agg_a_f;

    // bucketed edge pair buffer: fixed-capacity regions, cap = 1.25*avg + 256 (rounded to 256)
    int avgb = (int)(((long)E_TOT << BSHIFT) / (long)NCAT);
    int cap = ((avgb + avgb / 4 + 256) + 255) & ~255;
    size_t ebuf_floats = (size_t)NBUCK * (size_t)cap * 2;
    bool canBucket = (NBUCK <= 1024) &&
                     (((off + ebuf_floats + 64) * sizeof(float)) <= ws_size);
    uint2* ebuf = canBucket ? (uint2*)alloc(ebuf_floats) : nullptr;

    __half* agg_a  = (__half*)agg_a_f;
    __half* agg_t0 = (__half*)agg_t0f;
    __half* agg_t2 = (__half*)agg_t2f;
    __half* h_t    = (__half*)h_t_f;
    __half* h_a    = (__half*)h_a_f;
    __half* has0   = (__half*)asrc0a;
    __half* has1   = (__half*)asrc1t;
    __half* has2   = (__half*)asrc2t;

    dim3 blk(256);
    const int GPB_E = 4;    // encproj: 64 nodes per g-iter, 256 nodes/block
    const int GPB_C = 4;    // combineproj: 64 nodes per g-iter, 256 nodes/block
    int nbA8 = (NA + 7) / 8;
    int nbAe = (NA + 64 * GPB_E - 1) / (64 * GPB_E);
    int nbTe = (NT + 64 * GPB_E - 1) / (64 * GPB_E);
    int nbAcp = (NA + 64 * GPB_C - 1) / (64 * GPB_C);
    int nbTcp = (NT + 64 * GPB_C - 1) / (64 * GPB_C);
    int nbE = (E_TOT + 255) / 256;
    int nbScan = (NCAT + 1023) / 1024;

    // ---- CSR build (once, reused by all layers) ----
    if (canBucket) {
        int nbChunk = (E_TOT + CHUNK - 1) / CHUNK;
        zero_int_kernel<<<8, blk, 0, stream>>>((int*)scores, 64 + 1024);
        bucket_scatter_kernel<<<nbChunk, blk, 0, stream>>>(
            ei_in, ei_out, ei_sp, E_IN, E_OUT, E_SP, NT, NA, bcur, ebuf, E_TOT, NBUCK, cap);
        scanb_kernel<<<1, 1024, 0, stream>>>(bcur, boff, rowptrAll, NBUCK, cap, NCAT);
        bucket_csr_kernel<<<NBUCK, blk, 0, stream>>>(ebuf, boff, rowptrAll, colAll, NCAT, cap);
    } else {
        zero_int_kernel<<<2048, blk, 0, stream>>>(tmp, (long)tmp_span);
        hist_kernel<<<nbE, blk, 0, stream>>>(ei_in, ei_out, ei_sp, E_IN, E_OUT, E_SP, NT, NA, tmp, E_TOT);
        scan1_kernel<<<nbScan, blk, 0, stream>>>(tmp, rowptrAll, bsum, NCAT);
        scan2_kernel<<<1, 1024, 0, stream>>>(bsum, nbScan);
        scan3_kernel<<<(NCAT + 255) / 256, blk, 0, stream>>>(rowptrAll, bsum, tmp, NCAT, E_TOT);
        scatter_kernel<<<nbE, blk, 0, stream>>>(ei_in, ei_out, ei_sp, E_IN, E_OUT, E_SP, NT, NA, tmp, colAll, E_TOT);
    }

    // ---- fused encoder + layer-0 projection ----
    encproj_addr_kernel<<<nbAe, blk, 0, stream>>>(
        x_addr, enc_w_addr, enc_b_addr, pw_a, pb_a,
        att_src + 0 * 32, att_dst + 1 * 32,
        xa, h_a, has0, adst1a, NA, GPB_E);
    encproj_tx_kernel<<<nbTe, blk, 0, stream>>>(
        x_tx, enc_w_tx, enc_b_tx, pw_t, pb_t,
        att_src + 1 * 32, att_dst + 0 * 32, att_src + 2 * 32, att_dst + 2 * 32,
        xt, h_t, has1, adst0t, has2, adst2t, NT, GPB_E);

    auto agg_launch = [&](int mode, int nRows, const float* kw, const float* kb,
                          const float* q, float* sc) {
        int blocks = (nRows + 31) / 32;
        if (blocks > 2048) blocks = 2048;
        agg_all_kernel<<<blocks, blk, 0, stream>>>(
            rowptrAll, colAll, h_a, h_t,
            has0, adst0t, has1, adst1a, has2, adst2t,
            agg_t0, agg_a, agg_t2, kw, kb, q, sc, NT, NA, mode, nRows);
    };

    for (int l = 0; l < NLAYERS; l++) {
        bool last = (l == NLAYERS - 1);
        const float* kw = klw + l * 1024;
        const float* kb = klb + l * 32;
        const float* q  = qv + l * 32;
        float* sc = scores + 2 * l;
        if (!last) {
            if (roomy) {
                agg_launch(0, NCAT, kw, kb, q, sc);
            } else {
                agg_launch(1, 2 * NT, kw, kb, q, sc);
                agg_launch(2, NA, kw, kb, q, sc);
            }
            int lp = l + 1;
            combineproj_kernel<<<nbAcp + nbTcp, blk, 0, stream>>>(
                agg_a, agg_t0, agg_t2, xa, xt,
                ln_ag, ln_ab, ln_tg, ln_tb,
                sc, 1.0f / (float)NT,
                pw_a + lp * 1024, pb_a + lp * 32, pw_t + lp * 1024, pb_t + lp * 32,
                att_src + (lp * 3 + 0) * 32, att_dst + (lp * 3 + 1) * 32,
                att_src + (lp * 3 + 1) * 32, att_dst + (lp * 3 + 0) * 32,
                att_src + (lp * 3 + 2) * 32, att_dst + (lp * 3 + 2) * 32,
                h_a, h_t,
                has0, adst1a, has1, adst0t, has2, adst2t,
                NA, NT, nbAcp, GPB_C, lp == 3 ? 1 : 0);
        } else {
            agg_launch(2, NA, kw, kb, q, sc);
            combine_final_kernel<<<nbA8, blk, 0, stream>>>(agg_a, xa, ln_ag, ln_ab,
                                                           lin_w, lin_b, out, NA);
        }
    }
}

// Round 10
// 729.635 us; speedup vs baseline: 1.1342x; 1.0293x over previous
//
#include <hip/hip_runtime.h>
#include <hip/hip_fp16.h>

#define NLAYERS 4
#define BSHIFT 10   // 1024 rows per bucket
#define CHUNK 4096  // edges per bucket_scatter block (16/thread, register-staged)

typedef _Float16 f16x8 __attribute__((ext_vector_type(8)));
typedef float f32x4 __attribute__((ext_vector_type(4)));

// ---------------- zero fill ----------------
__global__ void zero_int_kernel(int* __restrict__ p, long n) {
    long i = (long)blockIdx.x * 256 + threadIdx.x;
    long stride = (long)gridDim.x * 256;
    for (; i < n; i += stride) p[i] = 0;
}

__device__ __forceinline__ float fast_tanh(float y) {
    y = fminf(fmaxf(y, -15.f), 15.f);
    float t = __expf(2.f * y);
    return (t - 1.f) / (t + 1.f);
}

// ================= CSR build over concatenated dst space =================
// [0,NT) rel0 dsts | [NT,NT+NA) rel1 dsts | [NT+NA,NCAT) rel2 dsts
__device__ __forceinline__ int edge_row(const int* ei_in, const int* ei_out, const int* ei_sp,
                                        int E_IN, int E_OUT, int E_SP, int NT, int NA,
                                        int e, int* src) {
    if (e < E_IN) { *src = ei_in[e]; return ei_in[E_IN + e]; }
    if (e < E_IN + E_OUT) { int i = e - E_IN; *src = ei_out[i]; return NT + ei_out[E_OUT + i]; }
    int i = e - E_IN - E_OUT; *src = ei_sp[i]; return NT + NA + ei_sp[E_SP + i];
}

// legacy direct hist/scatter (fallback when no workspace room for bucket buffer)
__global__ void hist_kernel(const int* __restrict__ ei_in, const int* __restrict__ ei_out,
                            const int* __restrict__ ei_sp, int E_IN, int E_OUT, int E_SP,
                            int NT, int NA, int* __restrict__ deg, int E_TOT) {
    int e = blockIdx.x * 256 + threadIdx.x;
    if (e >= E_TOT) return;
    int s;
    int row = edge_row(ei_in, ei_out, ei_sp, E_IN, E_OUT, E_SP, NT, NA, e, &s);
    atomicAdd(&deg[row], 1);
}

__global__ void scatter_kernel(const int* __restrict__ ei_in, const int* __restrict__ ei_out,
                               const int* __restrict__ ei_sp, int E_IN, int E_OUT, int E_SP,
                               int NT, int NA, int* __restrict__ cursor, int* __restrict__ col,
                               int E_TOT) {
    int e = blockIdx.x * 256 + threadIdx.x;
    if (e >= E_TOT) return;
    int s;
    int row = edge_row(ei_in, ei_out, ei_sp, E_IN, E_OUT, E_SP, NT, NA, e, &s);
    int pos = atomicAdd(&cursor[row], 1);
    col[pos] = s;
}

__global__ void scan1_kernel(const int* __restrict__ deg, int* __restrict__ rowptr,
                             int* __restrict__ bsum, int n) {
    __shared__ int lds[256];
    int tid = threadIdx.x;
    int base = blockIdx.x * 1024;
    int v[4];
    int mysum = 0;
    #pragma unroll
    for (int j = 0; j < 4; j++) {
        int idx = base + tid * 4 + j;
        v[j] = (idx < n) ? deg[idx] : 0;
        mysum += v[j];
    }
    lds[tid] = mysum;
    __syncthreads();
    for (int off = 1; off < 256; off <<= 1) {
        int t = (tid >= off) ? lds[tid - off] : 0;
        __syncthreads();
        lds[tid] += t;
        __syncthreads();
    }
    int excl = lds[tid] - mysum;
    if (tid == 255) bsum[blockIdx.x] = lds[tid];
    int run = excl;
    #pragma unroll
    for (int j = 0; j < 4; j++) {
        int idx = base + tid * 4 + j;
        if (idx < n) rowptr[idx] = run;
        run += v[j];
    }
}

__global__ void scan2_kernel(int* __restrict__ bsum, int nb) {
    __shared__ int lds[1024];
    int tid = threadIdx.x;
    int v = (tid < nb) ? bsum[tid] : 0;
    lds[tid] = v;
    __syncthreads();
    for (int off = 1; off < 1024; off <<= 1) {
        int t = (tid >= off) ? lds[tid - off] : 0;
        __syncthreads();
        lds[tid] += t;
        __syncthreads();
    }
    if (tid < nb) bsum[tid] = lds[tid] - v;
}

__global__ void scan3_kernel(int* __restrict__ rowptr, const int* __restrict__ bsum,
                             int* __restrict__ cursor, int n, int E) {
    int i = blockIdx.x * 256 + threadIdx.x;
    if (i < n) {
        int r = rowptr[i] + bsum[i >> 10];
        rowptr[i] = r;
        cursor[i] = r;
    }
    if (i == 0) rowptr[n] = E;
}

// ---- bucketed CSR build, pass 1: single global read; edges register-staged ----
__global__ void __launch_bounds__(256) bucket_scatter_kernel(
    const int* __restrict__ ei_in, const int* __restrict__ ei_out,
    const int* __restrict__ ei_sp, int E_IN, int E_OUT, int E_SP,
    int NT, int NA, int* __restrict__ bcur,
    uint2* __restrict__ ebuf, int E_TOT, int nbuck, int cap) {
    __shared__ int lc[1024], lbase[1024], lcur[1024];
    int tid = threadIdx.x;
    int chunk0 = blockIdx.x * CHUNK;
    int chunkN = E_TOT - chunk0;
    if (chunkN > CHUNK) chunkN = CHUNK;
    if (chunkN <= 0) return;
    for (int i = tid; i < nbuck; i += 256) { lc[i] = 0; lcur[i] = 0; }
    __syncthreads();
    uint2 er[CHUNK / 256];
    #pragma unroll
    for (int j = 0; j < CHUNK / 256; j++) {
        int i = tid + j * 256;   // coalesced within each sub-pass
        if (i < chunkN) {
            int s;
            int row = edge_row(ei_in, ei_out, ei_sp, E_IN, E_OUT, E_SP, NT, NA, chunk0 + i, &s);
            er[j] = make_uint2((unsigned)row, (unsigned)s);
            atomicAdd(&lc[row >> BSHIFT], 1);
        } else {
            er[j].x = 0xFFFFFFFFu;
        }
    }
    __syncthreads();
    for (int i = tid; i < nbuck; i += 256) if (lc[i]) lbase[i] = atomicAdd(&bcur[i], lc[i]);
    __syncthreads();
    #pragma unroll
    for (int j = 0; j < CHUNK / 256; j++) {
        if (er[j].x != 0xFFFFFFFFu) {
            int b = (int)(er[j].x >> BSHIFT);
            int pos = lbase[b] + atomicAdd(&lcur[b], 1);
            if (pos < cap) ebuf[(size_t)b * cap + pos] = er[j];
        }
    }
}

// ---- pass 2: exclusive scan of bucket counts -> global col offsets ----
__global__ void scanb_kernel(const int* __restrict__ bcur, int* __restrict__ boff,
                             int* __restrict__ rowptr, int nbuck, int cap, int NCAT) {
    __shared__ int lds[1024];
    int tid = threadIdx.x;
    int v = 0;
    if (tid < nbuck) { v = bcur[tid]; if (v > cap) v = cap; }
    lds[tid] = v;
    __syncthreads();
    for (int off = 1; off < 1024; off <<= 1) {
        int t = (tid >= off) ? lds[tid - off] : 0;
        __syncthreads();
        lds[tid] += t;
        __syncthreads();
    }
    if (tid < nbuck) boff[tid] = lds[tid] - v;
    if (tid == 1023) {
        boff[nbuck] = lds[1023];
        rowptr[NCAT] = lds[1023];
    }
}

// ---- pass 3: one block per bucket; LDS hist + LDS scan + LDS-cursor scatter ----
__global__ void __launch_bounds__(256) bucket_csr_kernel(
    const uint2* __restrict__ ebuf, const int* __restrict__ boff,
    int* __restrict__ rowptr, int* __restrict__ col, int NCAT, int cap) {
    __shared__ int ldeg[1024];
    __shared__ int lsum[256];
    int tid = threadIdx.x;
    int b = blockIdx.x;
    int row0 = b << BSHIFT;
    int e0 = boff[b], e1 = boff[b + 1];
    int cnt = e1 - e0;
    const uint2* src = ebuf + (size_t)b * cap;
    for (int i = tid; i < 1024; i += 256) ldeg[i] = 0;
    __syncthreads();
    for (int i = tid; i < cnt; i += 256)
        atomicAdd(&ldeg[src[i].x - (unsigned)row0], 1);
    __syncthreads();
    int bidx = tid * 4;
    int v0 = ldeg[bidx], v1 = ldeg[bidx + 1], v2 = ldeg[bidx + 2], v3 = ldeg[bidx + 3];
    int mysum = v0 + v1 + v2 + v3;
    lsum[tid] = mysum;
    __syncthreads();
    for (int off = 1; off < 256; off <<= 1) {
        int t = (tid >= off) ? lsum[tid - off] : 0;
        __syncthreads();
        lsum[tid] += t;
        __syncthreads();
    }
    int run = e0 + lsum[tid] - mysum;
    int vv[4] = {v0, v1, v2, v3};
    #pragma unroll
    for (int j = 0; j < 4; j++) {
        int r = bidx + j;
        if (row0 + r < NCAT) rowptr[row0 + r] = run;
        ldeg[r] = run;          // becomes the cursor
        run += vv[j];
    }
    __syncthreads();
    for (int i = tid; i < cnt; i += 256) {
        uint2 p = src[i];
        int pos = atomicAdd(&ldeg[p.x - (unsigned)row0], 1);
        col[pos] = (int)p.y;
    }
}

// ================= fused encoder + layer-0 projection (MFMA, 1 wave = 16 nodes) =================
__global__ void __launch_bounds__(256) encproj_addr_kernel(
    const float* __restrict__ x,
    const float* __restrict__ We, const float* __restrict__ be,
    const float* __restrict__ Wp, const float* __restrict__ bp,
    const float* __restrict__ a0, const float* __restrict__ a1,
    float* __restrict__ xa, __half* __restrict__ h,
    __half* __restrict__ o0, float* __restrict__ o1,
    int n, int gpb) {
    __shared__ __align__(16) float lds_t[4][16][36];
    __shared__ float sx[4][16 * 57];
    int tid = threadIdx.x;
    int wave = tid >> 6, lane = tid & 63;
    int colid = lane & 15, kgrp = lane >> 4;
    int fbase = kgrp * 8;

    f16x8 bE00, bE01, bE10, bE11;
    #pragma unroll
    for (int j = 0; j < 8; j++) {
        int k0 = fbase + j;
        int k1 = 32 + fbase + j;
        bE00[j] = (_Float16)We[k0 * 32 + colid];
        bE01[j] = (_Float16)We[k0 * 32 + 16 + colid];
        float w10 = (k1 < 53) ? We[k1 * 32 + colid] : 0.f;
        float w11 = (k1 < 53) ? We[k1 * 32 + 16 + colid] : 0.f;
        bE10[j] = (_Float16)w10;
        bE11[j] = (_Float16)w11;
    }
    float beC0 = be[colid], beC1 = be[16 + colid];

    f16x8 bP0, bP1;
    #pragma unroll
    for (int j = 0; j < 8; j++) {
        bP0[j] = (_Float16)Wp[(fbase + j) * 32 + colid];
        bP1[j] = (_Float16)Wp[(fbase + j) * 32 + 16 + colid];
    }
    float bpC0 = bp[colid], bpC1 = bp[16 + colid];

    float va0[8], va1[8];
    #pragma unroll
    for (int j = 0; j < 8; j++) { va0[j] = a0[fbase + j]; va1[j] = a1[fbase + j]; }

    float (*tp)[36] = lds_t[wave];
    float* sxw = sx[wave];
    int blockBase = blockIdx.x * gpb * 64;
    for (int gi = 0; gi < gpb; gi++) {
        int node0 = blockBase + gi * 64 + wave * 16;
        int node = node0 + colid;
        bool valid = node < n;
        int nn = n - node0;
        if (nn > 16) nn = 16;
        if (nn < 0) nn = 0;
        int elems = nn * 53;
        for (int i = lane; i < elems; i += 64) {
            int r = i / 53, c = i - r * 53;
            sxw[r * 57 + c] = x[(size_t)node0 * 53 + i];
        }
        f16x8 af0, af1;
        #pragma unroll
        for (int j = 0; j < 8; j++) {
            af0[j] = (_Float16)sxw[colid * 57 + fbase + j];
            int kk = 32 + fbase + j;
            float v1 = (kk < 53) ? sxw[colid * 57 + kk] : 0.f;
            af1[j] = (_Float16)v1;
        }
        f32x4 c0 = {0.f, 0.f, 0.f, 0.f};
        f32x4 c1 = {0.f, 0.f, 0.f, 0.f};
        c0 = __builtin_amdgcn_mfma_f32_16x16x32_f16(af0, bE00, c0, 0, 0, 0);
        c0 = __builtin_amdgcn_mfma_f32_16x16x32_f16(af1, bE10, c0, 0, 0, 0);
        c1 = __builtin_amdgcn_mfma_f32_16x16x32_f16(af0, bE01, c1, 0, 0, 0);
        c1 = __builtin_amdgcn_mfma_f32_16x16x32_f16(af1, bE11, c1, 0, 0, 0);
        #pragma unroll
        for (int r = 0; r < 4; r++) {
            c0[r] = fmaxf(c0[r] + beC0, 0.f);
            c1[r] = fmaxf(c1[r] + beC1, 0.f);
        }
        #pragma unroll
        for (int r = 0; r < 4; r++) {
            int row = kgrp * 4 + r;
            tp[row][colid] = c0[r];
            tp[row][16 + colid] = c1[r];
        }
        float4 xlo = *(const float4*)&tp[colid][fbase];
        float4 xhi = *(const float4*)&tp[colid][fbase + 4];
        float xe[8] = {xlo.x, xlo.y, xlo.z, xlo.w, xhi.x, xhi.y, xhi.z, xhi.w};
        if (valid) {
            size_t basep = (size_t)node * 32 + fbase;
            *(float4*)(xa + basep) = xlo;
            *(float4*)(xa + basep + 4) = xhi;
        }
        f16x8 af;
        #pragma unroll
        for (int j = 0; j < 8; j++) af[j] = (_Float16)xe[j];
        f32x4 p0 = {0.f, 0.f, 0.f, 0.f};
        f32x4 p1 = {0.f, 0.f, 0.f, 0.f};
        p0 = __builtin_amdgcn_mfma_f32_16x16x32_f16(af, bP0, p0, 0, 0, 0);
        p1 = __builtin_amdgcn_mfma_f32_16x16x32_f16(af, bP1, p1, 0, 0, 0);
        #pragma unroll
        for (int r = 0; r < 4; r++) { p0[r] += bpC0; p1[r] += bpC1; }
        #pragma unroll
        for (int r = 0; r < 4; r++) {
            int row = kgrp * 4 + r;
            tp[row][colid] = p0[r];
            tp[row][16 + colid] = p1[r];
        }
        float4 hlo = *(const float4*)&tp[colid][fbase];
        float4 hhi = *(const float4*)&tp[colid][fbase + 4];
        float hv[8] = {hlo.x, hlo.y, hlo.z, hlo.w, hhi.x, hhi.y, hhi.z, hhi.w};
        if (valid) {
            float4 hout;
            __half2* hp2 = (__half2*)&hout;
            hp2[0] = __floats2half2_rn(hv[0], hv[1]);
            hp2[1] = __floats2half2_rn(hv[2], hv[3]);
            hp2[2] = __floats2half2_rn(hv[4], hv[5]);
            hp2[3] = __floats2half2_rn(hv[6], hv[7]);
            *(float4*)(h + (size_t)node * 32 + fbase) = hout;
            float d0 = 0.f, d1 = 0.f;
            #pragma unroll
            for (int j = 0; j < 8; j++) {
                d0 += hv[j] * va0[j];
                d1 += hv[j] * va1[j];
            }
            size_t oidx = (size_t)node * 4 + kgrp;
            o0[oidx] = __float2half(d0);
            o1[oidx] = d1;
        }
    }
}

__global__ void __launch_bounds__(256) encproj_tx_kernel(
    const float* __restrict__ x,
    const float* __restrict__ We, const float* __restrict__ be,
    const float* __restrict__ Wp, const float* __restrict__ bp,
    const float* __restrict__ a0, const float* __restrict__ a1,
    const float* __restrict__ a2, const float* __restrict__ a3,
    float* __restrict__ xt, __half* __restrict__ h,
    __half* __restrict__ o0, float* __restrict__ o1,
    __half* __restrict__ o2, float* __restrict__ o3,
    int n, int gpb) {
    __shared__ __align__(16) float lds_t[4][16][36];
    int tid = threadIdx.x;
    int wave = tid >> 6, lane = tid & 63;
    int colid = lane & 15, kgrp = lane >> 4;
    int fbase = kgrp * 8;

    f16x8 bE0, bE1;
    #pragma unroll
    for (int j = 0; j < 8; j++) {
        int k = fbase + j;
        float w0 = (k < 6) ? We[k * 32 + colid] : 0.f;
        float w1 = (k < 6) ? We[k * 32 + 16 + colid] : 0.f;
        bE0[j] = (_Float16)w0;
        bE1[j] = (_Float16)w1;
    }
    float beC0 = be[colid], beC1 = be[16 + colid];

    f16x8 bP0, bP1;
    #pragma unroll
    for (int j = 0; j < 8; j++) {
        bP0[j] = (_Float16)Wp[(fbase + j) * 32 + colid];
        bP1[j] = (_Float16)Wp[(fbase + j) * 32 + 16 + colid];
    }
    float bpC0 = bp[colid], bpC1 = bp[16 + colid];

    float va0[8], va1[8], va2[8], va3[8];
    #pragma unroll
    for (int j = 0; j < 8; j++) {
        va0[j] = a0[fbase + j]; va1[j] = a1[fbase + j];
        va2[j] = a2[fbase + j]; va3[j] = a3[fbase + j];
    }

    float (*tp)[36] = lds_t[wave];
    int blockBase = blockIdx.x * gpb * 64;
    for (int gi = 0; gi < gpb; gi++) {
        int node = blockBase + gi * 64 + wave * 16 + colid;
        bool valid = node < n;
        f16x8 af0;
        #pragma unroll
        for (int j = 0; j < 8; j++) {
            int k = fbase + j;
            float xv = 0.f;
            if (k < 6 && valid) xv = x[(size_t)node * 6 + k];
            af0[j] = (_Float16)xv;
        }
        f32x4 c0 = {0.f, 0.f, 0.f, 0.f};
        f32x4 c1 = {0.f, 0.f, 0.f, 0.f};
        c0 = __builtin_amdgcn_mfma_f32_16x16x32_f16(af0, bE0, c0, 0, 0, 0);
        c1 = __builtin_amdgcn_mfma_f32_16x16x32_f16(af0, bE1, c1, 0, 0, 0);
        #pragma unroll
        for (int r = 0; r < 4; r++) {
            c0[r] = fmaxf(c0[r] + beC0, 0.f);
            c1[r] = fmaxf(c1[r] + beC1, 0.f);
        }
        #pragma unroll
        for (int r = 0; r < 4; r++) {
            int row = kgrp * 4 + r;
            tp[row][colid] = c0[r];
            tp[row][16 + colid] = c1[r];
        }
        float4 xlo = *(const float4*)&tp[colid][fbase];
        float4 xhi = *(const float4*)&tp[colid][fbase + 4];
        float xe[8] = {xlo.x, xlo.y, xlo.z, xlo.w, xhi.x, xhi.y, xhi.z, xhi.w};
        if (valid) {
            size_t basep = (size_t)node * 32 + fbase;
            *(float4*)(xt + basep) = xlo;
            *(float4*)(xt + basep + 4) = xhi;
        }
        f16x8 af;
        #pragma unroll
        for (int j = 0; j < 8; j++) af[j] = (_Float16)xe[j];
        f32x4 p0 = {0.f, 0.f, 0.f, 0.f};
        f32x4 p1 = {0.f, 0.f, 0.f, 0.f};
        p0 = __builtin_amdgcn_mfma_f32_16x16x32_f16(af, bP0, p0, 0, 0, 0);
        p1 = __builtin_amdgcn_mfma_f32_16x16x32_f16(af, bP1, p1, 0, 0, 0);
        #pragma unroll
        for (int r = 0; r < 4; r++) { p0[r] += bpC0; p1[r] += bpC1; }
        #pragma unroll
        for (int r = 0; r < 4; r++) {
            int row = kgrp * 4 + r;
            tp[row][colid] = p0[r];
            tp[row][16 + colid] = p1[r];
        }
        float4 hlo = *(const float4*)&tp[colid][fbase];
        float4 hhi = *(const float4*)&tp[colid][fbase + 4];
        float hv[8] = {hlo.x, hlo.y, hlo.z, hlo.w, hhi.x, hhi.y, hhi.z, hhi.w};
        if (valid) {
            float4 hout;
            __half2* hp2 = (__half2*)&hout;
            hp2[0] = __floats2half2_rn(hv[0], hv[1]);
            hp2[1] = __floats2half2_rn(hv[2], hv[3]);
            hp2[2] = __floats2half2_rn(hv[4], hv[5]);
            hp2[3] = __floats2half2_rn(hv[6], hv[7]);
            *(float4*)(h + (size_t)node * 32 + fbase) = hout;
            float d0 = 0.f, d1 = 0.f, d2 = 0.f, d3 = 0.f;
            #pragma unroll
            for (int j = 0; j < 8; j++) {
                d0 += hv[j] * va0[j];
                d1 += hv[j] * va1[j];
                d2 += hv[j] * va2[j];
                d3 += hv[j] * va3[j];
            }
            size_t oidx = (size_t)node * 4 + kgrp;
            o0[oidx] = __float2half(d0);
            o1[oidx] = d1;
            o2[oidx] = __float2half(d2);
            o3[oidx] = d3;
        }
    }
}

// ================= merged CSR aggregation (all rels) + fused semantic score =================
// 4 lanes/row (lane = head, 8 features/lane): 16 rows in flight per wave for 2x MLP.
__global__ void agg_all_kernel(
    const int* __restrict__ rowptr, const int* __restrict__ col,
    const __half* __restrict__ h_a, const __half* __restrict__ h_t,
    const __half* __restrict__ asrc0, const float* __restrict__ adst0,
    const __half* __restrict__ asrc1, const float* __restrict__ adst1,
    const __half* __restrict__ asrc2, const float* __restrict__ adst2,
    __half* __restrict__ agg_t0, __half* __restrict__ agg_a, __half* __restrict__ agg_t2,
    const float* __restrict__ kw, const float* __restrict__ kb, const float* __restrict__ q,
    float* __restrict__ scoreOut, int NT, int NA, int mode, int nRows) {
    __shared__ float sW[1024];
    __shared__ float sb[32];
    __shared__ float sq[32];
    __shared__ float sScore[2];
    int tid = threadIdx.x;
    bool doScore = (mode != 2);
    if (doScore) {
        for (int i = tid; i < 1024; i += 256) sW[i] = kw[i];
        if (tid < 32) { sb[tid] = kb[tid]; sq[tid] = q[tid]; }
        if (tid < 2) sScore[tid] = 0.f;
        __syncthreads();
    }
    int lane = tid & 3;        // head
    int f0 = lane * 8;         // feature base (8 features per lane)
    long stride = (long)gridDim.x * 64;
    for (long gi = (long)blockIdx.x * 64 + (tid >> 2); gi < (long)nRows; gi += stride) {
        int row;
        if (mode == 0) row = (int)gi;
        else if (mode == 1) row = (gi < NT) ? (int)gi : (int)(gi + NA);
        else row = NT + (int)gi;
        int rel, dst;
        const __half* h; const __half* asrc; const float* adp; __half* agg;
        if (row < NT)           { rel = 0; dst = row;           h = h_a; asrc = asrc0; adp = adst0; agg = agg_t0; }
        else if (row < NT + NA) { rel = 1; dst = row - NT;      h = h_t; asrc = asrc1; adp = adst1; agg = agg_a; }
        else                    { rel = 2; dst = row - NT - NA; h = h_t; asrc = asrc2; adp = adst2; agg = agg_t2; }
        float ad = adp[dst * 4 + lane];
        int e0 = rowptr[row], e1 = rowptr[row + 1];
        __half2 acc0 = __floats2half2_rn(0.f, 0.f);
        __half2 acc1 = acc0, acc2 = acc0, acc3 = acc0;
        float den = 0.f;
        for (int e = e0; e < e1; e += 4) {
            int s0 = col[e];
            int s1 = (e + 1 < e1) ? col[e + 1] : s0;
            int s2 = (e + 2 < e1) ? col[e + 2] : s0;
            int s3 = (e + 3 < e1) ? col[e + 3] : s0;
            float as0 = __half2float(asrc[s0 * 4 + lane]);
            float as1 = __half2float(asrc[s1 * 4 + lane]);
            float as2 = __half2float(asrc[s2 * 4 + lane]);
            float as3 = __half2float(asrc[s3 * 4 + lane]);
            float4 r0 = *(const float4*)(h + s0 * 32 + f0);
            float4 r1 = *(const float4*)(h + s1 * 32 + f0);
            float4 r2 = *(const float4*)(h + s2 * 32 + f0);
            float4 r3 = *(const float4*)(h + s3 * 32 + f0);
            float t0 = as0 + ad; t0 = t0 > 0.f ? t0 : 0.2f * t0;
            float t1 = as1 + ad; t1 = t1 > 0.f ? t1 : 0.2f * t1;
            float t2 = as2 + ad; t2 = t2 > 0.f ? t2 : 0.2f * t2;
            float t3 = as3 + ad; t3 = t3 > 0.f ? t3 : 0.2f * t3;
            float ex0 = __expf(t0);
            float ex1 = (e + 1 < e1) ? __expf(t1) : 0.f;
            float ex2 = (e + 2 < e1) ? __expf(t2) : 0.f;
            float ex3 = (e + 3 < e1) ? __expf(t3) : 0.f;
            den += (ex0 + ex1) + (ex2 + ex3);
            __half2 eh0 = __float2half2_rn(ex0), eh1 = __float2half2_rn(ex1);
            __half2 eh2 = __float2half2_rn(ex2), eh3 = __float2half2_rn(ex3);
            const __half2* h0 = (const __half2*)&r0;
            const __half2* h1 = (const __half2*)&r1;
            const __half2* h2 = (const __half2*)&r2;
            const __half2* h3 = (const __half2*)&r3;
            acc0 = __hfma2(eh0, h0[0], acc0);
            acc1 = __hfma2(eh0, h0[1], acc1);
            acc2 = __hfma2(eh0, h0[2], acc2);
            acc3 = __hfma2(eh0, h0[3], acc3);
            acc0 = __hfma2(eh1, h1[0], acc0);
            acc1 = __hfma2(eh1, h1[1], acc1);
            acc2 = __hfma2(eh1, h1[2], acc2);
            acc3 = __hfma2(eh1, h1[3], acc3);
            acc0 = __hfma2(eh2, h2[0], acc0);
            acc1 = __hfma2(eh2, h2[1], acc1);
            acc2 = __hfma2(eh2, h2[2], acc2);
            acc3 = __hfma2(eh2, h2[3], acc3);
            acc0 = __hfma2(eh3, h3[0], acc0);
            acc1 = __hfma2(eh3, h3[1], acc1);
            acc2 = __hfma2(eh3, h3[2], acc2);
            acc3 = __hfma2(eh3, h3[3], acc3);
        }
        float r = 1.f / (den + 1e-16f);
        float2 a0 = __half22float2(acc0), a1 = __half22float2(acc1);
        float2 a2 = __half22float2(acc2), a3 = __half22float2(acc3);
        float v[8] = {a0.x * r, a0.y * r, a1.x * r, a1.y * r,
                      a2.x * r, a2.y * r, a3.x * r, a3.y * r};
        float4 opack;
        __half2* op2 = (__half2*)&opack;
        op2[0] = __floats2half2_rn(v[0], v[1]);
        op2[1] = __floats2half2_rn(v[2], v[3]);
        op2[2] = __floats2half2_rn(v[4], v[5]);
        op2[3] = __floats2half2_rn(v[6], v[7]);
        *(float4*)(agg + dst * 32 + f0) = opack;
        if (doScore && rel != 1) {
            float rv[8];
            #pragma unroll
            for (int j = 0; j < 8; j++) rv[j] = fmaxf(v[j], 0.f);
            float y[8];
            #pragma unroll
            for (int j = 0; j < 8; j++) y[j] = sb[f0 + j];
            #pragma unroll
            for (int g = 0; g < 4; g++) {
                float c[8];
                #pragma unroll
                for (int jj = 0; jj < 8; jj++) c[jj] = __shfl(rv[jj], g, 4);
                int kb8 = g * 8;
                #pragma unroll
                for (int jj = 0; jj < 8; jj++) {
                    #pragma unroll
                    for (int j = 0; j < 8; j++)
                        y[j] += c[jj] * sW[(kb8 + jj) * 32 + f0 + j];
                }
            }
            float sacc = 0.f;
            #pragma unroll
            for (int j = 0; j < 8; j++) sacc += sq[f0 + j] * fast_tanh(y[j]);
            sacc += __shfl_xor(sacc, 1, 4);
            sacc += __shfl_xor(sacc, 2, 4);
            if (lane == 0) atomicAdd(&sScore[rel == 2 ? 1 : 0], sacc);
        }
    }
    if (doScore) {
        __syncthreads();
        if (tid < 2) unsafeAtomicAdd(scoreOut + tid, sScore[tid]);
    }
}

// ================= fused combine + next-layer projection (MFMA, 1 wave = 16 nodes) =================
__global__ void __launch_bounds__(256) combineproj_kernel(
    const __half* __restrict__ agg_a, const __half* __restrict__ agg_t0, const __half* __restrict__ agg_t2,
    float* __restrict__ xa, float* __restrict__ xt,
    const float* __restrict__ ln_ag, const float* __restrict__ ln_ab,
    const float* __restrict__ ln_tg, const float* __restrict__ ln_tb,
    const float* __restrict__ scores, float invNT,
    const float* __restrict__ Wa, const float* __restrict__ Ba,
    const float* __restrict__ Wt, const float* __restrict__ Bt,
    const float* __restrict__ as0, const float* __restrict__ ad1,
    const float* __restrict__ as1, const float* __restrict__ ad0,
    const float* __restrict__ as2, const float* __restrict__ ad2,
    __half* __restrict__ h_a, __half* __restrict__ h_t,
    __half* __restrict__ o_as0, float* __restrict__ o_ad1,
    __half* __restrict__ o_as1, float* __restrict__ o_ad0,
    __half* __restrict__ o_as2, float* __restrict__ o_ad2,
    int NA_, int NT_, int nbAcp, int gpb, int lastProj) {
    __shared__ __align__(16) float lds_t[4][16][36];
    int tid = threadIdx.x;
    int wave = tid >> 6;
    int lane = tid & 63;
    int colid = lane & 15;
    int kgrp = lane >> 4;
    int fbase = kgrp * 8;

    bool isA = blockIdx.x < (unsigned)nbAcp;
    const float* W = isA ? Wa : Wt;
    const float* Bp = isA ? Ba : Bt;
    int n = isA ? NA_ : NT_;

    f16x8 bf0, bf1;
    #pragma unroll
    for (int j = 0; j < 8; j++) {
        bf0[j] = (_Float16)W[(fbase + j) * 32 + colid];
        bf1[j] = (_Float16)W[(fbase + j) * 32 + 16 + colid];
    }
    float bp0 = Bp[colid], bp1 = Bp[16 + colid];

    const float* lng = isA ? ln_ag : ln_tg;
    const float* lnb = isA ? ln_ab : ln_tb;
    float g[8], bb[8];
    #pragma unroll
    for (int j = 0; j < 8; j++) { g[j] = lng[fbase + j]; bb[j] = lnb[fbase + j]; }

    float va0[8], va1[8], va2[8], va3[8];
    if (isA) {
        #pragma unroll
        for (int j = 0; j < 8; j++) { va0[j] = as0[fbase + j]; va1[j] = ad1[fbase + j]; }
    } else {
        #pragma unroll
        for (int j = 0; j < 8; j++) {
            va0[j] = as1[fbase + j]; va1[j] = ad0[fbase + j];
            va2[j] = as2[fbase + j]; va3[j] = ad2[fbase + j];
        }
    }

    float wsem0 = 0.f, wsem2 = 0.f;
    if (!isA) {
        float s0 = scores[0] * invNT, s2 = scores[1] * invNT;
        float mx = fmaxf(s0, s2);
        float e0 = __expf(s0 - mx), e2 = __expf(s2 - mx);
        float inv_s = 1.f / (e0 + e2);
        wsem0 = e0 * inv_s; wsem2 = e2 * inv_s;
    }

    float (*tp)[36] = lds_t[wave];
    int blockBase = (isA ? (int)blockIdx.x : (int)blockIdx.x - nbAcp) * gpb * 64;
    for (int gi = 0; gi < gpb; gi++) {
        int node = blockBase + gi * 64 + wave * 16 + colid;
        bool valid = node < n;
        float v[8];
        if (valid) {
            size_t base = (size_t)node * 32 + fbase;
            float4 xlo, xhi;
            if (isA) {
                xlo = *(const float4*)(xa + base);
                xhi = *(const float4*)(xa + base + 4);
                float4 ar = *(const float4*)(agg_a + base);
                const __half2* ah2 = (const __half2*)&ar;
                float2 f0 = __half22float2(ah2[0]);
                float2 f1 = __half22float2(ah2[1]);
                float2 f2 = __half22float2(ah2[2]);
                float2 f3 = __half22float2(ah2[3]);
                float av[8] = {f0.x, f0.y, f1.x, f1.y, f2.x, f2.y, f3.x, f3.y};
                float xv[8] = {xlo.x, xlo.y, xlo.z, xlo.w, xhi.x, xhi.y, xhi.z, xhi.w};
                #pragma unroll
                for (int j = 0; j < 8; j++) v[j] = fmaxf(av[j], 0.f) + xv[j];
            } else {
                xlo = *(const float4*)(xt + base);
                xhi = *(const float4*)(xt + base + 4);
                float4 a0r = *(const float4*)(agg_t0 + base);
                float4 a2r = *(const float4*)(agg_t2 + base);
                const __half2* a0h = (const __half2*)&a0r;
                const __half2* a2h = (const __half2*)&a2r;
                float xv[8] = {xlo.x, xlo.y, xlo.z, xlo.w, xhi.x, xhi.y, xhi.z, xhi.w};
                #pragma unroll
                for (int j = 0; j < 4; j++) {
                    float2 p0 = __half22float2(a0h[j]);
                    float2 p2 = __half22float2(a2h[j]);
                    float c0 = wsem0 * fmaxf(p0.x, 0.f) + wsem2 * fmaxf(p2.x, 0.f);
                    float c1 = wsem0 * fmaxf(p0.y, 0.f) + wsem2 * fmaxf(p2.y, 0.f);
                    v[2 * j]     = fmaxf(c0, 0.f) + xv[2 * j];
                    v[2 * j + 1] = fmaxf(c1, 0.f) + xv[2 * j + 1];
                }
            }
        } else {
            #pragma unroll
            for (int j = 0; j < 8; j++) v[j] = 0.f;
        }
        float s = 0.f;
        #pragma unroll
        for (int j = 0; j < 8; j++) s += v[j];
        s += __shfl_xor(s, 16, 64);
        s += __shfl_xor(s, 32, 64);
        float m = s * 0.03125f;
        float d[8], vv = 0.f;
        #pragma unroll
        for (int j = 0; j < 8; j++) { d[j] = v[j] - m; vv += d[j] * d[j]; }
        vv += __shfl_xor(vv, 16, 64);
        vv += __shfl_xor(vv, 32, 64);
        float inv = 1.f / sqrtf(vv * 0.03125f + 1e-5f);
        float ln[8];
        #pragma unroll
        for (int j = 0; j < 8; j++) ln[j] = d[j] * inv * g[j] + bb[j];

        if (valid && (isA || !lastProj)) {
            float* xp = isA ? xa : xt;
            size_t base = (size_t)node * 32 + fbase;
            *(float4*)(xp + base)     = make_float4(ln[0], ln[1], ln[2], ln[3]);
            *(float4*)(xp + base + 4) = make_float4(ln[4], ln[5], ln[6], ln[7]);
        }

        f16x8 af;
        #pragma unroll
        for (int j = 0; j < 8; j++) af[j] = (_Float16)ln[j];
        f32x4 c0 = {0.f, 0.f, 0.f, 0.f};
        f32x4 c1 = {0.f, 0.f, 0.f, 0.f};
        c0 = __builtin_amdgcn_mfma_f32_16x16x32_f16(af, bf0, c0, 0, 0, 0);
        c1 = __builtin_amdgcn_mfma_f32_16x16x32_f16(af, bf1, c1, 0, 0, 0);
        #pragma unroll
        for (int r = 0; r < 4; r++) { c0[r] += bp0; c1[r] += bp1; }

        #pragma unroll
        for (int r = 0; r < 4; r++) {
            int row = kgrp * 4 + r;
            tp[row][colid] = c0[r];
            tp[row][16 + colid] = c1[r];
        }
        float4 hlo = *(const float4*)&tp[colid][fbase];
        float4 hhi = *(const float4*)&tp[colid][fbase + 4];
        float hv[8] = {hlo.x, hlo.y, hlo.z, hlo.w, hhi.x, hhi.y, hhi.z, hhi.w};

        bool writeH = (!isA || !lastProj);
        if (valid && writeH) {
            float4 hout;
            __half2* hp2 = (__half2*)&hout;
            hp2[0] = __floats2half2_rn(hv[0], hv[1]);
            hp2[1] = __floats2half2_rn(hv[2], hv[3]);
            hp2[2] = __floats2half2_rn(hv[4], hv[5]);
            hp2[3] = __floats2half2_rn(hv[6], hv[7]);
            __half* hp = isA ? h_a : h_t;
            *(float4*)(hp + (size_t)node * 32 + fbase) = hout;
        }

        if (valid) {
            size_t oidx = (size_t)node * 4 + kgrp;
            if (isA) {
                if (!lastProj) {
                    float ds = 0.f;
                    #pragma unroll
                    for (int j = 0; j < 8; j++) ds += hv[j] * va0[j];
                    o_as0[oidx] = __float2half(ds);
                }
                float dd = 0.f;
                #pragma unroll
                for (int j = 0; j < 8; j++) dd += hv[j] * va1[j];
                o_ad1[oidx] = dd;
            } else {
                float d0 = 0.f;
                #pragma unroll
                for (int j = 0; j < 8; j++) d0 += hv[j] * va0[j];
                o_as1[oidx] = __float2half(d0);
                if (!lastProj) {
                    float d1 = 0.f, d2 = 0.f, d3 = 0.f;
                    #pragma unroll
                    for (int j = 0; j < 8; j++) {
                        d1 += hv[j] * va1[j];
                        d2 += hv[j] * va2[j];
                        d3 += hv[j] * va3[j];
                    }
                    o_ad0[oidx] = d1;
                    o_as2[oidx] = __float2half(d2);
                    o_ad2[oidx] = d3;
                }
            }
        }
    }
}

// ================= layer-3 combine_addr + output head =================
__global__ void combine_final_kernel(const __half* __restrict__ agg_a, const float* __restrict__ xa,
                                     const float* __restrict__ g, const float* __restrict__ bt,
                                     const float* __restrict__ lw, const float* __restrict__ lb,
                                     float* __restrict__ out, int n) {
    int tid = threadIdx.x;
    int local = tid >> 5, f = tid & 31;
    int node = blockIdx.x * 8 + local;
    if (node >= n) return;
    float a = __half2float(agg_a[(size_t)node * 32 + f]);
    float v = fmaxf(a, 0.f) + xa[(size_t)node * 32 + f];
    float m = v;
    #pragma unroll
    for (int mask = 1; mask < 32; mask <<= 1) m += __shfl_xor(m, mask, 64);
    m *= (1.f / 32.f);
    float d = v - m;
    float var = d * d;
    #pragma unroll
    for (int mask = 1; mask < 32; mask <<= 1) var += __shfl_xor(var, mask, 64);
    var *= (1.f / 32.f);
    float inv = 1.f / sqrtf(var + 1e-5f);
    float ln = d * inv * g[f] + bt[f];
    float p0 = ln * lw[f * 2 + 0];
    float p1 = ln * lw[f * 2 + 1];
    #pragma unroll
    for (int mask = 1; mask < 32; mask <<= 1) {
        p0 += __shfl_xor(p0, mask, 64);
        p1 += __shfl_xor(p1, mask, 64);
    }
    if (f == 0) {
        out[(size_t)node * 2 + 0] = p0 + lb[0];
        out[(size_t)node * 2 + 1] = p1 + lb[1];
    }
}

extern "C" void kernel_launch(void* const* d_in, const int* in_sizes, int n_in,
                              void* d_out, int out_size, void* d_ws, size_t ws_size,
                              hipStream_t stream) {
    const float* x_addr = (const float*)d_in[0];
    const float* x_tx   = (const float*)d_in[1];
    const int* ei_in    = (const int*)d_in[2];
    const int* ei_out   = (const int*)d_in[3];
    const int* ei_sp    = (const int*)d_in[4];
    const float* enc_w_addr = (const float*)d_in[5];
    const float* enc_b_addr = (const float*)d_in[6];
    const float* enc_w_tx   = (const float*)d_in[7];
    const float* enc_b_tx   = (const float*)d_in[8];
    const float* ln_ag = (const float*)d_in[9];
    const float* ln_ab = (const float*)d_in[10];
    const float* ln_tg = (const float*)d_in[11];
    const float* ln_tb = (const float*)d_in[12];
    const float* pw_a = (const float*)d_in[13];
    const float* pb_a = (const float*)d_in[14];
    const float* pw_t = (const float*)d_in[15];
    const float* pb_t = (const float*)d_in[16];
    const float* att_src = (const float*)d_in[17];
    const float* att_dst = (const float*)d_in[18];
    const float* klw = (const float*)d_in[19];
    const float* klb = (const float*)d_in[20];
    const float* qv  = (const float*)d_in[21];
    const float* lin_w = (const float*)d_in[22];
    const float* lin_b = (const float*)d_in[23];
    float* out = (float*)d_out;

    const int NA = in_sizes[0] / 53;
    const int NT = in_sizes[1] / 6;
    const int E_IN = in_sizes[2] / 2;
    const int E_OUT = in_sizes[3] / 2;
    const int E_SP = in_sizes[4] / 2;
    const int E_TOT = E_IN + E_OUT + E_SP;
    const int NCAT = NT + NA + NT;
    const int NBUCK = (NCAT + (1 << BSHIFT) - 1) >> BSHIFT;

    size_t off = 0;
    float* base = (float*)d_ws;
    auto alloc = [&](size_t nfloats) {
        float* p = base + off;
        off += (nfloats + 63) & ~(size_t)63;
        return p;
    };
    float* xa      = alloc((size_t)NA * 32);
    float* xt      = alloc((size_t)NT * 32);
    float* agg_a_f = alloc((size_t)NA * 16);
    float* agg_t0f = alloc((size_t)NT * 16);
    float* agg_t2f = alloc((size_t)NT * 16);
    float* h_t_f   = alloc((size_t)NT * 16);
    float* asrc0a  = alloc((size_t)NA * 2);   // fp16 x4 per node
    float* adst1a  = alloc((size_t)NA * 4);
    float* asrc1t  = alloc((size_t)NT * 2);   // fp16
    float* adst0t  = alloc((size_t)NT * 4);
    float* asrc2t  = alloc((size_t)NT * 2);   // fp16
    float* adst2t  = alloc((size_t)NT * 4);
    int* rowptrAll = (int*)alloc((size_t)NCAT + 64);
    int* colAll    = (int*)alloc((size_t)E_TOT);
    // legacy: tmp+bsum+scores+bcur zeroed together; bucket: scores+bcur only
    size_t tmp_span = (((size_t)NCAT + 63) & ~(size_t)63) + 1088 + 64 + 1024;
    int* tmp       = (int*)alloc((size_t)NCAT);
    int* bsum      = (int*)alloc(1088);
    float* scores  = alloc(64);
    int* bcur      = (int*)alloc(1024);
    int* boff      = (int*)alloc(1088);

    size_t ha_floats = (((size_t)NA * 16) + 63) & ~(size_t)63;
    bool roomy = ((off + ha_floats) * sizeof(float)) <= ws_size;
    float* h_a_f = roomy ? alloc((size_t)NA * 16) : agg_a_f;

    // bucketed edge pair buffer: fixed-capacity regions, cap = 1.25*avg + 256 (rounded to 256)
    int avgb = (int)(((long)E_TOT << BSHIFT) / (long)NCAT);
    int cap = ((avgb + avgb / 4 + 256) + 255) & ~255;
    size_t ebuf_floats = (size_t)NBUCK * (size_t)cap * 2;
    bool canBucket = (NBUCK <= 1024) &&
                     (((off + ebuf_floats + 64) * sizeof(float)) <= ws_size);
    uint2* ebuf = canBucket ? (uint2*)alloc(ebuf_floats) : nullptr;

    __half* agg_a  = (__half*)agg_a_f;
    __half* agg_t0 = (__half*)agg_t0f;
    __half* agg_t2 = (__half*)agg_t2f;
    __half* h_t    = (__half*)h_t_f;
    __half* h_a    = (__half*)h_a_f;
    __half* has0   = (__half*)asrc0a;
    __half* has1   = (__half*)asrc1t;
    __half* has2   = (__half*)asrc2t;

    dim3 blk(256);
    const int GPB_E = 4;    // encproj: 64 nodes per g-iter, 256 nodes/block
    const int GPB_C = 4;    // combineproj: 64 nodes per g-iter, 256 nodes/block
    int nbA8 = (NA + 7) / 8;
    int nbAe = (NA + 64 * GPB_E - 1) / (64 * GPB_E);
    int nbTe = (NT + 64 * GPB_E - 1) / (64 * GPB_E);
    int nbAcp = (NA + 64 * GPB_C - 1) / (64 * GPB_C);
    int nbTcp = (NT + 64 * GPB_C - 1) / (64 * GPB_C);
    int nbE = (E_TOT + 255) / 256;
    int nbScan = (NCAT + 1023) / 1024;

    // ---- CSR build (once, reused by all layers) ----
    if (canBucket) {
        int nbChunk = (E_TOT + CHUNK - 1) / CHUNK;
        zero_int_kernel<<<8, blk, 0, stream>>>((int*)scores, 64 + 1024);
        bucket_scatter_kernel<<<nbChunk, blk, 0, stream>>>(
            ei_in, ei_out, ei_sp, E_IN, E_OUT, E_SP, NT, NA, bcur, ebuf, E_TOT, NBUCK, cap);
        scanb_kernel<<<1, 1024, 0, stream>>>(bcur, boff, rowptrAll, NBUCK, cap, NCAT);
        bucket_csr_kernel<<<NBUCK, blk, 0, stream>>>(ebuf, boff, rowptrAll, colAll, NCAT, cap);
    } else {
        zero_int_kernel<<<2048, blk, 0, stream>>>(tmp, (long)tmp_span);
        hist_kernel<<<nbE, blk, 0, stream>>>(ei_in, ei_out, ei_sp, E_IN, E_OUT, E_SP, NT, NA, tmp, E_TOT);
        scan1_kernel<<<nbScan, blk, 0, stream>>>(tmp, rowptrAll, bsum, NCAT);
        scan2_kernel<<<1, 1024, 0, stream>>>(bsum, nbScan);
        scan3_kernel<<<(NCAT + 255) / 256, blk, 0, stream>>>(rowptrAll, bsum, tmp, NCAT, E_TOT);
        scatter_kernel<<<nbE, blk, 0, stream>>>(ei_in, ei_out, ei_sp, E_IN, E_OUT, E_SP, NT, NA, tmp, colAll, E_TOT);
    }

    // ---- fused encoder + layer-0 projection ----
    encproj_addr_kernel<<<nbAe, blk, 0, stream>>>(
        x_addr, enc_w_addr, enc_b_addr, pw_a, pb_a,
        att_src + 0 * 32, att_dst + 1 * 32,
        xa, h_a, has0, adst1a, NA, GPB_E);
    encproj_tx_kernel<<<nbTe, blk, 0, stream>>>(
        x_tx, enc_w_tx, enc_b_tx, pw_t, pb_t,
        att_src + 1 * 32, att_dst + 0 * 32, att_src + 2 * 32, att_dst + 2 * 32,
        xt, h_t, has1, adst0t, has2, adst2t, NT, GPB_E);

    auto agg_launch = [&](int mode, int nRows, const float* kw, const float* kb,
                          const float* q, float* sc) {
        int blocks = (nRows + 63) / 64;
        if (blocks > 2048) blocks = 2048;
        agg_all_kernel<<<blocks, blk, 0, stream>>>(
            rowptrAll, colAll, h_a, h_t,
            has0, adst0t, has1, adst1a, has2, adst2t,
            agg_t0, agg_a, agg_t2, kw, kb, q, sc, NT, NA, mode, nRows);
    };

    for (int l = 0; l < NLAYERS; l++) {
        bool last = (l == NLAYERS - 1);
        const float* kw = klw + l * 1024;
        const float* kb = klb + l * 32;
        const float* q  = qv + l * 32;
        float* sc = scores + 2 * l;
        if (!last) {
            if (roomy) {
                agg_launch(0, NCAT, kw, kb, q, sc);
            } else {
                agg_launch(1, 2 * NT, kw, kb, q, sc);
                agg_launch(2, NA, kw, kb, q, sc);
            }
            int lp = l + 1;
            combineproj_kernel<<<nbAcp + nbTcp, blk, 0, stream>>>(
                agg_a, agg_t0, agg_t2, xa, xt,
                ln_ag, ln_ab, ln_tg, ln_tb,
                sc, 1.0f / (float)NT,
                pw_a + lp * 1024, pb_a + lp * 32, pw_t + lp * 1024, pb_t + lp * 32,
                att_src + (lp * 3 + 0) * 32, att_dst + (lp * 3 + 1) * 32,
                att_src + (lp * 3 + 1) * 32, att_dst + (lp * 3 + 0) * 32,
                att_src + (lp * 3 + 2) * 32, att_dst + (lp * 3 + 2) * 32,
                h_a, h_t,
                has0, adst1a, has1, adst0t, has2, adst2t,
                NA, NT, nbAcp, GPB_C, lp == 3 ? 1 : 0);
        } else {
            agg_launch(2, NA, kw, kb, q, sc);
            combine_final_kernel<<<nbA8, blk, 0, stream>>>(agg_a, xa, ln_ag, ln_ab,
                                                           lin_w, lin_b, out, NA);
        }
    }
}

// Round 12
// 722.239 us; speedup vs baseline: 1.1458x; 1.0102x over previous
//
#include <hip/hip_runtime.h>
#include <hip/hip_fp16.h>

#define NLAYERS 4
#define BSHIFT 10   // 1024 rows per bucket
#define CHUNK 4096  // edges per bucket_scatter block (16/thread, register-staged)

typedef _Float16 f16x8 __attribute__((ext_vector_type(8)));
typedef float f32x4 __attribute__((ext_vector_type(4)));

// ---------------- zero fill ----------------
__global__ void zero_int_kernel(int* __restrict__ p, long n) {
    long i = (long)blockIdx.x * 256 + threadIdx.x;
    long stride = (long)gridDim.x * 256;
    for (; i < n; i += stride) p[i] = 0;
}

__device__ __forceinline__ float fast_tanh(float y) {
    y = fminf(fmaxf(y, -15.f), 15.f);
    float t = __expf(2.f * y);
    return (t - 1.f) / (t + 1.f);
}

// ================= CSR build over concatenated dst space =================
// [0,NT) rel0 dsts | [NT,NT+NA) rel1 dsts | [NT+NA,NCAT) rel2 dsts
__device__ __forceinline__ int edge_row(const int* ei_in, const int* ei_out, const int* ei_sp,
                                        int E_IN, int E_OUT, int E_SP, int NT, int NA,
                                        int e, int* src) {
    if (e < E_IN) { *src = ei_in[e]; return ei_in[E_IN + e]; }
    if (e < E_IN + E_OUT) { int i = e - E_IN; *src = ei_out[i]; return NT + ei_out[E_OUT + i]; }
    int i = e - E_IN - E_OUT; *src = ei_sp[i]; return NT + NA + ei_sp[E_SP + i];
}

// legacy direct hist/scatter (fallback when no workspace room for bucket buffer)
__global__ void hist_kernel(const int* __restrict__ ei_in, const int* __restrict__ ei_out,
                            const int* __restrict__ ei_sp, int E_IN, int E_OUT, int E_SP,
                            int NT, int NA, int* __restrict__ deg, int E_TOT) {
    int e = blockIdx.x * 256 + threadIdx.x;
    if (e >= E_TOT) return;
    int s;
    int row = edge_row(ei_in, ei_out, ei_sp, E_IN, E_OUT, E_SP, NT, NA, e, &s);
    atomicAdd(&deg[row], 1);
}

__global__ void scatter_kernel(const int* __restrict__ ei_in, const int* __restrict__ ei_out,
                               const int* __restrict__ ei_sp, int E_IN, int E_OUT, int E_SP,
                               int NT, int NA, int* __restrict__ cursor, int* __restrict__ col,
                               int E_TOT) {
    int e = blockIdx.x * 256 + threadIdx.x;
    if (e >= E_TOT) return;
    int s;
    int row = edge_row(ei_in, ei_out, ei_sp, E_IN, E_OUT, E_SP, NT, NA, e, &s);
    int pos = atomicAdd(&cursor[row], 1);
    col[pos] = s;
}

__global__ void scan1_kernel(const int* __restrict__ deg, int* __restrict__ rowptr,
                             int* __restrict__ bsum, int n) {
    __shared__ int lds[256];
    int tid = threadIdx.x;
    int base = blockIdx.x * 1024;
    int v[4];
    int mysum = 0;
    #pragma unroll
    for (int j = 0; j < 4; j++) {
        int idx = base + tid * 4 + j;
        v[j] = (idx < n) ? deg[idx] : 0;
        mysum += v[j];
    }
    lds[tid] = mysum;
    __syncthreads();
    for (int off = 1; off < 256; off <<= 1) {
        int t = (tid >= off) ? lds[tid - off] : 0;
        __syncthreads();
        lds[tid] += t;
        __syncthreads();
    }
    int excl = lds[tid] - mysum;
    if (tid == 255) bsum[blockIdx.x] = lds[tid];
    int run = excl;
    #pragma unroll
    for (int j = 0; j < 4; j++) {
        int idx = base + tid * 4 + j;
        if (idx < n) rowptr[idx] = run;
        run += v[j];
    }
}

__global__ void scan2_kernel(int* __restrict__ bsum, int nb) {
    __shared__ int lds[1024];
    int tid = threadIdx.x;
    int v = (tid < nb) ? bsum[tid] : 0;
    lds[tid] = v;
    __syncthreads();
    for (int off = 1; off < 1024; off <<= 1) {
        int t = (tid >= off) ? lds[tid - off] : 0;
        __syncthreads();
        lds[tid] += t;
        __syncthreads();
    }
    if (tid < nb) bsum[tid] = lds[tid] - v;
}

__global__ void scan3_kernel(int* __restrict__ rowptr, const int* __restrict__ bsum,
                             int* __restrict__ cursor, int n, int E) {
    int i = blockIdx.x * 256 + threadIdx.x;
    if (i < n) {
        int r = rowptr[i] + bsum[i >> 10];
        rowptr[i] = r;
        cursor[i] = r;
    }
    if (i == 0) rowptr[n] = E;
}

// ---- bucketed CSR build, pass 1: single global read; edges register-staged ----
__global__ void __launch_bounds__(256) bucket_scatter_kernel(
    const int* __restrict__ ei_in, const int* __restrict__ ei_out,
    const int* __restrict__ ei_sp, int E_IN, int E_OUT, int E_SP,
    int NT, int NA, int* __restrict__ bcur,
    uint2* __restrict__ ebuf, int E_TOT, int nbuck, int cap) {
    __shared__ int lc[1024], lbase[1024], lcur[1024];
    int tid = threadIdx.x;
    int chunk0 = blockIdx.x * CHUNK;
    int chunkN = E_TOT - chunk0;
    if (chunkN > CHUNK) chunkN = CHUNK;
    if (chunkN <= 0) return;
    for (int i = tid; i < nbuck; i += 256) { lc[i] = 0; lcur[i] = 0; }
    __syncthreads();
    uint2 er[CHUNK / 256];
    #pragma unroll
    for (int j = 0; j < CHUNK / 256; j++) {
        int i = tid + j * 256;   // coalesced within each sub-pass
        if (i < chunkN) {
            int s;
            int row = edge_row(ei_in, ei_out, ei_sp, E_IN, E_OUT, E_SP, NT, NA, chunk0 + i, &s);
            er[j] = make_uint2((unsigned)row, (unsigned)s);
            atomicAdd(&lc[row >> BSHIFT], 1);
        } else {
            er[j].x = 0xFFFFFFFFu;
        }
    }
    __syncthreads();
    for (int i = tid; i < nbuck; i += 256) if (lc[i]) lbase[i] = atomicAdd(&bcur[i], lc[i]);
    __syncthreads();
    #pragma unroll
    for (int j = 0; j < CHUNK / 256; j++) {
        if (er[j].x != 0xFFFFFFFFu) {
            int b = (int)(er[j].x >> BSHIFT);
            int pos = lbase[b] + atomicAdd(&lcur[b], 1);
            if (pos < cap) ebuf[(size_t)b * cap + pos] = er[j];
        }
    }
}

// ---- pass 2: exclusive scan of bucket counts -> global col offsets ----
__global__ void scanb_kernel(const int* __restrict__ bcur, int* __restrict__ boff,
                             int* __restrict__ rowptr, int nbuck, int cap, int NCAT) {
    __shared__ int lds[1024];
    int tid = threadIdx.x;
    int v = 0;
    if (tid < nbuck) { v = bcur[tid]; if (v > cap) v = cap; }
    lds[tid] = v;
    __syncthreads();
    for (int off = 1; off < 1024; off <<= 1) {
        int t = (tid >= off) ? lds[tid - off] : 0;
        __syncthreads();
        lds[tid] += t;
        __syncthreads();
    }
    if (tid < nbuck) boff[tid] = lds[tid] - v;
    if (tid == 1023) {
        boff[nbuck] = lds[1023];
        rowptr[NCAT] = lds[1023];
    }
}

// ---- pass 3: one block per bucket; LDS hist + LDS scan + LDS-cursor scatter ----
__global__ void __launch_bounds__(256) bucket_csr_kernel(
    const uint2* __restrict__ ebuf, const int* __restrict__ boff,
    int* __restrict__ rowptr, int* __restrict__ col, int NCAT, int cap) {
    __shared__ int ldeg[1024];
    __shared__ int lsum[256];
    int tid = threadIdx.x;
    int b = blockIdx.x;
    int row0 = b << BSHIFT;
    int e0 = boff[b], e1 = boff[b + 1];
    int cnt = e1 - e0;
    const uint2* src = ebuf + (size_t)b * cap;
    for (int i = tid; i < 1024; i += 256) ldeg[i] = 0;
    __syncthreads();
    for (int i = tid; i < cnt; i += 256)
        atomicAdd(&ldeg[src[i].x - (unsigned)row0], 1);
    __syncthreads();
    int bidx = tid * 4;
    int v0 = ldeg[bidx], v1 = ldeg[bidx + 1], v2 = ldeg[bidx + 2], v3 = ldeg[bidx + 3];
    int mysum = v0 + v1 + v2 + v3;
    lsum[tid] = mysum;
    __syncthreads();
    for (int off = 1; off < 256; off <<= 1) {
        int t = (tid >= off) ? lsum[tid - off] : 0;
        __syncthreads();
        lsum[tid] += t;
        __syncthreads();
    }
    int run = e0 + lsum[tid] - mysum;
    int vv[4] = {v0, v1, v2, v3};
    #pragma unroll
    for (int j = 0; j < 4; j++) {
        int r = bidx + j;
        if (row0 + r < NCAT) rowptr[row0 + r] = run;
        ldeg[r] = run;          // becomes the cursor
        run += vv[j];
    }
    __syncthreads();
    for (int i = tid; i < cnt; i += 256) {
        uint2 p = src[i];
        int pos = atomicAdd(&ldeg[p.x - (unsigned)row0], 1);
        col[pos] = (int)p.y;
    }
}

// ================= fused encoder + layer-0 projection (MFMA, 1 wave = 16 nodes) =================
__global__ void __launch_bounds__(256) encproj_addr_kernel(
    const float* __restrict__ x,
    const float* __restrict__ We, const float* __restrict__ be,
    const float* __restrict__ Wp, const float* __restrict__ bp,
    const float* __restrict__ a0, const float* __restrict__ a1,
    float* __restrict__ xa, __half* __restrict__ h,
    __half* __restrict__ o0, float* __restrict__ o1,
    int n, int gpb) {
    __shared__ __align__(16) float lds_t[4][16][36];
    __shared__ float sx[4][16 * 57];
    int tid = threadIdx.x;
    int wave = tid >> 6, lane = tid & 63;
    int colid = lane & 15, kgrp = lane >> 4;
    int fbase = kgrp * 8;

    f16x8 bE00, bE01, bE10, bE11;
    #pragma unroll
    for (int j = 0; j < 8; j++) {
        int k0 = fbase + j;
        int k1 = 32 + fbase + j;
        bE00[j] = (_Float16)We[k0 * 32 + colid];
        bE01[j] = (_Float16)We[k0 * 32 + 16 + colid];
        float w10 = (k1 < 53) ? We[k1 * 32 + colid] : 0.f;
        float w11 = (k1 < 53) ? We[k1 * 32 + 16 + colid] : 0.f;
        bE10[j] = (_Float16)w10;
        bE11[j] = (_Float16)w11;
    }
    float beC0 = be[colid], beC1 = be[16 + colid];

    f16x8 bP0, bP1;
    #pragma unroll
    for (int j = 0; j < 8; j++) {
        bP0[j] = (_Float16)Wp[(fbase + j) * 32 + colid];
        bP1[j] = (_Float16)Wp[(fbase + j) * 32 + 16 + colid];
    }
    float bpC0 = bp[colid], bpC1 = bp[16 + colid];

    float va0[8], va1[8];
    #pragma unroll
    for (int j = 0; j < 8; j++) { va0[j] = a0[fbase + j]; va1[j] = a1[fbase + j]; }

    float (*tp)[36] = lds_t[wave];
    float* sxw = sx[wave];
    int blockBase = blockIdx.x * gpb * 64;
    for (int gi = 0; gi < gpb; gi++) {
        int node0 = blockBase + gi * 64 + wave * 16;
        int node = node0 + colid;
        bool valid = node < n;
        int nn = n - node0;
        if (nn > 16) nn = 16;
        if (nn < 0) nn = 0;
        int elems = nn * 53;
        for (int i = lane; i < elems; i += 64) {
            int r = i / 53, c = i - r * 53;
            sxw[r * 57 + c] = x[(size_t)node0 * 53 + i];
        }
        f16x8 af0, af1;
        #pragma unroll
        for (int j = 0; j < 8; j++) {
            af0[j] = (_Float16)sxw[colid * 57 + fbase + j];
            int kk = 32 + fbase + j;
            float v1 = (kk < 53) ? sxw[colid * 57 + kk] : 0.f;
            af1[j] = (_Float16)v1;
        }
        f32x4 c0 = {0.f, 0.f, 0.f, 0.f};
        f32x4 c1 = {0.f, 0.f, 0.f, 0.f};
        c0 = __builtin_amdgcn_mfma_f32_16x16x32_f16(af0, bE00, c0, 0, 0, 0);
        c0 = __builtin_amdgcn_mfma_f32_16x16x32_f16(af1, bE10, c0, 0, 0, 0);
        c1 = __builtin_amdgcn_mfma_f32_16x16x32_f16(af0, bE01, c1, 0, 0, 0);
        c1 = __builtin_amdgcn_mfma_f32_16x16x32_f16(af1, bE11, c1, 0, 0, 0);
        #pragma unroll
        for (int r = 0; r < 4; r++) {
            c0[r] = fmaxf(c0[r] + beC0, 0.f);
            c1[r] = fmaxf(c1[r] + beC1, 0.f);
        }
        #pragma unroll
        for (int r = 0; r < 4; r++) {
            int row = kgrp * 4 + r;
            tp[row][colid] = c0[r];
            tp[row][16 + colid] = c1[r];
        }
        float4 xlo = *(const float4*)&tp[colid][fbase];
        float4 xhi = *(const float4*)&tp[colid][fbase + 4];
        float xe[8] = {xlo.x, xlo.y, xlo.z, xlo.w, xhi.x, xhi.y, xhi.z, xhi.w};
        if (valid) {
            size_t basep = (size_t)node * 32 + fbase;
            *(float4*)(xa + basep) = xlo;
            *(float4*)(xa + basep + 4) = xhi;
        }
        f16x8 af;
        #pragma unroll
        for (int j = 0; j < 8; j++) af[j] = (_Float16)xe[j];
        f32x4 p0 = {0.f, 0.f, 0.f, 0.f};
        f32x4 p1 = {0.f, 0.f, 0.f, 0.f};
        p0 = __builtin_amdgcn_mfma_f32_16x16x32_f16(af, bP0, p0, 0, 0, 0);
        p1 = __builtin_amdgcn_mfma_f32_16x16x32_f16(af, bP1, p1, 0, 0, 0);
        #pragma unroll
        for (int r = 0; r < 4; r++) { p0[r] += bpC0; p1[r] += bpC1; }
        #pragma unroll
        for (int r = 0; r < 4; r++) {
            int row = kgrp * 4 + r;
            tp[row][colid] = p0[r];
            tp[row][16 + colid] = p1[r];
        }
        float4 hlo = *(const float4*)&tp[colid][fbase];
        float4 hhi = *(const float4*)&tp[colid][fbase + 4];
        float hv[8] = {hlo.x, hlo.y, hlo.z, hlo.w, hhi.x, hhi.y, hhi.z, hhi.w};
        if (valid) {
            float4 hout;
            __half2* hp2 = (__half2*)&hout;
            hp2[0] = __floats2half2_rn(hv[0], hv[1]);
            hp2[1] = __floats2half2_rn(hv[2], hv[3]);
            hp2[2] = __floats2half2_rn(hv[4], hv[5]);
            hp2[3] = __floats2half2_rn(hv[6], hv[7]);
            *(float4*)(h + (size_t)node * 32 + fbase) = hout;
            float d0 = 0.f, d1 = 0.f;
            #pragma unroll
            for (int j = 0; j < 8; j++) {
                d0 += hv[j] * va0[j];
                d1 += hv[j] * va1[j];
            }
            size_t oidx = (size_t)node * 4 + kgrp;
            o0[oidx] = __float2half(d0);
            o1[oidx] = d1;
        }
    }
}

__global__ void __launch_bounds__(256) encproj_tx_kernel(
    const float* __restrict__ x,
    const float* __restrict__ We, const float* __restrict__ be,
    const float* __restrict__ Wp, const float* __restrict__ bp,
    const float* __restrict__ a0, const float* __restrict__ a1,
    const float* __restrict__ a2, const float* __restrict__ a3,
    float* __restrict__ xt, __half* __restrict__ h,
    __half* __restrict__ o0, float* __restrict__ o1,
    __half* __restrict__ o2, float* __restrict__ o3,
    int n, int gpb) {
    __shared__ __align__(16) float lds_t[4][16][36];
    int tid = threadIdx.x;
    int wave = tid >> 6, lane = tid & 63;
    int colid = lane & 15, kgrp = lane >> 4;
    int fbase = kgrp * 8;

    f16x8 bE0, bE1;
    #pragma unroll
    for (int j = 0; j < 8; j++) {
        int k = fbase + j;
        float w0 = (k < 6) ? We[k * 32 + colid] : 0.f;
        float w1 = (k < 6) ? We[k * 32 + 16 + colid] : 0.f;
        bE0[j] = (_Float16)w0;
        bE1[j] = (_Float16)w1;
    }
    float beC0 = be[colid], beC1 = be[16 + colid];

    f16x8 bP0, bP1;
    #pragma unroll
    for (int j = 0; j < 8; j++) {
        bP0[j] = (_Float16)Wp[(fbase + j) * 32 + colid];
        bP1[j] = (_Float16)Wp[(fbase + j) * 32 + 16 + colid];
    }
    float bpC0 = bp[colid], bpC1 = bp[16 + colid];

    float va0[8], va1[8], va2[8], va3[8];
    #pragma unroll
    for (int j = 0; j < 8; j++) {
        va0[j] = a0[fbase + j]; va1[j] = a1[fbase + j];
        va2[j] = a2[fbase + j]; va3[j] = a3[fbase + j];
    }

    float (*tp)[36] = lds_t[wave];
    int blockBase = blockIdx.x * gpb * 64;
    for (int gi = 0; gi < gpb; gi++) {
        int node = blockBase + gi * 64 + wave * 16 + colid;
        bool valid = node < n;
        f16x8 af0;
        #pragma unroll
        for (int j = 0; j < 8; j++) {
            int k = fbase + j;
            float xv = 0.f;
            if (k < 6 && valid) xv = x[(size_t)node * 6 + k];
            af0[j] = (_Float16)xv;
        }
        f32x4 c0 = {0.f, 0.f, 0.f, 0.f};
        f32x4 c1 = {0.f, 0.f, 0.f, 0.f};
        c0 = __builtin_amdgcn_mfma_f32_16x16x32_f16(af0, bE0, c0, 0, 0, 0);
        c1 = __builtin_amdgcn_mfma_f32_16x16x32_f16(af0, bE1, c1, 0, 0, 0);
        #pragma unroll
        for (int r = 0; r < 4; r++) {
            c0[r] = fmaxf(c0[r] + beC0, 0.f);
            c1[r] = fmaxf(c1[r] + beC1, 0.f);
        }
        #pragma unroll
        for (int r = 0; r < 4; r++) {
            int row = kgrp * 4 + r;
            tp[row][colid] = c0[r];
            tp[row][16 + colid] = c1[r];
        }
        float4 xlo = *(const float4*)&tp[colid][fbase];
        float4 xhi = *(const float4*)&tp[colid][fbase + 4];
        float xe[8] = {xlo.x, xlo.y, xlo.z, xlo.w, xhi.x, xhi.y, xhi.z, xhi.w};
        if (valid) {
            size_t basep = (size_t)node * 32 + fbase;
            *(float4*)(xt + basep) = xlo;
            *(float4*)(xt + basep + 4) = xhi;
        }
        f16x8 af;
        #pragma unroll
        for (int j = 0; j < 8; j++) af[j] = (_Float16)xe[j];
        f32x4 p0 = {0.f, 0.f, 0.f, 0.f};
        f32x4 p1 = {0.f, 0.f, 0.f, 0.f};
        p0 = __builtin_amdgcn_mfma_f32_16x16x32_f16(af, bP0, p0, 0, 0, 0);
        p1 = __builtin_amdgcn_mfma_f32_16x16x32_f16(af, bP1, p1, 0, 0, 0);
        #pragma unroll
        for (int r = 0; r < 4; r++) { p0[r] += bpC0; p1[r] += bpC1; }
        #pragma unroll
        for (int r = 0; r < 4; r++) {
            int row = kgrp * 4 + r;
            tp[row][colid] = p0[r];
            tp[row][16 + colid] = p1[r];
        }
        float4 hlo = *(const float4*)&tp[colid][fbase];
        float4 hhi = *(const float4*)&tp[colid][fbase + 4];
        float hv[8] = {hlo.x, hlo.y, hlo.z, hlo.w, hhi.x, hhi.y, hhi.z, hhi.w};
        if (valid) {
            float4 hout;
            __half2* hp2 = (__half2*)&hout;
            hp2[0] = __floats2half2_rn(hv[0], hv[1]);
            hp2[1] = __floats2half2_rn(hv[2], hv[3]);
            hp2[2] = __floats2half2_rn(hv[4], hv[5]);
            hp2[3] = __floats2half2_rn(hv[6], hv[7]);
            *(float4*)(h + (size_t)node * 32 + fbase) = hout;
            float d0 = 0.f, d1 = 0.f, d2 = 0.f, d3 = 0.f;
            #pragma unroll
            for (int j = 0; j < 8; j++) {
                d0 += hv[j] * va0[j];
                d1 += hv[j] * va1[j];
                d2 += hv[j] * va2[j];
                d3 += hv[j] * va3[j];
            }
            size_t oidx = (size_t)node * 4 + kgrp;
            o0[oidx] = __float2half(d0);
            o1[oidx] = d1;
            o2[oidx] = __float2half(d2);
            o3[oidx] = d3;
        }
    }
}

// ================= merged CSR aggregation (all rels) + MFMA-fused semantic score =================
// 4 lanes/row (lane = head, 8 features/lane), 16 rows/wave. Score: lane-permute the
// 16x32 relu(agg) tile into an MFMA A-fragment -> 2 MFMAs replace ~270 VALU ops/row.
__global__ void __launch_bounds__(256) agg_all_kernel(
    const int* __restrict__ rowptr, const int* __restrict__ col,
    const __half* __restrict__ h_a, const __half* __restrict__ h_t,
    const __half* __restrict__ asrc0, const float* __restrict__ adst0,
    const __half* __restrict__ asrc1, const float* __restrict__ adst1,
    const __half* __restrict__ asrc2, const float* __restrict__ adst2,
    __half* __restrict__ agg_t0, __half* __restrict__ agg_a, __half* __restrict__ agg_t2,
    const float* __restrict__ kw, const float* __restrict__ kb, const float* __restrict__ q,
    float* __restrict__ scoreOut, int NT, int NA, int mode, int nRows) {
    __shared__ float sScore[2];
    int tid = threadIdx.x;
    bool doScore = (mode != 2);
    if (tid < 2) sScore[tid] = 0.f;
    __syncthreads();
    int lane64 = tid & 63;
    int wave = tid >> 6;
    int lane = tid & 3;        // head
    int wr = lane64 >> 2;      // row within wave 0..15
    int f0 = lane * 8;         // feature base (8 features per lane)
    // MFMA-frag coords (score)
    int colid = lane64 & 15, kgrp = lane64 >> 4;
    f16x8 bK0 = {}, bK1 = {};
    float kb0 = 0.f, kb1 = 0.f, q0 = 0.f, q1 = 0.f;
    if (doScore) {
        #pragma unroll
        for (int j = 0; j < 8; j++) {
            bK0[j] = (_Float16)kw[(kgrp * 8 + j) * 32 + colid];
            bK1[j] = (_Float16)kw[(kgrp * 8 + j) * 32 + 16 + colid];
        }
        kb0 = kb[colid]; kb1 = kb[16 + colid];
        q0 = q[colid];  q1 = q[16 + colid];
    }
    int srcl = ((lane64 & 15) << 2) | (lane64 >> 4);   // A-frag lane permutation
    float s0acc = 0.f, s2acc = 0.f;
    long stride = (long)gridDim.x * 64;
    for (long wbase = (long)blockIdx.x * 64 + wave * 16; wbase < (long)nRows; wbase += stride) {
        long gi = wbase + wr;
        bool valid = gi < (long)nRows;
        long gc = valid ? gi : (long)nRows - 1;
        int row;
        if (mode == 0) row = (int)gc;
        else if (mode == 1) row = (gc < NT) ? (int)gc : (int)(gc + NA);
        else row = NT + (int)gc;
        int dst;
        const __half* h; const __half* asrc; const float* adp; __half* agg;
        if (row < NT)           { dst = row;           h = h_a; asrc = asrc0; adp = adst0; agg = agg_t0; }
        else if (row < NT + NA) { dst = row - NT;      h = h_t; asrc = asrc1; adp = adst1; agg = agg_a; }
        else                    { dst = row - NT - NA; h = h_t; asrc = asrc2; adp = adst2; agg = agg_t2; }
        float ad = adp[dst * 4 + lane];
        int e0 = rowptr[row], e1 = rowptr[row + 1];
        __half2 acc0 = __floats2half2_rn(0.f, 0.f);
        __half2 acc1 = acc0, acc2 = acc0, acc3 = acc0;
        float den = 0.f;
        for (int e = e0; e < e1; e += 4) {
            int s0 = col[e];
            int s1 = (e + 1 < e1) ? col[e + 1] : s0;
            int s2 = (e + 2 < e1) ? col[e + 2] : s0;
            int s3 = (e + 3 < e1) ? col[e + 3] : s0;
            float as0 = __half2float(asrc[s0 * 4 + lane]);
            float as1 = __half2float(asrc[s1 * 4 + lane]);
            float as2 = __half2float(asrc[s2 * 4 + lane]);
            float as3 = __half2float(asrc[s3 * 4 + lane]);
            float4 r0 = *(const float4*)(h + s0 * 32 + f0);
            float4 r1 = *(const float4*)(h + s1 * 32 + f0);
            float4 r2 = *(const float4*)(h + s2 * 32 + f0);
            float4 r3 = *(const float4*)(h + s3 * 32 + f0);
            float t0 = as0 + ad; t0 = t0 > 0.f ? t0 : 0.2f * t0;
            float t1 = as1 + ad; t1 = t1 > 0.f ? t1 : 0.2f * t1;
            float t2 = as2 + ad; t2 = t2 > 0.f ? t2 : 0.2f * t2;
            float t3 = as3 + ad; t3 = t3 > 0.f ? t3 : 0.2f * t3;
            float ex0 = __expf(t0);
            float ex1 = (e + 1 < e1) ? __expf(t1) : 0.f;
            float ex2 = (e + 2 < e1) ? __expf(t2) : 0.f;
            float ex3 = (e + 3 < e1) ? __expf(t3) : 0.f;
            den += (ex0 + ex1) + (ex2 + ex3);
            __half2 eh0 = __float2half2_rn(ex0), eh1 = __float2half2_rn(ex1);
            __half2 eh2 = __float2half2_rn(ex2), eh3 = __float2half2_rn(ex3);
            const __half2* h0 = (const __half2*)&r0;
            const __half2* h1 = (const __half2*)&r1;
            const __half2* h2 = (const __half2*)&r2;
            const __half2* h3 = (const __half2*)&r3;
            acc0 = __hfma2(eh0, h0[0], acc0);
            acc1 = __hfma2(eh0, h0[1], acc1);
            acc2 = __hfma2(eh0, h0[2], acc2);
            acc3 = __hfma2(eh0, h0[3], acc3);
            acc0 = __hfma2(eh1, h1[0], acc0);
            acc1 = __hfma2(eh1, h1[1], acc1);
            acc2 = __hfma2(eh1, h1[2], acc2);
            acc3 = __hfma2(eh1, h1[3], acc3);
            acc0 = __hfma2(eh2, h2[0], acc0);
            acc1 = __hfma2(eh2, h2[1], acc1);
            acc2 = __hfma2(eh2, h2[2], acc2);
            acc3 = __hfma2(eh2, h2[3], acc3);
            acc0 = __hfma2(eh3, h3[0], acc0);
            acc1 = __hfma2(eh3, h3[1], acc1);
            acc2 = __hfma2(eh3, h3[2], acc2);
            acc3 = __hfma2(eh3, h3[3], acc3);
        }
        float r = 1.f / (den + 1e-16f);
        float2 a0 = __half22float2(acc0), a1 = __half22float2(acc1);
        float2 a2 = __half22float2(acc2), a3 = __half22float2(acc3);
        float v[8] = {a0.x * r, a0.y * r, a1.x * r, a1.y * r,
                      a2.x * r, a2.y * r, a3.x * r, a3.y * r};
        float4 opack;
        __half2* op2 = (__half2*)&opack;
        op2[0] = __floats2half2_rn(v[0], v[1]);
        op2[1] = __floats2half2_rn(v[2], v[3]);
        op2[2] = __floats2half2_rn(v[4], v[5]);
        op2[3] = __floats2half2_rn(v[6], v[7]);
        if (valid) *(float4*)(agg + dst * 32 + f0) = opack;
        if (doScore) {
            // skip waves entirely inside the rel1 (addr-dst) band
            bool skipAll = (mode == 0) && (wbase >= (long)NT) && (wbase + 15 < (long)NT + NA);
            if (!skipAll) {
                float z = 0.f;
                __half2 ph0 = __floats2half2_rn(valid ? fmaxf(v[0], z) : z, valid ? fmaxf(v[1], z) : z);
                __half2 ph1 = __floats2half2_rn(valid ? fmaxf(v[2], z) : z, valid ? fmaxf(v[3], z) : z);
                __half2 ph2 = __floats2half2_rn(valid ? fmaxf(v[4], z) : z, valid ? fmaxf(v[5], z) : z);
                __half2 ph3 = __floats2half2_rn(valid ? fmaxf(v[6], z) : z, valid ? fmaxf(v[7], z) : z);
                int4 uu;
                uu.x = __shfl(*(int*)&ph0, srcl, 64);
                uu.y = __shfl(*(int*)&ph1, srcl, 64);
                uu.z = __shfl(*(int*)&ph2, srcl, 64);
                uu.w = __shfl(*(int*)&ph3, srcl, 64);
                f16x8 afrag = *(f16x8*)&uu;
                f32x4 y0 = {0.f, 0.f, 0.f, 0.f};
                f32x4 y1 = {0.f, 0.f, 0.f, 0.f};
                y0 = __builtin_amdgcn_mfma_f32_16x16x32_f16(afrag, bK0, y0, 0, 0, 0);
                y1 = __builtin_amdgcn_mfma_f32_16x16x32_f16(afrag, bK1, y1, 0, 0, 0);
                #pragma unroll
                for (int rr = 0; rr < 4; rr++) {
                    long gr = wbase + (long)(kgrp * 4 + rr);
                    if (gr < (long)nRows) {
                        bool isRel1, b0;
                        if (mode == 0) {
                            isRel1 = (gr >= (long)NT) && (gr < (long)NT + NA);
                            b0 = gr < (long)NT;
                        } else {
                            isRel1 = false;
                            b0 = gr < (long)NT;
                        }
                        if (!isRel1) {
                            float t = q0 * fast_tanh(y0[rr] + kb0) + q1 * fast_tanh(y1[rr] + kb1);
                            if (b0) s0acc += t; else s2acc += t;
                        }
                    }
                }
            }
        }
    }
    if (doScore) {
        #pragma unroll
        for (int m = 1; m < 64; m <<= 1) {
            s0acc += __shfl_xor(s0acc, m, 64);
            s2acc += __shfl_xor(s2acc, m, 64);
        }
        if (lane64 == 0) {
            atomicAdd(&sScore[0], s0acc);
            atomicAdd(&sScore[1], s2acc);
        }
        __syncthreads();
        if (tid < 2) unsafeAtomicAdd(scoreOut + tid, sScore[tid]);
    }
}

// ================= fused combine + next-layer projection (MFMA, 1 wave = 16 nodes) =================
__global__ void __launch_bounds__(256) combineproj_kernel(
    const __half* __restrict__ agg_a, const __half* __restrict__ agg_t0, const __half* __restrict__ agg_t2,
    float* __restrict__ xa, float* __restrict__ xt,
    const float* __restrict__ ln_ag, const float* __restrict__ ln_ab,
    const float* __restrict__ ln_tg, const float* __restrict__ ln_tb,
    const float* __restrict__ scores, float invNT,
    const float* __restrict__ Wa, const float* __restrict__ Ba,
    const float* __restrict__ Wt, const float* __restrict__ Bt,
    const float* __restrict__ as0, const float* __restrict__ ad1,
    const float* __restrict__ as1, const float* __restrict__ ad0,
    const float* __restrict__ as2, const float* __restrict__ ad2,
    __half* __restrict__ h_a, __half* __restrict__ h_t,
    __half* __restrict__ o_as0, float* __restrict__ o_ad1,
    __half* __restrict__ o_as1, float* __restrict__ o_ad0,
    __half* __restrict__ o_as2, float* __restrict__ o_ad2,
    int NA_, int NT_, int nbAcp, int gpb, int lastProj) {
    __shared__ __align__(16) float lds_t[4][16][36];
    int tid = threadIdx.x;
    int wave = tid >> 6;
    int lane = tid & 63;
    int colid = lane & 15;
    int kgrp = lane >> 4;
    int fbase = kgrp * 8;

    bool isA = blockIdx.x < (unsigned)nbAcp;
    const float* W = isA ? Wa : Wt;
    const float* Bp = isA ? Ba : Bt;
    int n = isA ? NA_ : NT_;

    f16x8 bf0, bf1;
    #pragma unroll
    for (int j = 0; j < 8; j++) {
        bf0[j] = (_Float16)W[(fbase + j) * 32 + colid];
        bf1[j] = (_Float16)W[(fbase + j) * 32 + 16 + colid];
    }
    float bp0 = Bp[colid], bp1 = Bp[16 + colid];

    const float* lng = isA ? ln_ag : ln_tg;
    const float* lnb = isA ? ln_ab : ln_tb;
    float g[8], bb[8];
    #pragma unroll
    for (int j = 0; j < 8; j++) { g[j] = lng[fbase + j]; bb[j] = lnb[fbase + j]; }

    float va0[8], va1[8], va2[8], va3[8];
    if (isA) {
        #pragma unroll
        for (int j = 0; j < 8; j++) { va0[j] = as0[fbase + j]; va1[j] = ad1[fbase + j]; }
    } else {
        #pragma unroll
        for (int j = 0; j < 8; j++) {
            va0[j] = as1[fbase + j]; va1[j] = ad0[fbase + j];
            va2[j] = as2[fbase + j]; va3[j] = ad2[fbase + j];
        }
    }

    float wsem0 = 0.f, wsem2 = 0.f;
    if (!isA) {
        float s0 = scores[0] * invNT, s2 = scores[1] * invNT;
        float mx = fmaxf(s0, s2);
        float e0 = __expf(s0 - mx), e2 = __expf(s2 - mx);
        float inv_s = 1.f / (e0 + e2);
        wsem0 = e0 * inv_s; wsem2 = e2 * inv_s;
    }

    float (*tp)[36] = lds_t[wave];
    int blockBase = (isA ? (int)blockIdx.x : (int)blockIdx.x - nbAcp) * gpb * 64;
    for (int gi = 0; gi < gpb; gi++) {
        int node = blockBase + gi * 64 + wave * 16 + colid;
        bool valid = node < n;
        float v[8];
        if (valid) {
            size_t base = (size_t)node * 32 + fbase;
            float4 xlo, xhi;
            if (isA) {
                xlo = *(const float4*)(xa + base);
                xhi = *(const float4*)(xa + base + 4);
                float4 ar = *(const float4*)(agg_a + base);
                const __half2* ah2 = (const __half2*)&ar;
                float2 f0 = __half22float2(ah2[0]);
                float2 f1 = __half22float2(ah2[1]);
                float2 f2 = __half22float2(ah2[2]);
                float2 f3 = __half22float2(ah2[3]);
                float av[8] = {f0.x, f0.y, f1.x, f1.y, f2.x, f2.y, f3.x, f3.y};
                float xv[8] = {xlo.x, xlo.y, xlo.z, xlo.w, xhi.x, xhi.y, xhi.z, xhi.w};
                #pragma unroll
                for (int j = 0; j < 8; j++) v[j] = fmaxf(av[j], 0.f) + xv[j];
            } else {
                xlo = *(const float4*)(xt + base);
                xhi = *(const float4*)(xt + base + 4);
                float4 a0r = *(const float4*)(agg_t0 + base);
                float4 a2r = *(const float4*)(agg_t2 + base);
                const __half2* a0h = (const __half2*)&a0r;
                const __half2* a2h = (const __half2*)&a2r;
                float xv[8] = {xlo.x, xlo.y, xlo.z, xlo.w, xhi.x, xhi.y, xhi.z, xhi.w};
                #pragma unroll
                for (int j = 0; j < 4; j++) {
                    float2 p0 = __half22float2(a0h[j]);
                    float2 p2 = __half22float2(a2h[j]);
                    float c0 = wsem0 * fmaxf(p0.x, 0.f) + wsem2 * fmaxf(p2.x, 0.f);
                    float c1 = wsem0 * fmaxf(p0.y, 0.f) + wsem2 * fmaxf(p2.y, 0.f);
                    v[2 * j]     = fmaxf(c0, 0.f) + xv[2 * j];
                    v[2 * j + 1] = fmaxf(c1, 0.f) + xv[2 * j + 1];
                }
            }
        } else {
            #pragma unroll
            for (int j = 0; j < 8; j++) v[j] = 0.f;
        }
        float s = 0.f;
        #pragma unroll
        for (int j = 0; j < 8; j++) s += v[j];
        s += __shfl_xor(s, 16, 64);
        s += __shfl_xor(s, 32, 64);
        float m = s * 0.03125f;
        float d[8], vv = 0.f;
        #pragma unroll
        for (int j = 0; j < 8; j++) { d[j] = v[j] - m; vv += d[j] * d[j]; }
        vv += __shfl_xor(vv, 16, 64);
        vv += __shfl_xor(vv, 32, 64);
        float inv = 1.f / sqrtf(vv * 0.03125f + 1e-5f);
        float ln[8];
        #pragma unroll
        for (int j = 0; j < 8; j++) ln[j] = d[j] * inv * g[j] + bb[j];

        if (valid && (isA || !lastProj)) {
            float* xp = isA ? xa : xt;
            size_t base = (size_t)node * 32 + fbase;
            *(float4*)(xp + base)     = make_float4(ln[0], ln[1], ln[2], ln[3]);
            *(float4*)(xp + base + 4) = make_float4(ln[4], ln[5], ln[6], ln[7]);
        }

        f16x8 af;
        #pragma unroll
        for (int j = 0; j < 8; j++) af[j] = (_Float16)ln[j];
        f32x4 c0 = {0.f, 0.f, 0.f, 0.f};
        f32x4 c1 = {0.f, 0.f, 0.f, 0.f};
        c0 = __builtin_amdgcn_mfma_f32_16x16x32_f16(af, bf0, c0, 0, 0, 0);
        c1 = __builtin_amdgcn_mfma_f32_16x16x32_f16(af, bf1, c1, 0, 0, 0);
        #pragma unroll
        for (int r = 0; r < 4; r++) { c0[r] += bp0; c1[r] += bp1; }

        #pragma unroll
        for (int r = 0; r < 4; r++) {
            int row = kgrp * 4 + r;
            tp[row][colid] = c0[r];
            tp[row][16 + colid] = c1[r];
        }
        float4 hlo = *(const float4*)&tp[colid][fbase];
        float4 hhi = *(const float4*)&tp[colid][fbase + 4];
        float hv[8] = {hlo.x, hlo.y, hlo.z, hlo.w, hhi.x, hhi.y, hhi.z, hhi.w};

        bool writeH = (!isA || !lastProj);
        if (valid && writeH) {
            float4 hout;
            __half2* hp2 = (__half2*)&hout;
            hp2[0] = __floats2half2_rn(hv[0], hv[1]);
            hp2[1] = __floats2half2_rn(hv[2], hv[3]);
            hp2[2] = __floats2half2_rn(hv[4], hv[5]);
            hp2[3] = __floats2half2_rn(hv[6], hv[7]);
            __half* hp = isA ? h_a : h_t;
            *(float4*)(hp + (size_t)node * 32 + fbase) = hout;
        }

        if (valid) {
            size_t oidx = (size_t)node * 4 + kgrp;
            if (isA) {
                if (!lastProj) {
                    float ds = 0.f;
                    #pragma unroll
                    for (int j = 0; j < 8; j++) ds += hv[j] * va0[j];
                    o_as0[oidx] = __float2half(ds);
                }
                float dd = 0.f;
                #pragma unroll
                for (int j = 0; j < 8; j++) dd += hv[j] * va1[j];
                o_ad1[oidx] = dd;
            } else {
                float d0 = 0.f;
                #pragma unroll
                for (int j = 0; j < 8; j++) d0 += hv[j] * va0[j];
                o_as1[oidx] = __float2half(d0);
                if (!lastProj) {
                    float d1 = 0.f, d2 = 0.f, d3 = 0.f;
                    #pragma unroll
                    for (int j = 0; j < 8; j++) {
                        d1 += hv[j] * va1[j];
                        d2 += hv[j] * va2[j];
                        d3 += hv[j] * va3[j];
                    }
                    o_ad0[oidx] = d1;
                    o_as2[oidx] = __float2half(d2);
                    o_ad2[oidx] = d3;
                }
            }
        }
    }
}

// ================= layer-3 combine_addr + output head =================
__global__ void combine_final_kernel(const __half* __restrict__ agg_a, const float* __restrict__ xa,
                                     const float* __restrict__ g, const float* __restrict__ bt,
                                     const float* __restrict__ lw, const float* __restrict__ lb,
                                     float* __restrict__ out, int n) {
    int tid = threadIdx.x;
    int local = tid >> 5, f = tid & 31;
    int node = blockIdx.x * 8 + local;
    if (node >= n) return;
    float a = __half2float(agg_a[(size_t)node * 32 + f]);
    float v = fmaxf(a, 0.f) + xa[(size_t)node * 32 + f];
    float m = v;
    #pragma unroll
    for (int mask = 1; mask < 32; mask <<= 1) m += __shfl_xor(m, mask, 64);
    m *= (1.f / 32.f);
    float d = v - m;
    float var = d * d;
    #pragma unroll
    for (int mask = 1; mask < 32; mask <<= 1) var += __shfl_xor(var, mask, 64);
    var *= (1.f / 32.f);
    float inv = 1.f / sqrtf(var + 1e-5f);
    float ln = d * inv * g[f] + bt[f];
    float p0 = ln * lw[f * 2 + 0];
    float p1 = ln * lw[f * 2 + 1];
    #pragma unroll
    for (int mask = 1; mask < 32; mask <<= 1) {
        p0 += __shfl_xor(p0, mask, 64);
        p1 += __shfl_xor(p1, mask, 64);
    }
    if (f == 0) {
        out[(size_t)node * 2 + 0] = p0 + lb[0];
        out[(size_t)node * 2 + 1] = p1 + lb[1];
    }
}

extern "C" void kernel_launch(void* const* d_in, const int* in_sizes, int n_in,
                              void* d_out, int out_size, void* d_ws, size_t ws_size,
                              hipStream_t stream) {
    const float* x_addr = (const float*)d_in[0];
    const float* x_tx   = (const float*)d_in[1];
    const int* ei_in    = (const int*)d_in[2];
    const int* ei_out   = (const int*)d_in[3];
    const int* ei_sp    = (const int*)d_in[4];
    const float* enc_w_addr = (const float*)d_in[5];
    const float* enc_b_addr = (const float*)d_in[6];
    const float* enc_w_tx   = (const float*)d_in[7];
    const float* enc_b_tx   = (const float*)d_in[8];
    const float* ln_ag = (const float*)d_in[9];
    const float* ln_ab = (const float*)d_in[10];
    const float* ln_tg = (const float*)d_in[11];
    const float* ln_tb = (const float*)d_in[12];
    const float* pw_a = (const float*)d_in[13];
    const float* pb_a = (const float*)d_in[14];
    const float* pw_t = (const float*)d_in[15];
    const float* pb_t = (const float*)d_in[16];
    const float* att_src = (const float*)d_in[17];
    const float* att_dst = (const float*)d_in[18];
    const float* klw = (const float*)d_in[19];
    const float* klb = (const float*)d_in[20];
    const float* qv  = (const float*)d_in[21];
    const float* lin_w = (const float*)d_in[22];
    const float* lin_b = (const float*)d_in[23];
    float* out = (float*)d_out;

    const int NA = in_sizes[0] / 53;
    const int NT = in_sizes[1] / 6;
    const int E_IN = in_sizes[2] / 2;
    const int E_OUT = in_sizes[3] / 2;
    const int E_SP = in_sizes[4] / 2;
    const int E_TOT = E_IN + E_OUT + E_SP;
    const int NCAT = NT + NA + NT;
    const int NBUCK = (NCAT + (1 << BSHIFT) - 1) >> BSHIFT;

    size_t off = 0;
    float* base = (float*)d_ws;
    auto alloc = [&](size_t nfloats) {
        float* p = base + off;
        off += (nfloats + 63) & ~(size_t)63;
        return p;
    };
    float* xa      = alloc((size_t)NA * 32);
    float* xt      = alloc((size_t)NT * 32);
    float* agg_a_f = alloc((size_t)NA * 16);
    float* agg_t0f = alloc((size_t)NT * 16);
    float* agg_t2f = alloc((size_t)NT * 16);
    float* h_t_f   = alloc((size_t)NT * 16);
    float* asrc0a  = alloc((size_t)NA * 2);   // fp16 x4 per node
    float* adst1a  = alloc((size_t)NA * 4);
    float* asrc1t  = alloc((size_t)NT * 2);   // fp16
    float* adst0t  = alloc((size_t)NT * 4);
    float* asrc2t  = alloc((size_t)NT * 2);   // fp16
    float* adst2t  = alloc((size_t)NT * 4);
    int* rowptrAll = (int*)alloc((size_t)NCAT + 64);
    int* colAll    = (int*)alloc((size_t)E_TOT);
    // legacy: tmp+bsum+scores+bcur zeroed together; bucket: scores+bcur only
    size_t tmp_span = (((size_t)NCAT + 63) & ~(size_t)63) + 1088 + 64 + 1024;
    int* tmp       = (int*)alloc((size_t)NCAT);
    int* bsum      = (int*)alloc(1088);
    float* scores  = alloc(64);
    int* bcur      = (int*)alloc(1024);
    int* boff      = (int*)alloc(1088);

    size_t ha_floats = (((size_t)NA * 16) + 63) & ~(size_t)63;
    bool roomy = ((off + ha_floats) * sizeof(float)) <= ws_size;
    float* h_a_f = roomy ? alloc((size_t)NA * 16) : agg_a_f;

    // bucketed edge pair buffer: fixed-capacity regions, cap = 1.25*avg + 256 (rounded to 256)
    int avgb = (int)(((long)E_TOT << BSHIFT) / (long)NCAT);
    int cap = ((avgb + avgb / 4 + 256) + 255) & ~255;
    size_t ebuf_floats = (size_t)NBUCK * (size_t)cap * 2;
    bool canBucket = (NBUCK <= 1024) &&
                     (((off + ebuf_floats + 64) * sizeof(float)) <= ws_size);
    uint2* ebuf = canBucket ? (uint2*)alloc(ebuf_floats) : nullptr;

    __half* agg_a  = (__half*)agg_a_f;
    __half* agg_t0 = (__half*)agg_t0f;
    __half* agg_t2 = (__half*)agg_t2f;
    __half* h_t    = (__half*)h_t_f;
    __half* h_a    = (__half*)h_a_f;
    __half* has0   = (__half*)asrc0a;
    __half* has1   = (__half*)asrc1t;
    __half* has2   = (__half*)asrc2t;

    dim3 blk(256);
    const int GPB_E = 4;    // encproj: 64 nodes per g-iter, 256 nodes/block
    const int GPB_C = 4;    // combineproj: 64 nodes per g-iter, 256 nodes/block
    int nbA8 = (NA + 7) / 8;
    int nbAe = (NA + 64 * GPB_E - 1) / (64 * GPB_E);
    int nbTe = (NT + 64 * GPB_E - 1) / (64 * GPB_E);
    int nbAcp = (NA + 64 * GPB_C - 1) / (64 * GPB_C);
    int nbTcp = (NT + 64 * GPB_C - 1) / (64 * GPB_C);
    int nbE = (E_TOT + 255) / 256;
    int nbScan = (NCAT + 1023) / 1024;

    // ---- CSR build (once, reused by all layers) ----
    if (canBucket) {
        int nbChunk = (E_TOT + CHUNK - 1) / CHUNK;
        zero_int_kernel<<<8, blk, 0, stream>>>((int*)scores, 64 + 1024);
        bucket_scatter_kernel<<<nbChunk, blk, 0, stream>>>(
            ei_in, ei_out, ei_sp, E_IN, E_OUT, E_SP, NT, NA, bcur, ebuf, E_TOT, NBUCK, cap);
        scanb_kernel<<<1, 1024, 0, stream>>>(bcur, boff, rowptrAll, NBUCK, cap, NCAT);
        bucket_csr_kernel<<<NBUCK, blk, 0, stream>>>(ebuf, boff, rowptrAll, colAll, NCAT, cap);
    } else {
        zero_int_kernel<<<2048, blk, 0, stream>>>(tmp, (long)tmp_span);
        hist_kernel<<<nbE, blk, 0, stream>>>(ei_in, ei_out, ei_sp, E_IN, E_OUT, E_SP, NT, NA, tmp, E_TOT);
        scan1_kernel<<<nbScan, blk, 0, stream>>>(tmp, rowptrAll, bsum, NCAT);
        scan2_kernel<<<1, 1024, 0, stream>>>(bsum, nbScan);
        scan3_kernel<<<(NCAT + 255) / 256, blk, 0, stream>>>(rowptrAll, bsum, tmp, NCAT, E_TOT);
        scatter_kernel<<<nbE, blk, 0, stream>>>(ei_in, ei_out, ei_sp, E_IN, E_OUT, E_SP, NT, NA, tmp, colAll, E_TOT);
    }

    // ---- fused encoder + layer-0 projection ----
    encproj_addr_kernel<<<nbAe, blk, 0, stream>>>(
        x_addr, enc_w_addr, enc_b_addr, pw_a, pb_a,
        att_src + 0 * 32, att_dst + 1 * 32,
        xa, h_a, has0, adst1a, NA, GPB_E);
    encproj_tx_kernel<<<nbTe, blk, 0, stream>>>(
        x_tx, enc_w_tx, enc_b_tx, pw_t, pb_t,
        att_src + 1 * 32, att_dst + 0 * 32, att_src + 2 * 32, att_dst + 2 * 32,
        xt, h_t, has1, adst0t, has2, adst2t, NT, GPB_E);

    auto agg_launch = [&](int mode, int nRows, const float* kw, const float* kb,
                          const float* q, float* sc) {
        int blocks = (nRows + 63) / 64;
        if (blocks > 2048) blocks = 2048;
        agg_all_kernel<<<blocks, blk, 0, stream>>>(
            rowptrAll, colAll, h_a, h_t,
            has0, adst0t, has1, adst1a, has2, adst2t,
            agg_t0, agg_a, agg_t2, kw, kb, q, sc, NT, NA, mode, nRows);
    };

    for (int l = 0; l < NLAYERS; l++) {
        bool last = (l == NLAYERS - 1);
        const float* kw = klw + l * 1024;
        const float* kb = klb + l * 32;
        const float* q  = qv + l * 32;
        float* sc = scores + 2 * l;
        if (!last) {
            if (roomy) {
                agg_launch(0, NCAT, kw, kb, q, sc);
            } else {
                agg_launch(1, 2 * NT, kw, kb, q, sc);
                agg_launch(2, NA, kw, kb, q, sc);
            }
            int lp = l + 1;
            combineproj_kernel<<<nbAcp + nbTcp, blk, 0, stream>>>(
                agg_a, agg_t0, agg_t2, xa, xt,
                ln_ag, ln_ab, ln_tg, ln_tb,
                sc, 1.0f / (float)NT,
                pw_a + lp * 1024, pb_a + lp * 32, pw_t + lp * 1024, pb_t + lp * 32,
                att_src + (lp * 3 + 0) * 32, att_dst + (lp * 3 + 1) * 32,
                att_src + (lp * 3 + 1) * 32, att_dst + (lp * 3 + 0) * 32,
                att_src + (lp * 3 + 2) * 32, att_dst + (lp * 3 + 2) * 32,
                h_a, h_t,
                has0, adst1a, has1, adst0t, has2, adst2t,
                NA, NT, nbAcp, GPB_C, lp == 3 ? 1 : 0);
        } else {
            agg_launch(2, NA, kw, kb, q, sc);
            combine_final_kernel<<<nbA8, blk, 0, stream>>>(agg_a, xa, ln_ag, ln_ab,
                                                           lin_w, lin_b, out, NA);
        }
    }
}